// Round 2
// baseline (5365.705 us; speedup 1.0000x reference)
//
#include <hip/hip_runtime.h>
#include <float.h>
#include <math.h>

constexpr int B = 8192;
constexpr int D = 512;
constexpr int KNN = 32;
constexpr float LAMBDA_REG = 0.1f;
constexpr float INV_TEMP = 10.0f;   // 1 / 0.1

__device__ __forceinline__ float waveReduceSum(float v) {
#pragma unroll
    for (int off = 32; off; off >>= 1) v += __shfl_down(v, off);
    return v;
}

// ---------------- row norms: nf = ||F||, invnf = 1/max(nf,1e-12) ----------------
__global__ __launch_bounds__(128) void k_norm(const float* __restrict__ F,
                                              float* __restrict__ nf,
                                              float* __restrict__ invnf) {
    int row = blockIdx.x, tid = threadIdx.x;
    const float4* f4 = (const float4*)(F + (size_t)row * D);
    float4 v = f4[tid];
    float ss = v.x * v.x + v.y * v.y + v.z * v.z + v.w * v.w;
    ss = waveReduceSum(ss);
    __shared__ float s2[2];
    if ((tid & 63) == 0) s2[tid >> 6] = ss;
    __syncthreads();
    if (tid == 0) {
        float nrm = sqrtf(s2[0] + s2[1]);
        nf[row] = nrm;
        invnf[row] = 1.0f / fmaxf(nrm, 1e-12f);
    }
}

// ---------------- ng = ||G|| ----------------
__global__ __launch_bounds__(128) void k_rownorm(const float* __restrict__ G,
                                                 float* __restrict__ ng) {
    int row = blockIdx.x, tid = threadIdx.x;
    const float4* g4 = (const float4*)(G + (size_t)row * D);
    float4 v = g4[tid];
    float ss = v.x * v.x + v.y * v.y + v.z * v.z + v.w * v.w;
    ss = waveReduceSum(ss);
    __shared__ float s2[2];
    if ((tid & 63) == 0) s2[tid >> 6] = ss;
    __syncthreads();
    if (tid == 0) ng[row] = sqrtf(s2[0] + s2[1]);
}

// ---------------- chunked NT GEMM over D, 64x64 tiles ----------------
// MODE 0: C[lr][c] = (f_r . f_c) * invnf[r] * invnf[c]                       (sim chunk)
// MODE 1: C[lr][c] = sim + 0.1 * (f_r . g_c) / max(nf[r]*ng[c], 1e-8)        (raw weights)
template <int MODE>
__global__ __launch_bounds__(256) void k_simgemm(const float* __restrict__ F,
                                                 const float* __restrict__ G2,
                                                 float* __restrict__ C, int r0,
                                                 const float* __restrict__ nf,
                                                 const float* __restrict__ invnf,
                                                 const float* __restrict__ ng) {
    constexpr int BK = 16;
    __shared__ __align__(16) float As[BK][68];
    __shared__ __align__(16) float Bs[BK][68];
    __shared__ __align__(16) float Gs[(MODE == 1) ? BK : 1][68];
    int tid = threadIdx.x;
    int tx = tid & 15, ty = tid >> 4;
    int gm = r0 + blockIdx.y * 64;   // global row base of tile
    int bn = blockIdx.x * 64;        // global col base of tile
    int lm = tid >> 2, lk = (tid & 3) * 4;
    const float* Ap = F + (size_t)(gm + lm) * D + lk;
    const float* Bp = F + (size_t)(bn + lm) * D + lk;
    const float* Gp = (MODE == 1) ? (G2 + (size_t)(bn + lm) * D + lk) : nullptr;
    float acc1[4][4] = {};
    float acc2[4][4] = {};
    for (int k0 = 0; k0 < D; k0 += BK) {
        float4 a = *(const float4*)(Ap + k0);
        float4 b = *(const float4*)(Bp + k0);
        As[lk + 0][lm] = a.x; As[lk + 1][lm] = a.y; As[lk + 2][lm] = a.z; As[lk + 3][lm] = a.w;
        Bs[lk + 0][lm] = b.x; Bs[lk + 1][lm] = b.y; Bs[lk + 2][lm] = b.z; Bs[lk + 3][lm] = b.w;
        if (MODE == 1) {
            float4 g = *(const float4*)(Gp + k0);
            Gs[lk + 0][lm] = g.x; Gs[lk + 1][lm] = g.y; Gs[lk + 2][lm] = g.z; Gs[lk + 3][lm] = g.w;
        }
        __syncthreads();
#pragma unroll
        for (int k = 0; k < BK; k++) {
            float4 ra = *(const float4*)&As[k][ty * 4];
            float4 rb = *(const float4*)&Bs[k][tx * 4];
            float av[4] = {ra.x, ra.y, ra.z, ra.w};
            float bv[4] = {rb.x, rb.y, rb.z, rb.w};
#pragma unroll
            for (int i = 0; i < 4; i++)
#pragma unroll
                for (int j = 0; j < 4; j++) acc1[i][j] += av[i] * bv[j];
            if (MODE == 1) {
                float4 rg = *(const float4*)&Gs[k][tx * 4];
                float gv[4] = {rg.x, rg.y, rg.z, rg.w};
#pragma unroll
                for (int i = 0; i < 4; i++)
#pragma unroll
                    for (int j = 0; j < 4; j++) acc2[i][j] += av[i] * gv[j];
            }
        }
        __syncthreads();
    }
#pragma unroll
    for (int i = 0; i < 4; i++) {
        int r = gm + ty * 4 + i;
        int lr = blockIdx.y * 64 + ty * 4 + i;
        float invr = invnf[r];
        float nfr = nf[r];
        float* Cp = C + (size_t)lr * B + bn + tx * 4;
        float4 o;
        float* op = &o.x;
#pragma unroll
        for (int j = 0; j < 4; j++) {
            int c = bn + tx * 4 + j;
            float s = acc1[i][j] * invr * invnf[c];
            if (MODE == 1)
                s += LAMBDA_REG * acc2[i][j] / fmaxf(nfr * ng[c], 1e-8f);
            op[j] = s;
        }
        *(float4*)Cp = o;
    }
}

// ---------------- per-row top-K (excluding self), iterative argmax in LDS ----------------
__global__ __launch_bounds__(256) void k_topk(const float* __restrict__ S,
                                              int* __restrict__ topk, int r0) {
    __shared__ float row[B];
    __shared__ float rv[4];
    __shared__ int ri[4];
    int li = blockIdx.x, tid = threadIdx.x;
    int i = r0 + li;  // global row
    const float4* s4 = (const float4*)(S + (size_t)li * B);
    for (int t = tid; t < B / 4; t += 256) {
        float4 v = s4[t];
        *(float4*)&row[t * 4] = v;
    }
    __syncthreads();
    if (tid == 0) row[i] = -FLT_MAX;  // exclude self
    __syncthreads();
    for (int it = 0; it < KNN; it++) {
        float bv = -FLT_MAX;
        int bi = 0;
        for (int t = tid; t < B; t += 256) {
            float v = row[t];
            if (v > bv) { bv = v; bi = t; }
        }
#pragma unroll
        for (int off = 32; off; off >>= 1) {
            float ov = __shfl_down(bv, off);
            int oi = __shfl_down(bi, off);
            if (ov > bv || (ov == bv && oi < bi)) { bv = ov; bi = oi; }
        }
        if ((tid & 63) == 0) { rv[tid >> 6] = bv; ri[tid >> 6] = bi; }
        __syncthreads();
        if (tid == 0) {
            float fv = rv[0]; int fi = ri[0];
#pragma unroll
            for (int w = 1; w < 4; w++)
                if (rv[w] > fv || (rv[w] == fv && ri[w] < fi)) { fv = rv[w]; fi = ri[w]; }
            topk[(size_t)i * KNN + it] = fi;
            row[fi] = -FLT_MAX;
        }
        __syncthreads();
    }
}

// ---------------- graph build ----------------
__global__ void k_zero2(int* __restrict__ a, int* __restrict__ b) {
    int i = blockIdx.x * 256 + threadIdx.x;
    a[i] = 0;
    b[i] = 0;
}

__global__ void k_count(const int* __restrict__ topk, int* __restrict__ indeg) {
    int e = blockIdx.x * 256 + threadIdx.x;
    atomicAdd(&indeg[topk[e]], 1);
}

__global__ __launch_bounds__(1024) void k_scan(const int* __restrict__ indeg,
                                               int* __restrict__ roff) {
    __shared__ int sums[1024];
    int tid = threadIdx.x;
    int base = tid * 8;
    int loc[8];
    int s = 0;
#pragma unroll
    for (int j = 0; j < 8; j++) { loc[j] = s; s += indeg[base + j]; }
    sums[tid] = s;
    __syncthreads();
    for (int off = 1; off < 1024; off <<= 1) {
        int v = (tid >= off) ? sums[tid - off] : 0;
        __syncthreads();
        sums[tid] += v;
        __syncthreads();
    }
    int prev = (tid > 0) ? sums[tid - 1] : 0;
#pragma unroll
    for (int j = 0; j < 8; j++) roff[base + j] = prev + loc[j];
    if (tid == 1023) roff[B] = sums[1023];
}

__global__ void k_dinv(const int* __restrict__ indeg, float* __restrict__ dinv) {
    int i = blockIdx.x * 256 + threadIdx.x;
    float dg = (float)(KNN + indeg[i]);
    dinv[i] = fminf(1.0f / sqrtf(dg), 1e6f);
}

__global__ void k_fill(const int* __restrict__ topk, const int* __restrict__ roff,
                       int* __restrict__ fill, int* __restrict__ ridx) {
    int e = blockIdx.x * 256 + threadIdx.x;
    int dst = topk[e];
    int src = e >> 5;  // e / KNN
    int pos = atomicAdd(&fill[dst], 1);
    ridx[roff[dst] + pos] = src;
}

// ---------------- normalized SpMM: out_i = dinv_i * (sum_out + sum_in) ----------------
__global__ __launch_bounds__(128) void k_spmm(const float* __restrict__ Vin,
                                              float* __restrict__ Vout,
                                              const int* __restrict__ topk,
                                              const int* __restrict__ roff,
                                              const int* __restrict__ ridx,
                                              const float* __restrict__ dinv) {
    int i = blockIdx.x, tid = threadIdx.x;
    float4 acc; acc.x = acc.y = acc.z = acc.w = 0.0f;
    for (int k = 0; k < KNN; k++) {
        int n = topk[(size_t)i * KNN + k];
        float w = dinv[n];
        float4 v = *(const float4*)(Vin + (size_t)n * D + tid * 4);
        acc.x += w * v.x; acc.y += w * v.y; acc.z += w * v.z; acc.w += w * v.w;
    }
    int s = roff[i], e = roff[i + 1];
    for (int t = s; t < e; t++) {
        int j = ridx[t];
        float w = dinv[j];
        float4 v = *(const float4*)(Vin + (size_t)j * D + tid * 4);
        acc.x += w * v.x; acc.y += w * v.y; acc.z += w * v.z; acc.w += w * v.w;
    }
    float wi = dinv[i];
    float4 o; o.x = wi * acc.x; o.y = wi * acc.y; o.z = wi * acc.z; o.w = wi * acc.w;
    *(float4*)(Vout + (size_t)i * D + tid * 4) = o;
}

// ---------------- in-place row softmax of chunk rows (raw * 10) ----------------
__global__ __launch_bounds__(256) void k_softmax(float* __restrict__ Wm) {
    __shared__ float row[B];
    __shared__ float red[4];
    int li = blockIdx.x, tid = threadIdx.x;
    float* rp = Wm + (size_t)li * B;
    float mx = -FLT_MAX;
    for (int t = tid; t < B / 4; t += 256) {
        float4 v = *(const float4*)(rp + t * 4);
        *(float4*)&row[t * 4] = v;
        mx = fmaxf(mx, fmaxf(fmaxf(v.x, v.y), fmaxf(v.z, v.w)));
    }
#pragma unroll
    for (int off = 32; off; off >>= 1) mx = fmaxf(mx, __shfl_down(mx, off));
    if ((tid & 63) == 0) red[tid >> 6] = mx;
    __syncthreads();
    mx = fmaxf(fmaxf(red[0], red[1]), fmaxf(red[2], red[3]));
    __syncthreads();
    float sum = 0.0f;
    for (int t = tid; t < B; t += 256) {
        float e = __expf((row[t] - mx) * INV_TEMP);
        row[t] = e;
        sum += e;
    }
    sum = waveReduceSum(sum);
    if ((tid & 63) == 0) red[tid >> 6] = sum;
    __syncthreads();
    sum = red[0] + red[1] + red[2] + red[3];
    float sc = 1.0f / sum;
    for (int t = tid; t < B / 4; t += 256) {
        float4 v = *(const float4*)&row[t * 4];
        float4 o; o.x = v.x * sc; o.y = v.y * sc; o.z = v.z * sc; o.w = v.w * sc;
        *(float4*)(rp + t * 4) = o;
    }
}

// ---------------- NN GEMM: out[r0+lr][n] = chunk[lr][:] @ F[:][n] ----------------
__global__ __launch_bounds__(256) void k_gemm_nn(const float* __restrict__ A,
                                                 const float* __restrict__ Bm,
                                                 float* __restrict__ Cout, int r0) {
    constexpr int BK = 16;
    __shared__ __align__(16) float As[BK][68];
    __shared__ __align__(16) float Bs[BK][68];
    int tid = threadIdx.x;
    int tx = tid & 15, ty = tid >> 4;
    int bm = blockIdx.y * 64;  // local chunk row base
    int bn = blockIdx.x * 64;  // output col base (< D)
    int lm = tid >> 2, lk = (tid & 3) * 4;   // A loader
    int bk = tid >> 4, bq = (tid & 15) * 4;  // B loader
    float acc[4][4] = {};
    for (int k0 = 0; k0 < B; k0 += BK) {
        float4 a = *(const float4*)(A + (size_t)(bm + lm) * B + k0 + lk);
        As[lk + 0][lm] = a.x; As[lk + 1][lm] = a.y; As[lk + 2][lm] = a.z; As[lk + 3][lm] = a.w;
        float4 b = *(const float4*)(Bm + (size_t)(k0 + bk) * D + bn + bq);
        *(float4*)&Bs[bk][bq] = b;
        __syncthreads();
#pragma unroll
        for (int k = 0; k < BK; k++) {
            float4 ra = *(const float4*)&As[k][ty * 4];
            float4 rb = *(const float4*)&Bs[k][tx * 4];
            float av[4] = {ra.x, ra.y, ra.z, ra.w};
            float bv[4] = {rb.x, rb.y, rb.z, rb.w};
#pragma unroll
            for (int i = 0; i < 4; i++)
#pragma unroll
                for (int j = 0; j < 4; j++) acc[i][j] += av[i] * bv[j];
        }
        __syncthreads();
    }
#pragma unroll
    for (int i = 0; i < 4; i++) {
        int r = r0 + bm + ty * 4 + i;
        float* Cp = Cout + (size_t)r * D + bn + tx * 4;
        float4 o; o.x = acc[i][0]; o.y = acc[i][1]; o.z = acc[i][2]; o.w = acc[i][3];
        *(float4*)Cp = o;
    }
}

extern "C" void kernel_launch(void* const* d_in, const int* in_sizes, int n_in,
                              void* d_out, int out_size, void* d_ws, size_t ws_size,
                              hipStream_t stream) {
    (void)in_sizes; (void)n_in; (void)out_size;
    const float* F = (const float*)d_in[0];
    float* out = (float*)d_out;

    char* ws = (char*)d_ws;
    size_t off = 0;
    auto take = [&](size_t bytes) -> void* {
        void* p = ws + off;
        off += (bytes + 255) & ~(size_t)255;
        return p;
    };
    float* nf    = (float*)take((size_t)B * 4);
    float* invnf = (float*)take((size_t)B * 4);
    float* ng    = (float*)take((size_t)B * 4);
    float* dinv  = (float*)take((size_t)B * 4);
    int*   topk  = (int*)take((size_t)B * KNN * 4);
    int*   indeg = (int*)take((size_t)B * 4);
    int*   roff  = (int*)take((size_t)(B + 1) * 4);
    int*   rfill = (int*)take((size_t)B * 4);
    int*   ridx  = (int*)take((size_t)B * KNN * 4);
    float* G2    = (float*)take((size_t)B * D * 4);
    size_t fixed = off;

    // pick chunk row count R from remaining workspace (R divides B)
    int R = 2048;
    if (ws_size > 0) {
        while (R > 64 && fixed + (size_t)R * B * 4 > ws_size) R >>= 1;
    } else {
        R = 512;
    }
    float* chunk = (float*)(ws + fixed);
    float* G1 = out;  // reuse output buffer as scratch for first SpMM result

    // 1. row norms of F
    k_norm<<<B, 128, 0, stream>>>(F, nf, invnf);

    // 2. chunked: sim chunk + top-K
    for (int r0 = 0; r0 < B; r0 += R) {
        dim3 g(B / 64, R / 64);
        k_simgemm<0><<<g, 256, 0, stream>>>(F, nullptr, chunk, r0, nf, invnf, nullptr);
        k_topk<<<R, 256, 0, stream>>>(chunk, topk, r0);
    }

    // 3. graph build
    k_zero2<<<B / 256, 256, 0, stream>>>(indeg, rfill);
    k_count<<<B * KNN / 256, 256, 0, stream>>>(topk, indeg);
    k_scan<<<1, 1024, 0, stream>>>(indeg, roff);
    k_dinv<<<B / 256, 256, 0, stream>>>(indeg, dinv);
    k_fill<<<B * KNN / 256, 256, 0, stream>>>(topk, roff, rfill, ridx);

    // 4. geodesic = A_hat @ (A_hat @ F)   (G1 lives in d_out temporarily)
    k_spmm<<<B, 128, 0, stream>>>(F, G1, topk, roff, ridx, dinv);
    k_spmm<<<B, 128, 0, stream>>>(G1, G2, topk, roff, ridx, dinv);

    // 5. ng = ||geodesic||
    k_rownorm<<<B, 128, 0, stream>>>(G2, ng);

    // 6. chunked: raw weights -> softmax -> enhanced rows
    for (int r0 = 0; r0 < B; r0 += R) {
        dim3 g(B / 64, R / 64);
        k_simgemm<1><<<g, 256, 0, stream>>>(F, G2, chunk, r0, nf, invnf, ng);
        k_softmax<<<R, 256, 0, stream>>>(chunk);
        dim3 gnn(D / 64, R / 64);
        k_gemm_nn<<<gnn, 256, 0, stream>>>(chunk, F, out, r0);
    }
}

// Round 3
// 1853.121 us; speedup vs baseline: 2.8955x; 2.8955x over previous
//
#include <hip/hip_runtime.h>
#include <hip/hip_bf16.h>
#include <float.h>
#include <math.h>

constexpr int B = 8192;
constexpr int D = 512;
constexpr int KNN = 32;

typedef __attribute__((ext_vector_type(8))) short bhalf8;
typedef __attribute__((ext_vector_type(4))) float floatx4;

#if defined(__has_builtin)
#if __has_builtin(__builtin_amdgcn_global_load_lds)
#define HAS_GLD 1
#else
#define HAS_GLD 0
#endif
#else
#define HAS_GLD 0
#endif

__device__ __forceinline__ unsigned short f2bf(float f) {
    __hip_bfloat16 h = __float2bfloat16(f);
    return __builtin_bit_cast(unsigned short, h);
}

__device__ __forceinline__ float waveReduceSum(float v) {
#pragma unroll
    for (int off = 32; off; off >>= 1) v += __shfl_down(v, off);
    return v;
}

// stage one 16B chunk of a 128x32-bf16 tile (linear LDS, 64B rows).
// c in [0,512): byte offset c*16.  gld path needs wave-uniform LDS base.
__device__ __forceinline__ void stage_chunk(const unsigned short* __restrict__ g,
                                            char* __restrict__ lds_tile, int c) {
#if HAS_GLD
    char* wavebase = lds_tile + (size_t)(c & ~63) * 16;
    __builtin_amdgcn_global_load_lds((const __attribute__((address_space(1))) void*)g,
                                     (__attribute__((address_space(3))) void*)wavebase,
                                     16, 0, 0);
#else
    *(int4*)(lds_tile + (size_t)c * 16) = *(const int4*)g;
#endif
}

// ---------------- bf16 MFMA GEMM, NT form: C[m][n] = s1*A[m][:].B1[n][:] (+ s2*A.B2) ----
// 128x128 tile, BK=32, 256 threads = 4 waves (2x2), each wave 64x64 via 4x4 16x16x32 MFMA.
template <bool DUAL>
__global__ __launch_bounds__(256, 2) void k_mfma_nt(
    const unsigned short* __restrict__ A, int lda,
    const unsigned short* __restrict__ B1,
    const unsigned short* __restrict__ B2, int ldb,
    float* __restrict__ C, int ldc, int Kd, float s1, float s2) {
    constexpr int NT = DUAL ? 3 : 2;
    __shared__ __align__(16) char smem[NT * 8192];
    char* Asm = smem;
    char* B1sm = smem + 8192;
    char* B2sm = smem + 16384;  // only touched when DUAL

    int tid = threadIdx.x;
    int lane = tid & 63;
    int wid = tid >> 6;
    int wm = (wid >> 1) * 64, wn = (wid & 1) * 64;
    int lrow = lane & 15;
    int kh = lane >> 4;  // 0..3 -> k-offset kh*8 elements (16 bytes)
    int gm = blockIdx.y * 128, gn = blockIdx.x * 128;

    floatx4 zero4 = {0.0f, 0.0f, 0.0f, 0.0f};
    floatx4 acc1[4][4], acc2[4][4];
#pragma unroll
    for (int m = 0; m < 4; m++)
#pragma unroll
        for (int n = 0; n < 4; n++) { acc1[m][n] = zero4; acc2[m][n] = zero4; }

    for (int k0 = 0; k0 < Kd; k0 += 32) {
        __syncthreads();  // protect LDS from previous iteration's readers
#pragma unroll
        for (int p = 0; p < 2; p++) {
            int c = p * 256 + tid;
            int row = c >> 2;
            int col = (c & 3) * 8;
            stage_chunk(A + (size_t)(gm + row) * lda + k0 + col, Asm, c);
            stage_chunk(B1 + (size_t)(gn + row) * ldb + k0 + col, B1sm, c);
            if (DUAL)
                stage_chunk(B2 + (size_t)(gn + row) * ldb + k0 + col, B2sm, c);
        }
        __syncthreads();  // drains vmcnt (global_load_lds) + lgkm

        bhalf8 a[4];
#pragma unroll
        for (int m = 0; m < 4; m++)
            a[m] = *(const bhalf8*)(Asm + (wm + m * 16 + lrow) * 64 + kh * 16);
#pragma unroll
        for (int n = 0; n < 4; n++) {
            bhalf8 b = *(const bhalf8*)(B1sm + (wn + n * 16 + lrow) * 64 + kh * 16);
#pragma unroll
            for (int m = 0; m < 4; m++)
                acc1[m][n] = __builtin_amdgcn_mfma_f32_16x16x32_bf16(a[m], b, acc1[m][n], 0, 0, 0);
            if (DUAL) {
                bhalf8 b2 = *(const bhalf8*)(B2sm + (wn + n * 16 + lrow) * 64 + kh * 16);
#pragma unroll
                for (int m = 0; m < 4; m++)
                    acc2[m][n] = __builtin_amdgcn_mfma_f32_16x16x32_bf16(a[m], b2, acc2[m][n], 0, 0, 0);
            }
        }
    }

    // epilogue: C/D layout col=lane&15, row=(lane>>4)*4+q  [m89-verified]
#pragma unroll
    for (int m = 0; m < 4; m++) {
#pragma unroll
        for (int n = 0; n < 4; n++) {
            int cc = gn + wn + n * 16 + lrow;
#pragma unroll
            for (int q = 0; q < 4; q++) {
                int r = gm + wm + m * 16 + kh * 4 + q;
                float v = acc1[m][n][q] * s1;
                if (DUAL) v += acc2[m][n][q] * s2;
                C[(size_t)r * ldc + cc] = v;
            }
        }
    }
}

// ---------------- normalize rows of F -> bf16 Xb ----------------
__global__ __launch_bounds__(128) void k_norm(const float* __restrict__ F,
                                              unsigned short* __restrict__ Xb) {
    int row = blockIdx.x, tid = threadIdx.x;
    float4 v = ((const float4*)(F + (size_t)row * D))[tid];
    float ss = v.x * v.x + v.y * v.y + v.z * v.z + v.w * v.w;
    ss = waveReduceSum(ss);
    __shared__ float s2[2];
    if ((tid & 63) == 0) s2[tid >> 6] = ss;
    __syncthreads();
    float inv = 1.0f / fmaxf(sqrtf(s2[0] + s2[1]), 1e-12f);
    union { unsigned short s[4]; int2 q; } u;
    u.s[0] = f2bf(v.x * inv); u.s[1] = f2bf(v.y * inv);
    u.s[2] = f2bf(v.z * inv); u.s[3] = f2bf(v.w * inv);
    *(int2*)(Xb + (size_t)row * D + tid * 4) = u.q;
}

// ---------------- transpose F (fp32 BxD) -> FbT (bf16 DxB) ----------------
__global__ __launch_bounds__(256) void k_transpose(const float* __restrict__ F,
                                                   unsigned short* __restrict__ FbT) {
    __shared__ float t[64][65];
    int r0 = blockIdx.x * 64, d0 = blockIdx.y * 64;
    int tid = threadIdx.x;
#pragma unroll
    for (int p = 0; p < 4; p++) {
        int idx = p * 256 + tid;  // 64 rows x 16 float4
        int r = idx >> 4, c4 = (idx & 15) * 4;
        float4 v = *(const float4*)(F + (size_t)(r0 + r) * D + d0 + c4);
        t[r][c4 + 0] = v.x; t[r][c4 + 1] = v.y; t[r][c4 + 2] = v.z; t[r][c4 + 3] = v.w;
    }
    __syncthreads();
#pragma unroll
    for (int p = 0; p < 2; p++) {
        int idx = p * 256 + tid;  // 64 d-rows x 8 chunks of 8
        int d = idx >> 3, rc = (idx & 7) * 8;
        union { unsigned short s[8]; int4 v; } u;
#pragma unroll
        for (int j = 0; j < 8; j++) u.s[j] = f2bf(t[rc + j][d]);
        *(int4*)(FbT + (size_t)(d0 + d) * B + r0 + rc) = u.v;
    }
}

// ---------------- G2 (fp32) -> bf16 Hb = G2/||G2 row|| ----------------
__global__ __launch_bounds__(128) void k_hnorm(const float* __restrict__ G,
                                               unsigned short* __restrict__ Hb) {
    int row = blockIdx.x, tid = threadIdx.x;
    float4 v = ((const float4*)(G + (size_t)row * D))[tid];
    float ss = v.x * v.x + v.y * v.y + v.z * v.z + v.w * v.w;
    ss = waveReduceSum(ss);
    __shared__ float s2[2];
    if ((tid & 63) == 0) s2[tid >> 6] = ss;
    __syncthreads();
    float inv = 1.0f / fmaxf(sqrtf(s2[0] + s2[1]), 1e-12f);
    union { unsigned short s[4]; int2 q; } u;
    u.s[0] = f2bf(v.x * inv); u.s[1] = f2bf(v.y * inv);
    u.s[2] = f2bf(v.z * inv); u.s[3] = f2bf(v.w * inv);
    *(int2*)(Hb + (size_t)row * D + tid * 4) = u.q;
}

// ---------------- per-row top-K (excluding self) on fp32 sim chunk ----------------
__global__ __launch_bounds__(256) void k_topk(const float* __restrict__ S,
                                              int* __restrict__ topk, int r0) {
    __shared__ float row[B];
    __shared__ float rv[4];
    __shared__ int ri[4];
    int li = blockIdx.x, tid = threadIdx.x;
    int i = r0 + li;
    const float4* s4 = (const float4*)(S + (size_t)li * B);
    for (int t = tid; t < B / 4; t += 256) *(float4*)&row[t * 4] = s4[t];
    __syncthreads();
    if (tid == 0) row[i] = -FLT_MAX;
    __syncthreads();
    for (int it = 0; it < KNN; it++) {
        float bv = -FLT_MAX;
        int bi = 0;
        for (int t = tid; t < B; t += 256) {
            float v = row[t];
            if (v > bv) { bv = v; bi = t; }
        }
#pragma unroll
        for (int off = 32; off; off >>= 1) {
            float ov = __shfl_down(bv, off);
            int oi = __shfl_down(bi, off);
            if (ov > bv || (ov == bv && oi < bi)) { bv = ov; bi = oi; }
        }
        if ((tid & 63) == 0) { rv[tid >> 6] = bv; ri[tid >> 6] = bi; }
        __syncthreads();
        if (tid == 0) {
            float fv = rv[0]; int fi = ri[0];
#pragma unroll
            for (int w = 1; w < 4; w++)
                if (rv[w] > fv || (rv[w] == fv && ri[w] < fi)) { fv = rv[w]; fi = ri[w]; }
            topk[(size_t)i * KNN + it] = fi;
            row[fi] = -FLT_MAX;
        }
        __syncthreads();
    }
}

// ---------------- graph build ----------------
__global__ void k_zero2(int* __restrict__ a, int* __restrict__ b) {
    int i = blockIdx.x * 256 + threadIdx.x;
    a[i] = 0;
    b[i] = 0;
}

__global__ void k_count(const int* __restrict__ topk, int* __restrict__ indeg) {
    int e = blockIdx.x * 256 + threadIdx.x;
    atomicAdd(&indeg[topk[e]], 1);
}

__global__ __launch_bounds__(1024) void k_scan(const int* __restrict__ indeg,
                                               int* __restrict__ roff) {
    __shared__ int sums[1024];
    int tid = threadIdx.x;
    int base = tid * 8;
    int loc[8];
    int s = 0;
#pragma unroll
    for (int j = 0; j < 8; j++) { loc[j] = s; s += indeg[base + j]; }
    sums[tid] = s;
    __syncthreads();
    for (int off = 1; off < 1024; off <<= 1) {
        int v = (tid >= off) ? sums[tid - off] : 0;
        __syncthreads();
        sums[tid] += v;
        __syncthreads();
    }
    int prev = (tid > 0) ? sums[tid - 1] : 0;
#pragma unroll
    for (int j = 0; j < 8; j++) roff[base + j] = prev + loc[j];
    if (tid == 1023) roff[B] = sums[1023];
}

__global__ void k_dinv(const int* __restrict__ indeg, float* __restrict__ dinv) {
    int i = blockIdx.x * 256 + threadIdx.x;
    float dg = (float)(KNN + indeg[i]);
    dinv[i] = fminf(1.0f / sqrtf(dg), 1e6f);
}

__global__ void k_fill(const int* __restrict__ topk, const int* __restrict__ roff,
                       int* __restrict__ fill, int* __restrict__ ridx) {
    int e = blockIdx.x * 256 + threadIdx.x;
    int dst = topk[e];
    int src = e >> 5;  // e / KNN
    int pos = atomicAdd(&fill[dst], 1);
    ridx[roff[dst] + pos] = src;
}

// ---------------- normalized SpMM: out_i = dinv_i * (sum_out + sum_in) ----------------
__global__ __launch_bounds__(128) void k_spmm(const float* __restrict__ Vin,
                                              float* __restrict__ Vout,
                                              const int* __restrict__ topk,
                                              const int* __restrict__ roff,
                                              const int* __restrict__ ridx,
                                              const float* __restrict__ dinv) {
    int i = blockIdx.x, tid = threadIdx.x;
    float4 acc; acc.x = acc.y = acc.z = acc.w = 0.0f;
    for (int k = 0; k < KNN; k++) {
        int n = topk[(size_t)i * KNN + k];
        float w = dinv[n];
        float4 v = *(const float4*)(Vin + (size_t)n * D + tid * 4);
        acc.x += w * v.x; acc.y += w * v.y; acc.z += w * v.z; acc.w += w * v.w;
    }
    int s = roff[i], e = roff[i + 1];
    for (int t = s; t < e; t++) {
        int j = ridx[t];
        float w = dinv[j];
        float4 v = *(const float4*)(Vin + (size_t)j * D + tid * 4);
        acc.x += w * v.x; acc.y += w * v.y; acc.z += w * v.z; acc.w += w * v.w;
    }
    float wi = dinv[i];
    float4 o; o.x = wi * acc.x; o.y = wi * acc.y; o.z = wi * acc.z; o.w = wi * acc.w;
    *(float4*)(Vout + (size_t)i * D + tid * 4) = o;
}

// ------- row softmax of prescaled logits; writes bf16 weights IN PLACE (row in LDS first) ----
__global__ __launch_bounds__(256) void k_softmax(float* __restrict__ chunk) {
    __shared__ float row[B];
    __shared__ float red[4];
    int li = blockIdx.x, tid = threadIdx.x;
    float* rp = chunk + (size_t)li * B;
    float mx = -FLT_MAX;
    for (int t = tid; t < B / 4; t += 256) {
        float4 v = *(const float4*)(rp + t * 4);
        *(float4*)&row[t * 4] = v;
        mx = fmaxf(mx, fmaxf(fmaxf(v.x, v.y), fmaxf(v.z, v.w)));
    }
#pragma unroll
    for (int off = 32; off; off >>= 1) mx = fmaxf(mx, __shfl_down(mx, off));
    if ((tid & 63) == 0) red[tid >> 6] = mx;
    __syncthreads();
    mx = fmaxf(fmaxf(red[0], red[1]), fmaxf(red[2], red[3]));
    __syncthreads();
    float sum = 0.0f;
    for (int t = tid; t < B; t += 256) {
        float e = __expf(row[t] - mx);
        row[t] = e;
        sum += e;
    }
    sum = waveReduceSum(sum);
    if ((tid & 63) == 0) red[tid >> 6] = sum;
    __syncthreads();
    sum = red[0] + red[1] + red[2] + red[3];
    float sc = 1.0f / sum;
    unsigned short* wp = (unsigned short*)rp;  // bf16 over first half of the fp32 row
    for (int t = tid; t < B / 8; t += 256) {
        union { unsigned short s[8]; int4 v; } u;
#pragma unroll
        for (int j = 0; j < 8; j++) u.s[j] = f2bf(row[t * 8 + j] * sc);
        *(int4*)(wp + t * 8) = u.v;
    }
}

extern "C" void kernel_launch(void* const* d_in, const int* in_sizes, int n_in,
                              void* d_out, int out_size, void* d_ws, size_t ws_size,
                              hipStream_t stream) {
    (void)in_sizes; (void)n_in; (void)out_size;
    const float* F = (const float*)d_in[0];
    float* out = (float*)d_out;

    char* ws = (char*)d_ws;
    size_t off = 0;
    auto take = [&](size_t bytes) -> void* {
        void* p = ws + off;
        off += (bytes + 255) & ~(size_t)255;
        return p;
    };
    float* dinv = (float*)take((size_t)B * 4);
    int* topk = (int*)take((size_t)B * KNN * 4);
    int* indeg = (int*)take((size_t)B * 4);
    int* roff = (int*)take((size_t)(B + 1) * 4);
    int* rfill = (int*)take((size_t)B * 4);
    int* ridx = (int*)take((size_t)B * KNN * 4);
    float* G2 = (float*)take((size_t)B * D * 4);
    unsigned short* Xb = (unsigned short*)take((size_t)B * D * 2);
    unsigned short* Hb = (unsigned short*)take((size_t)B * D * 2);
    unsigned short* FbT = (unsigned short*)take((size_t)D * B * 2);
    size_t fixed = off;

    int R = 2048;
    if (ws_size > 0) {
        while (R > 128 && fixed + (size_t)R * B * 4 > ws_size) R >>= 1;
    } else {
        R = 1024;
    }
    float* chunk = (float*)(ws + fixed);
    float* G1 = out;  // d_out doubles as scratch for first SpMM result

    // 1. Xb = bf16 normalized F; FbT = bf16 F^T
    k_norm<<<B, 128, 0, stream>>>(F, Xb);
    dim3 gt(B / 64, D / 64);
    k_transpose<<<gt, 256, 0, stream>>>(F, FbT);

    // 2. chunked: sim = Xb Xb^T (fp32 out) + top-K
    for (int r0 = 0; r0 < B; r0 += R) {
        dim3 g(B / 128, R / 128);
        k_mfma_nt<false><<<g, 256, 0, stream>>>(Xb + (size_t)r0 * D, D, Xb, nullptr, D,
                                                chunk, B, D, 1.0f, 0.0f);
        k_topk<<<R, 256, 0, stream>>>(chunk, topk, r0);
    }

    // 3. graph build
    k_zero2<<<B / 256, 256, 0, stream>>>(indeg, rfill);
    k_count<<<B * KNN / 256, 256, 0, stream>>>(topk, indeg);
    k_scan<<<1, 1024, 0, stream>>>(indeg, roff);
    k_dinv<<<B / 256, 256, 0, stream>>>(indeg, dinv);
    k_fill<<<B * KNN / 256, 256, 0, stream>>>(topk, roff, rfill, ridx);

    // 4. geodesic = A_hat @ (A_hat @ F); Hb = bf16 row-normalized geodesic
    k_spmm<<<B, 128, 0, stream>>>(F, G1, topk, roff, ridx, dinv);
    k_spmm<<<B, 128, 0, stream>>>(G1, G2, topk, roff, ridx, dinv);
    k_hnorm<<<B, 128, 0, stream>>>(G2, Hb);

    // 5. chunked: logits = 10*sim + cos -> softmax (bf16 in place) -> out rows = W @ F
    for (int r0 = 0; r0 < B; r0 += R) {
        dim3 g(B / 128, R / 128);
        k_mfma_nt<true><<<g, 256, 0, stream>>>(Xb + (size_t)r0 * D, D, Xb, Hb, D,
                                               chunk, B, D, 10.0f, 1.0f);
        k_softmax<<<R, 256, 0, stream>>>(chunk);
        dim3 gf(D / 128, R / 128);
        k_mfma_nt<false><<<gf, 256, 0, stream>>>((const unsigned short*)chunk, 2 * B, FbT,
                                                 nullptr, B, out + (size_t)r0 * D, D, B,
                                                 1.0f, 0.0f);
    }
}

// Round 5
// 1036.206 us; speedup vs baseline: 5.1782x; 1.7884x over previous
//
#include <hip/hip_runtime.h>
#include <hip/hip_bf16.h>
#include <float.h>
#include <math.h>

constexpr int B = 8192;
constexpr int D = 512;
constexpr int KNN = 32;

typedef __attribute__((ext_vector_type(8))) short bhalf8;
typedef __attribute__((ext_vector_type(4))) float floatx4;

#if defined(__has_builtin)
#if __has_builtin(__builtin_amdgcn_global_load_lds)
#define HAS_GLD 1
#else
#define HAS_GLD 0
#endif
#else
#define HAS_GLD 0
#endif

__device__ __forceinline__ unsigned short f2bf(float f) {
    __hip_bfloat16 h = __float2bfloat16(f);
    return __builtin_bit_cast(unsigned short, h);
}

__device__ __forceinline__ float waveReduceSum(float v) {
#pragma unroll
    for (int off = 32; off; off >>= 1) v += __shfl_down(v, off);
    return v;
}

// stage one 16B chunk of a 128x32-bf16 tile (linear LDS, 64B rows).
__device__ __forceinline__ void stage_chunk(const unsigned short* __restrict__ g,
                                            char* __restrict__ lds_tile, int c) {
#if HAS_GLD
    char* wavebase = lds_tile + (size_t)(c & ~63) * 16;
    __builtin_amdgcn_global_load_lds((const __attribute__((address_space(1))) void*)g,
                                     (__attribute__((address_space(3))) void*)wavebase,
                                     16, 0, 0);
#else
    *(int4*)(lds_tile + (size_t)c * 16) = *(const int4*)g;
#endif
}

// ---------------- bf16 MFMA GEMM, NT form ----------------
// C[m][n] = s1*A[m][:].B1[n][:] (+ s2*A.B2).  128x128 tile, BK=32, 4 waves 2x2.
// Split-K via blockIdx.z: K-range [z*ksplit, (z+1)*ksplit), C += z*zstride.
// NOTE: lda/ldb are in u16 elements; ldc/zstride in floats.
template <bool DUAL>
__global__ __launch_bounds__(256, 2) void k_mfma_nt(
    const unsigned short* __restrict__ A, int lda,
    const unsigned short* __restrict__ B1,
    const unsigned short* __restrict__ B2, int ldb,
    float* __restrict__ C, int ldc, int zstride, int ksplit,
    float s1, float s2) {
    constexpr int NT = DUAL ? 3 : 2;
    __shared__ __align__(16) char smem[NT * 8192];
    char* Asm = smem;
    char* B1sm = smem + 8192;
    char* B2sm = smem + 16384;  // only touched when DUAL

    int tid = threadIdx.x;
    int lane = tid & 63;
    int wid = tid >> 6;
    int wm = (wid >> 1) * 64, wn = (wid & 1) * 64;
    int lrow = lane & 15;
    int kh = lane >> 4;
    int gm = blockIdx.y * 128, gn = blockIdx.x * 128;
    int kbeg = blockIdx.z * ksplit;
    C += (size_t)blockIdx.z * zstride;

    floatx4 zero4 = {0.0f, 0.0f, 0.0f, 0.0f};
    floatx4 acc1[4][4], acc2[4][4];
#pragma unroll
    for (int m = 0; m < 4; m++)
#pragma unroll
        for (int n = 0; n < 4; n++) { acc1[m][n] = zero4; acc2[m][n] = zero4; }

    for (int k0 = kbeg; k0 < kbeg + ksplit; k0 += 32) {
        __syncthreads();
#pragma unroll
        for (int p = 0; p < 2; p++) {
            int c = p * 256 + tid;
            int row = c >> 2;
            int col = (c & 3) * 8;
            stage_chunk(A + (size_t)(gm + row) * lda + k0 + col, Asm, c);
            stage_chunk(B1 + (size_t)(gn + row) * ldb + k0 + col, B1sm, c);
            if (DUAL)
                stage_chunk(B2 + (size_t)(gn + row) * ldb + k0 + col, B2sm, c);
        }
        __syncthreads();

        bhalf8 a[4];
#pragma unroll
        for (int m = 0; m < 4; m++)
            a[m] = *(const bhalf8*)(Asm + (wm + m * 16 + lrow) * 64 + kh * 16);
#pragma unroll
        for (int n = 0; n < 4; n++) {
            bhalf8 b = *(const bhalf8*)(B1sm + (wn + n * 16 + lrow) * 64 + kh * 16);
#pragma unroll
            for (int m = 0; m < 4; m++)
                acc1[m][n] = __builtin_amdgcn_mfma_f32_16x16x32_bf16(a[m], b, acc1[m][n], 0, 0, 0);
            if (DUAL) {
                bhalf8 b2 = *(const bhalf8*)(B2sm + (wn + n * 16 + lrow) * 64 + kh * 16);
#pragma unroll
                for (int m = 0; m < 4; m++)
                    acc2[m][n] = __builtin_amdgcn_mfma_f32_16x16x32_bf16(a[m], b2, acc2[m][n], 0, 0, 0);
            }
        }
    }

    // C/D layout col=lane&15, row=(lane>>4)*4+q  [m89-verified]
#pragma unroll
    for (int m = 0; m < 4; m++) {
#pragma unroll
        for (int n = 0; n < 4; n++) {
            int cc = gn + wn + n * 16 + lrow;
#pragma unroll
            for (int q = 0; q < 4; q++) {
                int r = gm + wm + m * 16 + kh * 4 + q;
                float v = acc1[m][n][q] * s1;
                if (DUAL) v += acc2[m][n][q] * s2;
                C[(size_t)r * ldc + cc] = v;
            }
        }
    }
}

// ---------------- split-K reduce: out[lr][d] = sum_p partial(p,lr,d) ----------------
// partial(p,lr,d) at P + lr*8192 + p*512 + d   (P = chunk + 4096: upper half of each row)
__global__ __launch_bounds__(256) void k_red(const float* __restrict__ P,
                                             float* __restrict__ outp, int SK) {
    int idx = blockIdx.x * 256 + threadIdx.x;
    int lr = idx >> 7;
    int d4 = (idx & 127) * 4;
    const float* base = P + (size_t)lr * 8192 + d4;
    float4 s = *(const float4*)base;
    for (int p = 1; p < SK; p++) {
        float4 v = *(const float4*)(base + (size_t)p * 512);
        s.x += v.x; s.y += v.y; s.z += v.z; s.w += v.w;
    }
    *(float4*)(outp + (size_t)lr * 512 + d4) = s;
}

// ---------------- normalize rows of F -> bf16 Xb ----------------
__global__ __launch_bounds__(128) void k_norm(const float* __restrict__ F,
                                              unsigned short* __restrict__ Xb) {
    int row = blockIdx.x, tid = threadIdx.x;
    float4 v = ((const float4*)(F + (size_t)row * D))[tid];
    float ss = v.x * v.x + v.y * v.y + v.z * v.z + v.w * v.w;
    ss = waveReduceSum(ss);
    __shared__ float s2[2];
    if ((tid & 63) == 0) s2[tid >> 6] = ss;
    __syncthreads();
    float inv = 1.0f / fmaxf(sqrtf(s2[0] + s2[1]), 1e-12f);
    union { unsigned short s[4]; int2 q; } u;
    u.s[0] = f2bf(v.x * inv); u.s[1] = f2bf(v.y * inv);
    u.s[2] = f2bf(v.z * inv); u.s[3] = f2bf(v.w * inv);
    *(int2*)(Xb + (size_t)row * D + tid * 4) = u.q;
}

// ---------------- transpose F (fp32 BxD) -> FbT (bf16 DxB) ----------------
__global__ __launch_bounds__(256) void k_transpose(const float* __restrict__ F,
                                                   unsigned short* __restrict__ FbT) {
    __shared__ float t[64][65];
    int r0 = blockIdx.x * 64, d0 = blockIdx.y * 64;
    int tid = threadIdx.x;
#pragma unroll
    for (int p = 0; p < 4; p++) {
        int idx = p * 256 + tid;
        int r = idx >> 4, c4 = (idx & 15) * 4;
        float4 v = *(const float4*)(F + (size_t)(r0 + r) * D + d0 + c4);
        t[r][c4 + 0] = v.x; t[r][c4 + 1] = v.y; t[r][c4 + 2] = v.z; t[r][c4 + 3] = v.w;
    }
    __syncthreads();
#pragma unroll
    for (int p = 0; p < 2; p++) {
        int idx = p * 256 + tid;
        int d = idx >> 3, rc = (idx & 7) * 8;
        union { unsigned short s[8]; int4 v; } u;
#pragma unroll
        for (int j = 0; j < 8; j++) u.s[j] = f2bf(t[rc + j][d]);
        *(int4*)(FbT + (size_t)(d0 + d) * B + r0 + rc) = u.v;
    }
}

// ---------------- G2 (fp32) -> bf16 Hb = G2/||G2 row|| ----------------
__global__ __launch_bounds__(128) void k_hnorm(const float* __restrict__ G,
                                               unsigned short* __restrict__ Hb) {
    int row = blockIdx.x, tid = threadIdx.x;
    float4 v = ((const float4*)(G + (size_t)row * D))[tid];
    float ss = v.x * v.x + v.y * v.y + v.z * v.z + v.w * v.w;
    ss = waveReduceSum(ss);
    __shared__ float s2[2];
    if ((tid & 63) == 0) s2[tid >> 6] = ss;
    __syncthreads();
    float inv = 1.0f / fmaxf(sqrtf(s2[0] + s2[1]), 1e-12f);
    union { unsigned short s[4]; int2 q; } u;
    u.s[0] = f2bf(v.x * inv); u.s[1] = f2bf(v.y * inv);
    u.s[2] = f2bf(v.z * inv); u.s[3] = f2bf(v.w * inv);
    *(int2*)(Hb + (size_t)row * D + tid * 4) = u.q;
}

// ---------------- top-K via binary-search threshold on monotonic uint keys ----------
// Matches lax.top_k order: value desc, then index asc (packed u64 keys).
__global__ __launch_bounds__(256) void k_topk2(const float* __restrict__ S,
                                               int* __restrict__ topk, int r0) {
    __shared__ int cslot[2][4];
    __shared__ int islot[4];
    __shared__ unsigned long long buf[128];
    __shared__ int outIdx[KNN];
    __shared__ int ccount;
    int li = blockIdx.x, tid = threadIdx.x;
    int i = r0 + li;
    const float* rp = S + (size_t)li * B;

    // load 32 keys/thread; col = j8*1024 + tid*4 + q
    unsigned int key[32];
#pragma unroll
    for (int j8 = 0; j8 < 8; j8++) {
        float4 v = *(const float4*)(rp + j8 * 1024 + tid * 4);
        float fv[4] = {v.x, v.y, v.z, v.w};
#pragma unroll
        for (int q = 0; q < 4; q++) {
            int col = j8 * 1024 + tid * 4 + q;
            unsigned int u = __builtin_bit_cast(unsigned int, fv[q]);
            unsigned int k = u ^ ((u & 0x80000000u) ? 0xFFFFFFFFu : 0x80000000u);
            key[j8 * 4 + q] = (col == i) ? 0u : k;
        }
    }

    // binary search for a threshold with 32 <= count(key > T) <= 128
    unsigned int lo = 0u, hi = 0xFFFFFFFFu;
    unsigned int T = 0;
    bool found = false;
    for (int it = 0; it < 33; ++it) {
        unsigned int mid = lo + ((hi - lo) >> 1);
        if (mid == lo) break;
        int c = 0;
#pragma unroll
        for (int j = 0; j < 32; j++) c += (key[j] > mid) ? 1 : 0;
#pragma unroll
        for (int off = 32; off; off >>= 1) c += __shfl_down(c, off);
        if ((tid & 63) == 0) cslot[it & 1][tid >> 6] = c;
        __syncthreads();
        int tot = cslot[it & 1][0] + cslot[it & 1][1] + cslot[it & 1][2] + cslot[it & 1][3];
        if (tot >= KNN && tot <= 128) { T = mid; found = true; break; }
        if (tot < KNN) hi = mid; else lo = mid;
    }
    if (!found) T = hi;  // exact-tie slow path: candidates are keys > hi, rest == hi

    if (tid == 0) ccount = 0;
    __syncthreads();
#pragma unroll
    for (int j8 = 0; j8 < 8; j8++) {
#pragma unroll
        for (int q = 0; q < 4; q++) {
            int j = j8 * 4 + q;
            if (key[j] > T) {
                int p = atomicAdd(&ccount, 1);
                if (p < 128) {
                    int col = j8 * 1024 + tid * 4 + q;
                    buf[p] = ((unsigned long long)key[j] << 13) |
                             (unsigned long long)(8191 - col);
                }
            }
        }
    }
    __syncthreads();
    int C = ccount < 128 ? ccount : 128;

    // wave 0: iterative argmax over candidates (<=128)
    if (tid < 64) {
        unsigned long long p0 = (tid < C) ? buf[tid] : 0ull;
        unsigned long long p1 = (tid + 64 < C) ? buf[tid + 64] : 0ull;
        for (int it = 0; it < KNN; ++it) {
            unsigned long long m = (p0 > p1) ? p0 : p1;
#pragma unroll
            for (int off = 32; off; off >>= 1) {
                unsigned long long o = __shfl_down(m, off);
                m = (o > m) ? o : m;
            }
            m = __shfl(m, 0);
            if (tid == 0 && m != 0ull) outIdx[it] = 8191 - (int)(m & 0x1FFFull);
            if (p0 == m) p0 = 0ull; else if (p1 == m) p1 = 0ull;
        }
    }
    __syncthreads();

    if (C < KNN) {
        // fill remaining with smallest-index ties (key == T); effectively never hit
        int last = -1;
        for (int it = C; it < KNN; ++it) {
            int best = 0x7fffffff;
#pragma unroll
            for (int j8 = 0; j8 < 8; j8++) {
#pragma unroll
                for (int q = 0; q < 4; q++) {
                    int j = j8 * 4 + q;
                    int col = j8 * 1024 + tid * 4 + q;
                    if (key[j] == T && col > last && col < best) best = col;
                }
            }
#pragma unroll
            for (int off = 32; off; off >>= 1) {
                int o = __shfl_down(best, off);
                best = (o < best) ? o : best;
            }
            if ((tid & 63) == 0) islot[tid >> 6] = best;
            __syncthreads();
            best = min(min(islot[0], islot[1]), min(islot[2], islot[3]));
            if (tid == 0) outIdx[it] = best;
            last = best;
            __syncthreads();
        }
    }
    __syncthreads();
    if (tid < KNN) topk[(size_t)i * KNN + tid] = outIdx[tid];
}

// ---------------- graph build ----------------
__global__ void k_zero2(int* __restrict__ a, int* __restrict__ b) {
    int i = blockIdx.x * 256 + threadIdx.x;
    a[i] = 0;
    b[i] = 0;
}

__global__ void k_count(const int* __restrict__ topk, int* __restrict__ indeg) {
    int e = blockIdx.x * 256 + threadIdx.x;
    atomicAdd(&indeg[topk[e]], 1);
}

__global__ __launch_bounds__(1024) void k_scan(const int* __restrict__ indeg,
                                               int* __restrict__ roff) {
    __shared__ int sums[1024];
    int tid = threadIdx.x;
    int base = tid * 8;
    int loc[8];
    int s = 0;
#pragma unroll
    for (int j = 0; j < 8; j++) { loc[j] = s; s += indeg[base + j]; }
    sums[tid] = s;
    __syncthreads();
    for (int off = 1; off < 1024; off <<= 1) {
        int v = (tid >= off) ? sums[tid - off] : 0;
        __syncthreads();
        sums[tid] += v;
        __syncthreads();
    }
    int prev = (tid > 0) ? sums[tid - 1] : 0;
#pragma unroll
    for (int j = 0; j < 8; j++) roff[base + j] = prev + loc[j];
    if (tid == 1023) roff[B] = sums[1023];
}

__global__ void k_dinv(const int* __restrict__ indeg, float* __restrict__ dinv) {
    int i = blockIdx.x * 256 + threadIdx.x;
    float dg = (float)(KNN + indeg[i]);
    dinv[i] = fminf(1.0f / sqrtf(dg), 1e6f);
}

__global__ void k_fill(const int* __restrict__ topk, const int* __restrict__ roff,
                       int* __restrict__ fill, int* __restrict__ ridx) {
    int e = blockIdx.x * 256 + threadIdx.x;
    int dst = topk[e];
    int src = e >> 5;
    int pos = atomicAdd(&fill[dst], 1);
    ridx[roff[dst] + pos] = src;
}

// ---------------- normalized SpMM ----------------
__global__ __launch_bounds__(128) void k_spmm(const float* __restrict__ Vin,
                                              float* __restrict__ Vout,
                                              const int* __restrict__ topk,
                                              const int* __restrict__ roff,
                                              const int* __restrict__ ridx,
                                              const float* __restrict__ dinv) {
    int i = blockIdx.x, tid = threadIdx.x;
    float4 acc; acc.x = acc.y = acc.z = acc.w = 0.0f;
    for (int k = 0; k < KNN; k++) {
        int n = topk[(size_t)i * KNN + k];
        float w = dinv[n];
        float4 v = *(const float4*)(Vin + (size_t)n * D + tid * 4);
        acc.x += w * v.x; acc.y += w * v.y; acc.z += w * v.z; acc.w += w * v.w;
    }
    int s = roff[i], e = roff[i + 1];
    for (int t = s; t < e; t++) {
        int j = ridx[t];
        float w = dinv[j];
        float4 v = *(const float4*)(Vin + (size_t)j * D + tid * 4);
        acc.x += w * v.x; acc.y += w * v.y; acc.z += w * v.z; acc.w += w * v.w;
    }
    float wi = dinv[i];
    float4 o; o.x = wi * acc.x; o.y = wi * acc.y; o.z = wi * acc.z; o.w = wi * acc.w;
    *(float4*)(Vout + (size_t)i * D + tid * 4) = o;
}

// ------- row softmax of prescaled logits; writes bf16 weights in place ----------
__global__ __launch_bounds__(256) void k_softmax(float* __restrict__ chunk) {
    __shared__ float row[B];
    __shared__ float red[4];
    int li = blockIdx.x, tid = threadIdx.x;
    float* rp = chunk + (size_t)li * B;
    float mx = -FLT_MAX;
    for (int t = tid; t < B / 4; t += 256) {
        float4 v = *(const float4*)(rp + t * 4);
        *(float4*)&row[t * 4] = v;
        mx = fmaxf(mx, fmaxf(fmaxf(v.x, v.y), fmaxf(v.z, v.w)));
    }
#pragma unroll
    for (int off = 32; off; off >>= 1) mx = fmaxf(mx, __shfl_down(mx, off));
    if ((tid & 63) == 0) red[tid >> 6] = mx;
    __syncthreads();
    mx = fmaxf(fmaxf(red[0], red[1]), fmaxf(red[2], red[3]));
    __syncthreads();
    float sum = 0.0f;
    for (int t = tid; t < B; t += 256) {
        float e = __expf(row[t] - mx);
        row[t] = e;
        sum += e;
    }
    sum = waveReduceSum(sum);
    if ((tid & 63) == 0) red[tid >> 6] = sum;
    __syncthreads();
    sum = red[0] + red[1] + red[2] + red[3];
    float sc = 1.0f / sum;
    unsigned short* wp = (unsigned short*)rp;
    for (int t = tid; t < B / 8; t += 256) {
        union { unsigned short s[8]; int4 v; } u;
#pragma unroll
        for (int j = 0; j < 8; j++) u.s[j] = f2bf(row[t * 8 + j] * sc);
        *(int4*)(wp + t * 8) = u.v;
    }
}

extern "C" void kernel_launch(void* const* d_in, const int* in_sizes, int n_in,
                              void* d_out, int out_size, void* d_ws, size_t ws_size,
                              hipStream_t stream) {
    (void)in_sizes; (void)n_in; (void)out_size;
    const float* F = (const float*)d_in[0];
    float* out = (float*)d_out;

    char* ws = (char*)d_ws;
    size_t off = 0;
    auto take = [&](size_t bytes) -> void* {
        void* p = ws + off;
        off += (bytes + 255) & ~(size_t)255;
        return p;
    };
    float* dinv = (float*)take((size_t)B * 4);
    int* topk = (int*)take((size_t)B * KNN * 4);
    int* indeg = (int*)take((size_t)B * 4);
    int* roff = (int*)take((size_t)(B + 1) * 4);
    int* rfill = (int*)take((size_t)B * 4);
    int* ridx = (int*)take((size_t)B * KNN * 4);
    float* G2 = (float*)take((size_t)B * D * 4);
    unsigned short* Xb = (unsigned short*)take((size_t)B * D * 2);
    unsigned short* Hb = (unsigned short*)take((size_t)B * D * 2);
    unsigned short* FbT = (unsigned short*)take((size_t)D * B * 2);
    size_t fixed = off;

    int R = 2048;
    if (ws_size > 0) {
        while (R > 128 && fixed + (size_t)R * B * 4 > ws_size) R >>= 1;
    } else {
        R = 1024;
    }
    float* chunk = (float*)(ws + fixed);
    float* G1 = out;  // d_out doubles as scratch for first SpMM result

    // split-K config for final GEMM: grid (D/128)*(R/128)*SK -> aim 256 blocks
    int SK = 8192 / R;
    if (SK > 8) SK = 8;
    int ksplit = B / SK;

    // 1. Xb = bf16 normalized F; FbT = bf16 F^T
    k_norm<<<B, 128, 0, stream>>>(F, Xb);
    dim3 gt(B / 64, D / 64);
    k_transpose<<<gt, 256, 0, stream>>>(F, FbT);

    // 2. chunked: sim = Xb Xb^T + top-K
    for (int r0 = 0; r0 < B; r0 += R) {
        dim3 g(B / 128, R / 128);
        k_mfma_nt<false><<<g, 256, 0, stream>>>(Xb + (size_t)r0 * D, D, Xb, nullptr, D,
                                                chunk, B, 0, D, 1.0f, 0.0f);
        k_topk2<<<R, 256, 0, stream>>>(chunk, topk, r0);
    }

    // 3. graph build
    k_zero2<<<B / 256, 256, 0, stream>>>(indeg, rfill);
    k_count<<<B * KNN / 256, 256, 0, stream>>>(topk, indeg);
    k_scan<<<1, 1024, 0, stream>>>(indeg, roff);
    k_dinv<<<B / 256, 256, 0, stream>>>(indeg, dinv);
    k_fill<<<B * KNN / 256, 256, 0, stream>>>(topk, roff, rfill, ridx);

    // 4. geodesic = A_hat @ (A_hat @ F); Hb = bf16 row-normalized geodesic
    k_spmm<<<B, 128, 0, stream>>>(F, G1, topk, roff, ridx, dinv);
    k_spmm<<<B, 128, 0, stream>>>(G1, G2, topk, roff, ridx, dinv);
    k_hnorm<<<B, 128, 0, stream>>>(G2, Hb);

    // 5. chunked: logits = 10*sim + cos -> softmax (bf16 in place)
    //    -> split-K GEMM into per-row free space -> reduce into out
    for (int r0 = 0; r0 < B; r0 += R) {
        dim3 g(B / 128, R / 128);
        k_mfma_nt<true><<<g, 256, 0, stream>>>(Xb + (size_t)r0 * D, D, Xb, Hb, D,
                                               chunk, B, 0, D, 10.0f, 1.0f);
        k_softmax<<<R, 256, 0, stream>>>(chunk);
        // final GEMM: W (bf16, lda=2B u16 per row) x FbT -> partials in row upper halves
        // ldc = B floats (row stride), zstride = D floats (per split-K partial)
        float* part = chunk + 4096;  // 16KB into each 32KB row
        dim3 gf(D / 128, R / 128, SK);
        k_mfma_nt<false><<<gf, 256, 0, stream>>>((const unsigned short*)chunk, 2 * B, FbT,
                                                 nullptr, B, part, B, D, ksplit,
                                                 1.0f, 0.0f);
        k_red<<<R / 2, 256, 0, stream>>>(part, out + (size_t)r0 * D, SK);
    }
}

// Round 6
// 865.427 us; speedup vs baseline: 6.2001x; 1.1973x over previous
//
#include <hip/hip_runtime.h>
#include <hip/hip_bf16.h>
#include <float.h>
#include <math.h>

constexpr int B = 8192;
constexpr int D = 512;
constexpr int KNN = 32;

typedef __attribute__((ext_vector_type(8))) short bhalf8;
typedef __attribute__((ext_vector_type(4))) float floatx4;

#if defined(__has_builtin)
#if __has_builtin(__builtin_amdgcn_global_load_lds)
#define HAS_GLD 1
#else
#define HAS_GLD 0
#endif
#else
#define HAS_GLD 0
#endif

__device__ __forceinline__ unsigned short f2bf(float f) {
    __hip_bfloat16 h = __float2bfloat16(f);
    return __builtin_bit_cast(unsigned short, h);
}

__device__ __forceinline__ float bf2f(unsigned short u) {
    unsigned int x = ((unsigned int)u) << 16;
    return __builtin_bit_cast(float, x);
}

__device__ __forceinline__ float waveReduceSum(float v) {
#pragma unroll
    for (int off = 32; off; off >>= 1) v += __shfl_down(v, off);
    return v;
}

// stage one 16B chunk of a 128x32-bf16 tile (linear LDS, 64B rows).
__device__ __forceinline__ void stage_chunk(const unsigned short* __restrict__ g,
                                            char* __restrict__ lds_tile, int c) {
#if HAS_GLD
    char* wavebase = lds_tile + (size_t)(c & ~63) * 16;
    __builtin_amdgcn_global_load_lds((const __attribute__((address_space(1))) void*)g,
                                     (__attribute__((address_space(3))) void*)wavebase,
                                     16, 0, 0);
#else
    *(int4*)(lds_tile + (size_t)c * 16) = *(const int4*)g;
#endif
}

// ---------------- bf16 MFMA GEMM, NT form ----------------
// C[m][n] = A[m][:].B1[n][:].  128x128 tile, BK=32, 4 waves 2x2.
// Split-K via blockIdx.z: K-range [z*ksplit, (z+1)*ksplit), C += z*zstride.
// lda/ldb in u16 elements; ldc/zstride in floats.
__global__ __launch_bounds__(256, 2) void k_mfma_nt(
    const unsigned short* __restrict__ A, int lda,
    const unsigned short* __restrict__ B1, int ldb,
    float* __restrict__ C, int ldc, int zstride, int ksplit) {
    __shared__ __align__(16) char smem[2 * 8192];
    char* Asm = smem;
    char* B1sm = smem + 8192;

    int tid = threadIdx.x;
    int lane = tid & 63;
    int wid = tid >> 6;
    int wm = (wid >> 1) * 64, wn = (wid & 1) * 64;
    int lrow = lane & 15;
    int kh = lane >> 4;
    int gm = blockIdx.y * 128, gn = blockIdx.x * 128;
    int kbeg = blockIdx.z * ksplit;
    C += (size_t)blockIdx.z * zstride;

    floatx4 zero4 = {0.0f, 0.0f, 0.0f, 0.0f};
    floatx4 acc1[4][4];
#pragma unroll
    for (int m = 0; m < 4; m++)
#pragma unroll
        for (int n = 0; n < 4; n++) acc1[m][n] = zero4;

    for (int k0 = kbeg; k0 < kbeg + ksplit; k0 += 32) {
        __syncthreads();
#pragma unroll
        for (int p = 0; p < 2; p++) {
            int c = p * 256 + tid;
            int row = c >> 2;
            int col = (c & 3) * 8;
            stage_chunk(A + (size_t)(gm + row) * lda + k0 + col, Asm, c);
            stage_chunk(B1 + (size_t)(gn + row) * ldb + k0 + col, B1sm, c);
        }
        __syncthreads();

        bhalf8 a[4];
#pragma unroll
        for (int m = 0; m < 4; m++)
            a[m] = *(const bhalf8*)(Asm + (wm + m * 16 + lrow) * 64 + kh * 16);
#pragma unroll
        for (int n = 0; n < 4; n++) {
            bhalf8 b = *(const bhalf8*)(B1sm + (wn + n * 16 + lrow) * 64 + kh * 16);
#pragma unroll
            for (int m = 0; m < 4; m++)
                acc1[m][n] = __builtin_amdgcn_mfma_f32_16x16x32_bf16(a[m], b, acc1[m][n], 0, 0, 0);
        }
    }

    // C/D layout col=lane&15, row=(lane>>4)*4+q  [m89-verified]
#pragma unroll
    for (int m = 0; m < 4; m++) {
#pragma unroll
        for (int n = 0; n < 4; n++) {
            int cc = gn + wn + n * 16 + lrow;
#pragma unroll
            for (int q = 0; q < 4; q++) {
                int r = gm + wm + m * 16 + kh * 4 + q;
                C[(size_t)r * ldc + cc] = acc1[m][n][q];
            }
        }
    }
}

// ---------------- split-K reduce: out[lr][d] = sum_p partial(p,lr,d) ----------------
// partial(p,lr,d) at P + lr*8192 + p*512 + d   (P = chunk + 4096: upper half of each row)
__global__ __launch_bounds__(256) void k_red(const float* __restrict__ P,
                                             float* __restrict__ outp, int SK) {
    int idx = blockIdx.x * 256 + threadIdx.x;
    int lr = idx >> 7;
    int d4 = (idx & 127) * 4;
    const float* base = P + (size_t)lr * 8192 + d4;
    float4 s = *(const float4*)base;
    for (int p = 1; p < SK; p++) {
        float4 v = *(const float4*)(base + (size_t)p * 512);
        s.x += v.x; s.y += v.y; s.z += v.z; s.w += v.w;
    }
    *(float4*)(outp + (size_t)lr * 512 + d4) = s;
}

// ------- normalize rows of F -> bf16 Xb (normalized), bf16 Fb (raw), invnf -------
__global__ __launch_bounds__(128) void k_norm(const float* __restrict__ F,
                                              unsigned short* __restrict__ Xb,
                                              unsigned short* __restrict__ Fb,
                                              float* __restrict__ invnf) {
    int row = blockIdx.x, tid = threadIdx.x;
    float4 v = ((const float4*)(F + (size_t)row * D))[tid];
    float ss = v.x * v.x + v.y * v.y + v.z * v.z + v.w * v.w;
    ss = waveReduceSum(ss);
    __shared__ float s2[2];
    if ((tid & 63) == 0) s2[tid >> 6] = ss;
    __syncthreads();
    float inv = 1.0f / fmaxf(sqrtf(s2[0] + s2[1]), 1e-12f);
    if (tid == 0) invnf[row] = inv;
    union { unsigned short s[4]; int2 q; } ux, uf;
    ux.s[0] = f2bf(v.x * inv); ux.s[1] = f2bf(v.y * inv);
    ux.s[2] = f2bf(v.z * inv); ux.s[3] = f2bf(v.w * inv);
    uf.s[0] = f2bf(v.x); uf.s[1] = f2bf(v.y);
    uf.s[2] = f2bf(v.z); uf.s[3] = f2bf(v.w);
    *(int2*)(Xb + (size_t)row * D + tid * 4) = ux.q;
    *(int2*)(Fb + (size_t)row * D + tid * 4) = uf.q;
}

// ---------------- transpose F (fp32 BxD) -> FbT (bf16 DxB) ----------------
__global__ __launch_bounds__(256) void k_transpose(const float* __restrict__ F,
                                                   unsigned short* __restrict__ FbT) {
    __shared__ float t[64][65];
    int r0 = blockIdx.x * 64, d0 = blockIdx.y * 64;
    int tid = threadIdx.x;
#pragma unroll
    for (int p = 0; p < 4; p++) {
        int idx = p * 256 + tid;
        int r = idx >> 4, c4 = (idx & 15) * 4;
        float4 v = *(const float4*)(F + (size_t)(r0 + r) * D + d0 + c4);
        t[r][c4 + 0] = v.x; t[r][c4 + 1] = v.y; t[r][c4 + 2] = v.z; t[r][c4 + 3] = v.w;
    }
    __syncthreads();
#pragma unroll
    for (int p = 0; p < 2; p++) {
        int idx = p * 256 + tid;
        int d = idx >> 3, rc = (idx & 7) * 8;
        union { unsigned short s[8]; int4 v; } u;
#pragma unroll
        for (int j = 0; j < 8; j++) u.s[j] = f2bf(t[rc + j][d]);
        *(int4*)(FbT + (size_t)(d0 + d) * B + r0 + rc) = u.v;
    }
}

// ---------------- top-K via binary-search threshold on monotonic uint keys ----------
__global__ __launch_bounds__(256) void k_topk2(const float* __restrict__ S,
                                               int* __restrict__ topk, int r0) {
    __shared__ int cslot[2][4];
    __shared__ int islot[4];
    __shared__ unsigned long long buf[128];
    __shared__ int outIdx[KNN];
    __shared__ int ccount;
    int li = blockIdx.x, tid = threadIdx.x;
    int i = r0 + li;
    const float* rp = S + (size_t)li * B;

    unsigned int key[32];
#pragma unroll
    for (int j8 = 0; j8 < 8; j8++) {
        float4 v = *(const float4*)(rp + j8 * 1024 + tid * 4);
        float fv[4] = {v.x, v.y, v.z, v.w};
#pragma unroll
        for (int q = 0; q < 4; q++) {
            int col = j8 * 1024 + tid * 4 + q;
            unsigned int u = __builtin_bit_cast(unsigned int, fv[q]);
            unsigned int k = u ^ ((u & 0x80000000u) ? 0xFFFFFFFFu : 0x80000000u);
            key[j8 * 4 + q] = (col == i) ? 0u : k;
        }
    }

    unsigned int lo = 0u, hi = 0xFFFFFFFFu;
    unsigned int T = 0;
    bool found = false;
    for (int it = 0; it < 33; ++it) {
        unsigned int mid = lo + ((hi - lo) >> 1);
        if (mid == lo) break;
        int c = 0;
#pragma unroll
        for (int j = 0; j < 32; j++) c += (key[j] > mid) ? 1 : 0;
#pragma unroll
        for (int off = 32; off; off >>= 1) c += __shfl_down(c, off);
        if ((tid & 63) == 0) cslot[it & 1][tid >> 6] = c;
        __syncthreads();
        int tot = cslot[it & 1][0] + cslot[it & 1][1] + cslot[it & 1][2] + cslot[it & 1][3];
        if (tot >= KNN && tot <= 128) { T = mid; found = true; break; }
        if (tot < KNN) hi = mid; else lo = mid;
    }
    if (!found) T = hi;

    if (tid == 0) ccount = 0;
    __syncthreads();
#pragma unroll
    for (int j8 = 0; j8 < 8; j8++) {
#pragma unroll
        for (int q = 0; q < 4; q++) {
            int j = j8 * 4 + q;
            if (key[j] > T) {
                int p = atomicAdd(&ccount, 1);
                if (p < 128) {
                    int col = j8 * 1024 + tid * 4 + q;
                    buf[p] = ((unsigned long long)key[j] << 13) |
                             (unsigned long long)(8191 - col);
                }
            }
        }
    }
    __syncthreads();
    int C = ccount < 128 ? ccount : 128;

    if (tid < 64) {
        unsigned long long p0 = (tid < C) ? buf[tid] : 0ull;
        unsigned long long p1 = (tid + 64 < C) ? buf[tid + 64] : 0ull;
        for (int it = 0; it < KNN; ++it) {
            unsigned long long m = (p0 > p1) ? p0 : p1;
#pragma unroll
            for (int off = 32; off; off >>= 1) {
                unsigned long long o = __shfl_down(m, off);
                m = (o > m) ? o : m;
            }
            m = __shfl(m, 0);
            if (tid == 0 && m != 0ull) outIdx[it] = 8191 - (int)(m & 0x1FFFull);
            if (p0 == m) p0 = 0ull; else if (p1 == m) p1 = 0ull;
        }
    }
    __syncthreads();

    if (C < KNN) {
        int last = -1;
        for (int it = C; it < KNN; ++it) {
            int best = 0x7fffffff;
#pragma unroll
            for (int j8 = 0; j8 < 8; j8++) {
#pragma unroll
                for (int q = 0; q < 4; q++) {
                    int j = j8 * 4 + q;
                    int col = j8 * 1024 + tid * 4 + q;
                    if (key[j] == T && col > last && col < best) best = col;
                }
            }
#pragma unroll
            for (int off = 32; off; off >>= 1) {
                int o = __shfl_down(best, off);
                best = (o < best) ? o : best;
            }
            if ((tid & 63) == 0) islot[tid >> 6] = best;
            __syncthreads();
            best = min(min(islot[0], islot[1]), min(islot[2], islot[3]));
            if (tid == 0) outIdx[it] = best;
            last = best;
            __syncthreads();
        }
    }
    __syncthreads();
    if (tid < KNN) topk[(size_t)i * KNN + tid] = outIdx[tid];
}

// ---------------- graph build ----------------
__global__ void k_zero2(int* __restrict__ a, int* __restrict__ b) {
    int i = blockIdx.x * 256 + threadIdx.x;
    a[i] = 0;
    b[i] = 0;
}

__global__ void k_count(const int* __restrict__ topk, int* __restrict__ indeg) {
    int e = blockIdx.x * 256 + threadIdx.x;
    atomicAdd(&indeg[topk[e]], 1);
}

__global__ __launch_bounds__(1024) void k_scan(const int* __restrict__ indeg,
                                               int* __restrict__ roff) {
    __shared__ int sums[1024];
    int tid = threadIdx.x;
    int base = tid * 8;
    int loc[8];
    int s = 0;
#pragma unroll
    for (int j = 0; j < 8; j++) { loc[j] = s; s += indeg[base + j]; }
    sums[tid] = s;
    __syncthreads();
    for (int off = 1; off < 1024; off <<= 1) {
        int v = (tid >= off) ? sums[tid - off] : 0;
        __syncthreads();
        sums[tid] += v;
        __syncthreads();
    }
    int prev = (tid > 0) ? sums[tid - 1] : 0;
#pragma unroll
    for (int j = 0; j < 8; j++) roff[base + j] = prev + loc[j];
    if (tid == 1023) roff[B] = sums[1023];
}

__global__ void k_dinv(const int* __restrict__ indeg, float* __restrict__ dinv) {
    int i = blockIdx.x * 256 + threadIdx.x;
    float dg = (float)(KNN + indeg[i]);
    dinv[i] = fminf(1.0f / sqrtf(dg), 1e6f);
}

__global__ void k_fill(const int* __restrict__ topk, const int* __restrict__ roff,
                       int* __restrict__ fill, int* __restrict__ ridx) {
    int e = blockIdx.x * 256 + threadIdx.x;
    int dst = topk[e];
    int src = e >> 5;
    int pos = atomicAdd(&fill[dst], 1);
    ridx[roff[dst] + pos] = src;
}

// ------- SpMM 1: G1b (bf16) = A_hat @ Fb, gather in bf16 -------
__global__ __launch_bounds__(128) void k_spmm1(const unsigned short* __restrict__ Fb,
                                               unsigned short* __restrict__ G1b,
                                               const int* __restrict__ topk,
                                               const int* __restrict__ roff,
                                               const int* __restrict__ ridx,
                                               const float* __restrict__ dinv) {
    int i = blockIdx.x, tid = threadIdx.x;
    float a0 = 0, a1 = 0, a2 = 0, a3 = 0;
    const int* ti = topk + (size_t)i * KNN;
#pragma unroll 4
    for (int k = 0; k < KNN; k++) {
        int n = ti[k];
        float w = dinv[n];
        int2 p = *(const int2*)(Fb + (size_t)n * D + tid * 4);
        const unsigned short* us = (const unsigned short*)&p;
        a0 += w * bf2f(us[0]); a1 += w * bf2f(us[1]);
        a2 += w * bf2f(us[2]); a3 += w * bf2f(us[3]);
    }
    int s = roff[i], e = roff[i + 1];
    for (int t = s; t < e; t++) {
        int j = ridx[t];
        float w = dinv[j];
        int2 p = *(const int2*)(Fb + (size_t)j * D + tid * 4);
        const unsigned short* us = (const unsigned short*)&p;
        a0 += w * bf2f(us[0]); a1 += w * bf2f(us[1]);
        a2 += w * bf2f(us[2]); a3 += w * bf2f(us[3]);
    }
    float wi = dinv[i];
    union { unsigned short s4[4]; int2 q; } u;
    u.s4[0] = f2bf(wi * a0); u.s4[1] = f2bf(wi * a1);
    u.s4[2] = f2bf(wi * a2); u.s4[3] = f2bf(wi * a3);
    *(int2*)(G1b + (size_t)i * D + tid * 4) = u.q;
}

// ------- SpMM 2 fused with Yb build:
//   g = (A_hat @ G1b)_row i ;  Yb_i = bf16(10 * F_i * invnf_i + g * (1/max(||g||,1e-12)))
__global__ __launch_bounds__(128) void k_spmm2y(const unsigned short* __restrict__ G1b,
                                                const float* __restrict__ F,
                                                const float* __restrict__ invnf,
                                                unsigned short* __restrict__ Yb,
                                                const int* __restrict__ topk,
                                                const int* __restrict__ roff,
                                                const int* __restrict__ ridx,
                                                const float* __restrict__ dinv) {
    int i = blockIdx.x, tid = threadIdx.x;
    float a0 = 0, a1 = 0, a2 = 0, a3 = 0;
    const int* ti = topk + (size_t)i * KNN;
#pragma unroll 4
    for (int k = 0; k < KNN; k++) {
        int n = ti[k];
        float w = dinv[n];
        int2 p = *(const int2*)(G1b + (size_t)n * D + tid * 4);
        const unsigned short* us = (const unsigned short*)&p;
        a0 += w * bf2f(us[0]); a1 += w * bf2f(us[1]);
        a2 += w * bf2f(us[2]); a3 += w * bf2f(us[3]);
    }
    int s = roff[i], e = roff[i + 1];
    for (int t = s; t < e; t++) {
        int j = ridx[t];
        float w = dinv[j];
        int2 p = *(const int2*)(G1b + (size_t)j * D + tid * 4);
        const unsigned short* us = (const unsigned short*)&p;
        a0 += w * bf2f(us[0]); a1 += w * bf2f(us[1]);
        a2 += w * bf2f(us[2]); a3 += w * bf2f(us[3]);
    }
    float wi = dinv[i];
    float g0 = wi * a0, g1 = wi * a1, g2 = wi * a2, g3 = wi * a3;

    float ss = g0 * g0 + g1 * g1 + g2 * g2 + g3 * g3;
    ss = waveReduceSum(ss);
    __shared__ float s2[2];
    if ((tid & 63) == 0) s2[tid >> 6] = ss;
    __syncthreads();
    float invng = 1.0f / fmaxf(sqrtf(s2[0] + s2[1]), 1e-12f);

    float4 f = ((const float4*)(F + (size_t)i * D))[tid];
    float inf_ = 10.0f * invnf[i];
    union { unsigned short s4[4]; int2 q; } u;
    u.s4[0] = f2bf(f.x * inf_ + g0 * invng);
    u.s4[1] = f2bf(f.y * inf_ + g1 * invng);
    u.s4[2] = f2bf(f.z * inf_ + g2 * invng);
    u.s4[3] = f2bf(f.w * inf_ + g3 * invng);
    *(int2*)(Yb + (size_t)i * D + tid * 4) = u.q;
}

// ------- row softmax of logits; writes bf16 weights in place ----------
__global__ __launch_bounds__(256) void k_softmax(float* __restrict__ chunk) {
    __shared__ float row[B];
    __shared__ float red[4];
    int li = blockIdx.x, tid = threadIdx.x;
    float* rp = chunk + (size_t)li * B;
    float mx = -FLT_MAX;
    for (int t = tid; t < B / 4; t += 256) {
        float4 v = *(const float4*)(rp + t * 4);
        *(float4*)&row[t * 4] = v;
        mx = fmaxf(mx, fmaxf(fmaxf(v.x, v.y), fmaxf(v.z, v.w)));
    }
#pragma unroll
    for (int off = 32; off; off >>= 1) mx = fmaxf(mx, __shfl_down(mx, off));
    if ((tid & 63) == 0) red[tid >> 6] = mx;
    __syncthreads();
    mx = fmaxf(fmaxf(red[0], red[1]), fmaxf(red[2], red[3]));
    __syncthreads();
    float sum = 0.0f;
    for (int t = tid; t < B; t += 256) {
        float e = __expf(row[t] - mx);
        row[t] = e;
        sum += e;
    }
    sum = waveReduceSum(sum);
    if ((tid & 63) == 0) red[tid >> 6] = sum;
    __syncthreads();
    sum = red[0] + red[1] + red[2] + red[3];
    float sc = 1.0f / sum;
    unsigned short* wp = (unsigned short*)rp;
    for (int t = tid; t < B / 8; t += 256) {
        union { unsigned short s[8]; int4 v; } u;
#pragma unroll
        for (int j = 0; j < 8; j++) u.s[j] = f2bf(row[t * 8 + j] * sc);
        *(int4*)(wp + t * 8) = u.v;
    }
}

extern "C" void kernel_launch(void* const* d_in, const int* in_sizes, int n_in,
                              void* d_out, int out_size, void* d_ws, size_t ws_size,
                              hipStream_t stream) {
    (void)in_sizes; (void)n_in; (void)out_size;
    const float* F = (const float*)d_in[0];
    float* out = (float*)d_out;

    char* ws = (char*)d_ws;
    size_t off = 0;
    auto take = [&](size_t bytes) -> void* {
        void* p = ws + off;
        off += (bytes + 255) & ~(size_t)255;
        return p;
    };
    float* invnf = (float*)take((size_t)B * 4);
    float* dinv = (float*)take((size_t)B * 4);
    int* topk = (int*)take((size_t)B * KNN * 4);
    int* indeg = (int*)take((size_t)B * 4);
    int* roff = (int*)take((size_t)(B + 1) * 4);
    int* rfill = (int*)take((size_t)B * 4);
    int* ridx = (int*)take((size_t)B * KNN * 4);
    unsigned short* Xb = (unsigned short*)take((size_t)B * D * 2);
    unsigned short* Fb = (unsigned short*)take((size_t)B * D * 2);
    unsigned short* Yb = (unsigned short*)take((size_t)B * D * 2);
    unsigned short* FbT = (unsigned short*)take((size_t)D * B * 2);
    size_t fixed = off;

    int R = 2048;
    if (ws_size > 0) {
        while (R > 128 && fixed + (size_t)R * B * 4 > ws_size) R >>= 1;
    } else {
        R = 1024;
    }
    float* chunk = (float*)(ws + fixed);
    unsigned short* G1b = (unsigned short*)out;  // d_out as scratch for SpMM-1 (8 MB of 16)

    int SK = 8192 / R;
    if (SK > 8) SK = 8;
    int ksplit = B / SK;

    // 1. Xb / Fb / invnf; FbT = bf16 F^T
    k_norm<<<B, 128, 0, stream>>>(F, Xb, Fb, invnf);
    dim3 gt(B / 64, D / 64);
    k_transpose<<<gt, 256, 0, stream>>>(F, FbT);

    // 2. chunked: sim = Xb Xb^T + top-K
    for (int r0 = 0; r0 < B; r0 += R) {
        dim3 g(B / 128, R / 128);
        k_mfma_nt<<<g, 256, 0, stream>>>(Xb + (size_t)r0 * D, D, Xb, D, chunk, B, 0, D);
        k_topk2<<<R, 256, 0, stream>>>(chunk, topk, r0);
    }

    // 3. graph build
    k_zero2<<<B / 256, 256, 0, stream>>>(indeg, rfill);
    k_count<<<B * KNN / 256, 256, 0, stream>>>(topk, indeg);
    k_scan<<<1, 1024, 0, stream>>>(indeg, roff);
    k_dinv<<<B / 256, 256, 0, stream>>>(indeg, dinv);
    k_fill<<<B * KNN / 256, 256, 0, stream>>>(topk, roff, rfill, ridx);

    // 4. G1b = A_hat Fb (bf16); Yb = 10*Xhat + normalize(A_hat G1b)  (fused)
    k_spmm1<<<B, 128, 0, stream>>>(Fb, G1b, topk, roff, ridx, dinv);
    k_spmm2y<<<B, 128, 0, stream>>>(G1b, F, invnf, Yb, topk, roff, ridx, dinv);

    // 5. chunked: logits = Xb @ Yb^T (= 10*sim + cos) -> softmax -> out rows = W @ F
    for (int r0 = 0; r0 < B; r0 += R) {
        dim3 g(B / 128, R / 128);
        k_mfma_nt<<<g, 256, 0, stream>>>(Xb + (size_t)r0 * D, D, Yb, D, chunk, B, 0, D);
        k_softmax<<<R, 256, 0, stream>>>(chunk);
        float* part = chunk + 4096;
        dim3 gf(D / 128, R / 128, SK);
        k_mfma_nt<<<gf, 256, 0, stream>>>((const unsigned short*)chunk, 2 * B, FbT, B,
                                          part, B, D, ksplit);
        k_red<<<R / 2, 256, 0, stream>>>(part, out + (size_t)r0 * D, SK);
    }
}

// Round 7
// 838.555 us; speedup vs baseline: 6.3988x; 1.0320x over previous
//
#include <hip/hip_runtime.h>
#include <hip/hip_bf16.h>
#include <float.h>
#include <math.h>

constexpr int B = 8192;
constexpr int D = 512;
constexpr int KNN = 32;

typedef __attribute__((ext_vector_type(8))) short bhalf8;
typedef __attribute__((ext_vector_type(4))) float floatx4;

#if defined(__has_builtin)
#if __has_builtin(__builtin_amdgcn_global_load_lds)
#define HAS_GLD 1
#else
#define HAS_GLD 0
#endif
#else
#define HAS_GLD 0
#endif

__device__ __forceinline__ unsigned short f2bf(float f) {
    __hip_bfloat16 h = __float2bfloat16(f);
    return __builtin_bit_cast(unsigned short, h);
}

__device__ __forceinline__ float bf2f(unsigned short u) {
    unsigned int x = ((unsigned int)u) << 16;
    return __builtin_bit_cast(float, x);
}

__device__ __forceinline__ float waveReduceSum(float v) {
#pragma unroll
    for (int off = 32; off; off >>= 1) v += __shfl_down(v, off);
    return v;
}

// stage one 16B chunk of a 128x32-bf16 tile (linear LDS, 64B rows).
__device__ __forceinline__ void stage_chunk(const unsigned short* __restrict__ g,
                                            char* __restrict__ lds_tile, int c) {
#if HAS_GLD
    char* wavebase = lds_tile + (size_t)(c & ~63) * 16;
    __builtin_amdgcn_global_load_lds((const __attribute__((address_space(1))) void*)g,
                                     (__attribute__((address_space(3))) void*)wavebase,
                                     16, 0, 0);
#else
    *(int4*)(lds_tile + (size_t)c * 16) = *(const int4*)g;
#endif
}

// ---------------- bf16 MFMA GEMM, NT form ----------------
// C[m][n] = A[m][:].B1[n][:].  128x128 tile, BK=32, 4 waves 2x2.
// Split-K via blockIdx.z: K-range [z*ksplit, (z+1)*ksplit), C += z*zstride.
// lda/ldb in u16 elements; ldc/zstride in floats.
__global__ __launch_bounds__(256, 2) void k_mfma_nt(
    const unsigned short* __restrict__ A, int lda,
    const unsigned short* __restrict__ B1, int ldb,
    float* __restrict__ C, int ldc, int zstride, int ksplit) {
    __shared__ __align__(16) char smem[2 * 8192];
    char* Asm = smem;
    char* B1sm = smem + 8192;

    int tid = threadIdx.x;
    int lane = tid & 63;
    int wid = tid >> 6;
    int wm = (wid >> 1) * 64, wn = (wid & 1) * 64;
    int lrow = lane & 15;
    int kh = lane >> 4;
    int gm = blockIdx.y * 128, gn = blockIdx.x * 128;
    int kbeg = blockIdx.z * ksplit;
    C += (size_t)blockIdx.z * zstride;

    floatx4 zero4 = {0.0f, 0.0f, 0.0f, 0.0f};
    floatx4 acc1[4][4];
#pragma unroll
    for (int m = 0; m < 4; m++)
#pragma unroll
        for (int n = 0; n < 4; n++) acc1[m][n] = zero4;

    for (int k0 = kbeg; k0 < kbeg + ksplit; k0 += 32) {
        __syncthreads();
#pragma unroll
        for (int p = 0; p < 2; p++) {
            int c = p * 256 + tid;
            int row = c >> 2;
            int col = (c & 3) * 8;
            stage_chunk(A + (size_t)(gm + row) * lda + k0 + col, Asm, c);
            stage_chunk(B1 + (size_t)(gn + row) * ldb + k0 + col, B1sm, c);
        }
        __syncthreads();

        bhalf8 a[4];
#pragma unroll
        for (int m = 0; m < 4; m++)
            a[m] = *(const bhalf8*)(Asm + (wm + m * 16 + lrow) * 64 + kh * 16);
#pragma unroll
        for (int n = 0; n < 4; n++) {
            bhalf8 b = *(const bhalf8*)(B1sm + (wn + n * 16 + lrow) * 64 + kh * 16);
#pragma unroll
            for (int m = 0; m < 4; m++)
                acc1[m][n] = __builtin_amdgcn_mfma_f32_16x16x32_bf16(a[m], b, acc1[m][n], 0, 0, 0);
        }
    }

    // C/D layout col=lane&15, row=(lane>>4)*4+q  [m89-verified]
#pragma unroll
    for (int m = 0; m < 4; m++) {
#pragma unroll
        for (int n = 0; n < 4; n++) {
            int cc = gn + wn + n * 16 + lrow;
#pragma unroll
            for (int q = 0; q < 4; q++) {
                int r = gm + wm + m * 16 + kh * 4 + q;
                C[(size_t)r * ldc + cc] = acc1[m][n][q];
            }
        }
    }
}

// ---------------- split-K reduce: out[lr][d] = sum_p partial(p,lr,d) ----------------
__global__ __launch_bounds__(256) void k_red(const float* __restrict__ P,
                                             float* __restrict__ outp, int SK) {
    int idx = blockIdx.x * 256 + threadIdx.x;
    int lr = idx >> 7;
    int d4 = (idx & 127) * 4;
    const float* base = P + (size_t)lr * 8192 + d4;
    float4 s = *(const float4*)base;
    for (int p = 1; p < SK; p++) {
        float4 v = *(const float4*)(base + (size_t)p * 512);
        s.x += v.x; s.y += v.y; s.z += v.z; s.w += v.w;
    }
    *(float4*)(outp + (size_t)lr * 512 + d4) = s;
}

// ------- normalize rows of F -> bf16 Xb (normalized), bf16 Fb (raw), invnf -------
__global__ __launch_bounds__(128) void k_norm(const float* __restrict__ F,
                                              unsigned short* __restrict__ Xb,
                                              unsigned short* __restrict__ Fb,
                                              float* __restrict__ invnf) {
    int row = blockIdx.x, tid = threadIdx.x;
    float4 v = ((const float4*)(F + (size_t)row * D))[tid];
    float ss = v.x * v.x + v.y * v.y + v.z * v.z + v.w * v.w;
    ss = waveReduceSum(ss);
    __shared__ float s2[2];
    if ((tid & 63) == 0) s2[tid >> 6] = ss;
    __syncthreads();
    float inv = 1.0f / fmaxf(sqrtf(s2[0] + s2[1]), 1e-12f);
    if (tid == 0) invnf[row] = inv;
    union { unsigned short s[4]; int2 q; } ux, uf;
    ux.s[0] = f2bf(v.x * inv); ux.s[1] = f2bf(v.y * inv);
    ux.s[2] = f2bf(v.z * inv); ux.s[3] = f2bf(v.w * inv);
    uf.s[0] = f2bf(v.x); uf.s[1] = f2bf(v.y);
    uf.s[2] = f2bf(v.z); uf.s[3] = f2bf(v.w);
    *(int2*)(Xb + (size_t)row * D + tid * 4) = ux.q;
    *(int2*)(Fb + (size_t)row * D + tid * 4) = uf.q;
}

// ---------------- transpose F (fp32 BxD) -> FbT (bf16 DxB) ----------------
__global__ __launch_bounds__(256) void k_transpose(const float* __restrict__ F,
                                                   unsigned short* __restrict__ FbT) {
    __shared__ float t[64][65];
    int r0 = blockIdx.x * 64, d0 = blockIdx.y * 64;
    int tid = threadIdx.x;
#pragma unroll
    for (int p = 0; p < 4; p++) {
        int idx = p * 256 + tid;
        int r = idx >> 4, c4 = (idx & 15) * 4;
        float4 v = *(const float4*)(F + (size_t)(r0 + r) * D + d0 + c4);
        t[r][c4 + 0] = v.x; t[r][c4 + 1] = v.y; t[r][c4 + 2] = v.z; t[r][c4 + 3] = v.w;
    }
    __syncthreads();
#pragma unroll
    for (int p = 0; p < 2; p++) {
        int idx = p * 256 + tid;
        int d = idx >> 3, rc = (idx & 7) * 8;
        union { unsigned short s[8]; int4 v; } u;
#pragma unroll
        for (int j = 0; j < 8; j++) u.s[j] = f2bf(t[rc + j][d]);
        *(int4*)(FbT + (size_t)(d0 + d) * B + r0 + rc) = u.v;
    }
}

// ---------------- top-K: 12-bit radix histogram select + exact candidate argmax ------
// Matches lax.top_k order: value desc, then index asc (packed u64 keys).
__global__ __launch_bounds__(256) void k_topk2(const float* __restrict__ S,
                                               int* __restrict__ topk, int r0) {
    __shared__ int hist[4096];
    __shared__ int totals[256];
    __shared__ int cslot[2][4];
    __shared__ int islot[4];
    __shared__ unsigned long long buf[128];
    __shared__ int outIdx[KNN];
    __shared__ int ccount;
    __shared__ int sbin;
    __shared__ int sSb;
    int li = blockIdx.x, tid = threadIdx.x;
    int i = r0 + li;
    const float* rp = S + (size_t)li * B;

    // load 32 keys/thread; col = j8*1024 + tid*4 + q ; monotonic uint mapping
    unsigned int key[32];
#pragma unroll
    for (int j8 = 0; j8 < 8; j8++) {
        float4 v = *(const float4*)(rp + j8 * 1024 + tid * 4);
        float fv[4] = {v.x, v.y, v.z, v.w};
#pragma unroll
        for (int q = 0; q < 4; q++) {
            int col = j8 * 1024 + tid * 4 + q;
            unsigned int u = __builtin_bit_cast(unsigned int, fv[q]);
            unsigned int k = u ^ ((u & 0x80000000u) ? 0xFFFFFFFFu : 0x80000000u);
            key[j8 * 4 + q] = (col == i) ? 0u : k;
        }
    }

    // zero histogram + init
#pragma unroll
    for (int j = 0; j < 16; j++) hist[tid * 16 + j] = 0;
    if (tid == 0) { sbin = -1; ccount = 0; }
    __syncthreads();

    // histogram top 12 bits
#pragma unroll
    for (int j = 0; j < 32; j++) atomicAdd(&hist[key[j] >> 20], 1);
    __syncthreads();

    // per-thread bin totals (bins [tid*16, tid*16+16))
    int base = tid * 16;
    {
        int s = 0;
#pragma unroll
        for (int j = 0; j < 16; j++) s += hist[base + j];
        totals[tid] = s;
    }
    __syncthreads();
    // Hillis-Steele suffix scan over totals: totals[t] = sum_{t'>=t}
    for (int off = 1; off < 256; off <<= 1) {
        int v = (tid + off < 256) ? totals[tid + off] : 0;
        __syncthreads();
        totals[tid] += v;
        __syncthreads();
    }
    int nextT = (tid < 255) ? totals[tid + 1] : 0;

    // highest bin with suffix >= KNN (per-thread candidate, then block max)
    {
        int bestj = -1;
        int s2 = nextT;
#pragma unroll
        for (int j = 15; j >= 0; j--) {
            s2 += hist[base + j];
            if (s2 >= KNN && bestj < 0) bestj = base + j;
        }
        if (bestj >= 0) atomicMax(&sbin, bestj);
    }
    __syncthreads();
    int b = sbin;  // >= 0 always (suffix(0) = B-1 >= KNN)
    if (tid == (b >> 4)) {
        int s2 = nextT;
        for (int j = 15; j >= (b & 15); j--) s2 += hist[(b & ~15) + j];
        sSb = s2;  // suffix(b) = count(keys >= b<<20)
    }
    __syncthreads();
    int Sb = sSb;

    unsigned int T = 0;
    bool found = false;
    if (Sb <= 128) {
        // b >= 1 here (bin 0 has suffix B-1 > 128)
        T = (((unsigned int)b) << 20) - 1u;
        found = true;
    } else {
        // refine inside bin b: count(>lo) > 128, count(>hi) < KNN
        unsigned int lo = (b == 0) ? 0u : ((((unsigned int)b) << 20) - 1u);
        unsigned int hi = (((unsigned int)(b + 1)) << 20) - 1u;  // b=4095 wraps to 0xFFFFFFFF
        for (int it = 0; it < 33; ++it) {
            unsigned int mid = lo + ((hi - lo) >> 1);
            if (mid == lo) break;
            int c = 0;
#pragma unroll
            for (int j = 0; j < 32; j++) c += (key[j] > mid) ? 1 : 0;
#pragma unroll
            for (int off = 32; off; off >>= 1) c += __shfl_down(c, off);
            if ((tid & 63) == 0) cslot[it & 1][tid >> 6] = c;
            __syncthreads();
            int tot = cslot[it & 1][0] + cslot[it & 1][1] + cslot[it & 1][2] + cslot[it & 1][3];
            if (tot >= KNN && tot <= 128) { T = mid; found = true; break; }
            if (tot < KNN) hi = mid; else lo = mid;
        }
        if (!found) T = hi;  // exact-tie slow path: keys > hi are candidates, rest == hi
    }
    __syncthreads();

    // collect candidates (key > T) into buf
#pragma unroll
    for (int j8 = 0; j8 < 8; j8++) {
#pragma unroll
        for (int q = 0; q < 4; q++) {
            int j = j8 * 4 + q;
            if (key[j] > T) {
                int p = atomicAdd(&ccount, 1);
                if (p < 128) {
                    int col = j8 * 1024 + tid * 4 + q;
                    buf[p] = ((unsigned long long)key[j] << 13) |
                             (unsigned long long)(8191 - col);
                }
            }
        }
    }
    __syncthreads();
    int C = ccount < 128 ? ccount : 128;

    // wave 0: iterative argmax over candidates (<=128)
    if (tid < 64) {
        unsigned long long p0 = (tid < C) ? buf[tid] : 0ull;
        unsigned long long p1 = (tid + 64 < C) ? buf[tid + 64] : 0ull;
        for (int it = 0; it < KNN; ++it) {
            unsigned long long m = (p0 > p1) ? p0 : p1;
#pragma unroll
            for (int off = 32; off; off >>= 1) {
                unsigned long long o = __shfl_down(m, off);
                m = (o > m) ? o : m;
            }
            m = __shfl(m, 0);
            if (tid == 0 && m != 0ull) outIdx[it] = 8191 - (int)(m & 0x1FFFull);
            if (p0 == m) p0 = 0ull; else if (p1 == m) p1 = 0ull;
        }
    }
    __syncthreads();

    if (C < KNN) {
        // fill remaining with smallest-index ties (key == T); effectively never hit
        int last = -1;
        for (int it = C; it < KNN; ++it) {
            int best = 0x7fffffff;
#pragma unroll
            for (int j8 = 0; j8 < 8; j8++) {
#pragma unroll
                for (int q = 0; q < 4; q++) {
                    int j = j8 * 4 + q;
                    int col = j8 * 1024 + tid * 4 + q;
                    if (key[j] == T && col > last && col < best) best = col;
                }
            }
#pragma unroll
            for (int off = 32; off; off >>= 1) {
                int o = __shfl_down(best, off);
                best = (o < best) ? o : best;
            }
            if ((tid & 63) == 0) islot[tid >> 6] = best;
            __syncthreads();
            best = min(min(islot[0], islot[1]), min(islot[2], islot[3]));
            if (tid == 0) outIdx[it] = best;
            last = best;
            __syncthreads();
        }
    }
    __syncthreads();
    if (tid < KNN) topk[(size_t)i * KNN + tid] = outIdx[tid];
}

// ---------------- graph build ----------------
__global__ void k_zero2(int* __restrict__ a, int* __restrict__ b) {
    int i = blockIdx.x * 256 + threadIdx.x;
    a[i] = 0;
    b[i] = 0;
}

__global__ void k_count(const int* __restrict__ topk, int* __restrict__ indeg) {
    int e = blockIdx.x * 256 + threadIdx.x;
    atomicAdd(&indeg[topk[e]], 1);
}

__global__ __launch_bounds__(1024) void k_scan(const int* __restrict__ indeg,
                                               int* __restrict__ roff) {
    __shared__ int sums[1024];
    int tid = threadIdx.x;
    int base = tid * 8;
    int loc[8];
    int s = 0;
#pragma unroll
    for (int j = 0; j < 8; j++) { loc[j] = s; s += indeg[base + j]; }
    sums[tid] = s;
    __syncthreads();
    for (int off = 1; off < 1024; off <<= 1) {
        int v = (tid >= off) ? sums[tid - off] : 0;
        __syncthreads();
        sums[tid] += v;
        __syncthreads();
    }
    int prev = (tid > 0) ? sums[tid - 1] : 0;
#pragma unroll
    for (int j = 0; j < 8; j++) roff[base + j] = prev + loc[j];
    if (tid == 1023) roff[B] = sums[1023];
}

__global__ void k_dinv(const int* __restrict__ indeg, float* __restrict__ dinv) {
    int i = blockIdx.x * 256 + threadIdx.x;
    float dg = (float)(KNN + indeg[i]);
    dinv[i] = fminf(1.0f / sqrtf(dg), 1e6f);
}

__global__ void k_fill(const int* __restrict__ topk, const int* __restrict__ roff,
                       int* __restrict__ fill, int* __restrict__ ridx) {
    int e = blockIdx.x * 256 + threadIdx.x;
    int dst = topk[e];
    int src = e >> 5;
    int pos = atomicAdd(&fill[dst], 1);
    ridx[roff[dst] + pos] = src;
}

// ------- SpMM 1: G1b (bf16) = A_hat @ Fb, gather in bf16 -------
__global__ __launch_bounds__(128) void k_spmm1(const unsigned short* __restrict__ Fb,
                                               unsigned short* __restrict__ G1b,
                                               const int* __restrict__ topk,
                                               const int* __restrict__ roff,
                                               const int* __restrict__ ridx,
                                               const float* __restrict__ dinv) {
    int i = blockIdx.x, tid = threadIdx.x;
    float a0 = 0, a1 = 0, a2 = 0, a3 = 0;
    const int* ti = topk + (size_t)i * KNN;
#pragma unroll 4
    for (int k = 0; k < KNN; k++) {
        int n = ti[k];
        float w = dinv[n];
        int2 p = *(const int2*)(Fb + (size_t)n * D + tid * 4);
        const unsigned short* us = (const unsigned short*)&p;
        a0 += w * bf2f(us[0]); a1 += w * bf2f(us[1]);
        a2 += w * bf2f(us[2]); a3 += w * bf2f(us[3]);
    }
    int s = roff[i], e = roff[i + 1];
    for (int t = s; t < e; t++) {
        int j = ridx[t];
        float w = dinv[j];
        int2 p = *(const int2*)(Fb + (size_t)j * D + tid * 4);
        const unsigned short* us = (const unsigned short*)&p;
        a0 += w * bf2f(us[0]); a1 += w * bf2f(us[1]);
        a2 += w * bf2f(us[2]); a3 += w * bf2f(us[3]);
    }
    float wi = dinv[i];
    union { unsigned short s4[4]; int2 q; } u;
    u.s4[0] = f2bf(wi * a0); u.s4[1] = f2bf(wi * a1);
    u.s4[2] = f2bf(wi * a2); u.s4[3] = f2bf(wi * a3);
    *(int2*)(G1b + (size_t)i * D + tid * 4) = u.q;
}

// ------- SpMM 2 fused with Yb build:
//   g = (A_hat @ G1b)_row i ;  Yb_i = bf16(10 * F_i * invnf_i + g / max(||g||,1e-12))
__global__ __launch_bounds__(128) void k_spmm2y(const unsigned short* __restrict__ G1b,
                                                const float* __restrict__ F,
                                                const float* __restrict__ invnf,
                                                unsigned short* __restrict__ Yb,
                                                const int* __restrict__ topk,
                                                const int* __restrict__ roff,
                                                const int* __restrict__ ridx,
                                                const float* __restrict__ dinv) {
    int i = blockIdx.x, tid = threadIdx.x;
    float a0 = 0, a1 = 0, a2 = 0, a3 = 0;
    const int* ti = topk + (size_t)i * KNN;
#pragma unroll 4
    for (int k = 0; k < KNN; k++) {
        int n = ti[k];
        float w = dinv[n];
        int2 p = *(const int2*)(G1b + (size_t)n * D + tid * 4);
        const unsigned short* us = (const unsigned short*)&p;
        a0 += w * bf2f(us[0]); a1 += w * bf2f(us[1]);
        a2 += w * bf2f(us[2]); a3 += w * bf2f(us[3]);
    }
    int s = roff[i], e = roff[i + 1];
    for (int t = s; t < e; t++) {
        int j = ridx[t];
        float w = dinv[j];
        int2 p = *(const int2*)(G1b + (size_t)j * D + tid * 4);
        const unsigned short* us = (const unsigned short*)&p;
        a0 += w * bf2f(us[0]); a1 += w * bf2f(us[1]);
        a2 += w * bf2f(us[2]); a3 += w * bf2f(us[3]);
    }
    float wi = dinv[i];
    float g0 = wi * a0, g1 = wi * a1, g2 = wi * a2, g3 = wi * a3;

    float ss = g0 * g0 + g1 * g1 + g2 * g2 + g3 * g3;
    ss = waveReduceSum(ss);
    __shared__ float s2[2];
    if ((tid & 63) == 0) s2[tid >> 6] = ss;
    __syncthreads();
    float invng = 1.0f / fmaxf(sqrtf(s2[0] + s2[1]), 1e-12f);

    float4 f = ((const float4*)(F + (size_t)i * D))[tid];
    float inf_ = 10.0f * invnf[i];
    union { unsigned short s4[4]; int2 q; } u;
    u.s4[0] = f2bf(f.x * inf_ + g0 * invng);
    u.s4[1] = f2bf(f.y * inf_ + g1 * invng);
    u.s4[2] = f2bf(f.z * inf_ + g2 * invng);
    u.s4[3] = f2bf(f.w * inf_ + g3 * invng);
    *(int2*)(Yb + (size_t)i * D + tid * 4) = u.q;
}

// ------- row softmax of logits; writes bf16 weights in place ----------
__global__ __launch_bounds__(256) void k_softmax(float* __restrict__ chunk) {
    __shared__ float row[B];
    __shared__ float red[4];
    int li = blockIdx.x, tid = threadIdx.x;
    float* rp = chunk + (size_t)li * B;
    float mx = -FLT_MAX;
    for (int t = tid; t < B / 4; t += 256) {
        float4 v = *(const float4*)(rp + t * 4);
        *(float4*)&row[t * 4] = v;
        mx = fmaxf(mx, fmaxf(fmaxf(v.x, v.y), fmaxf(v.z, v.w)));
    }
#pragma unroll
    for (int off = 32; off; off >>= 1) mx = fmaxf(mx, __shfl_down(mx, off));
    if ((tid & 63) == 0) red[tid >> 6] = mx;
    __syncthreads();
    mx = fmaxf(fmaxf(red[0], red[1]), fmaxf(red[2], red[3]));
    __syncthreads();
    float sum = 0.0f;
    for (int t = tid; t < B; t += 256) {
        float e = __expf(row[t] - mx);
        row[t] = e;
        sum += e;
    }
    sum = waveReduceSum(sum);
    if ((tid & 63) == 0) red[tid >> 6] = sum;
    __syncthreads();
    sum = red[0] + red[1] + red[2] + red[3];
    float sc = 1.0f / sum;
    unsigned short* wp = (unsigned short*)rp;
    for (int t = tid; t < B / 8; t += 256) {
        union { unsigned short s[8]; int4 v; } u;
#pragma unroll
        for (int j = 0; j < 8; j++) u.s[j] = f2bf(row[t * 8 + j] * sc);
        *(int4*)(wp + t * 8) = u.v;
    }
}

extern "C" void kernel_launch(void* const* d_in, const int* in_sizes, int n_in,
                              void* d_out, int out_size, void* d_ws, size_t ws_size,
                              hipStream_t stream) {
    (void)in_sizes; (void)n_in; (void)out_size;
    const float* F = (const float*)d_in[0];
    float* out = (float*)d_out;

    char* ws = (char*)d_ws;
    size_t off = 0;
    auto take = [&](size_t bytes) -> void* {
        void* p = ws + off;
        off += (bytes + 255) & ~(size_t)255;
        return p;
    };
    float* invnf = (float*)take((size_t)B * 4);
    float* dinv = (float*)take((size_t)B * 4);
    int* topk = (int*)take((size_t)B * KNN * 4);
    int* indeg = (int*)take((size_t)B * 4);
    int* roff = (int*)take((size_t)(B + 1) * 4);
    int* rfill = (int*)take((size_t)B * 4);
    int* ridx = (int*)take((size_t)B * KNN * 4);
    unsigned short* Xb = (unsigned short*)take((size_t)B * D * 2);
    unsigned short* Fb = (unsigned short*)take((size_t)B * D * 2);
    unsigned short* Yb = (unsigned short*)take((size_t)B * D * 2);
    unsigned short* FbT = (unsigned short*)take((size_t)D * B * 2);
    size_t fixed = off;

    int R = 2048;
    if (ws_size > 0) {
        while (R > 128 && fixed + (size_t)R * B * 4 > ws_size) R >>= 1;
    } else {
        R = 1024;
    }
    float* chunk = (float*)(ws + fixed);
    unsigned short* G1b = (unsigned short*)out;  // d_out as scratch for SpMM-1 (8 MB of 16)

    int SK = 8192 / R;
    if (SK > 8) SK = 8;
    int ksplit = B / SK;

    // 1. Xb / Fb / invnf; FbT = bf16 F^T
    k_norm<<<B, 128, 0, stream>>>(F, Xb, Fb, invnf);
    dim3 gt(B / 64, D / 64);
    k_transpose<<<gt, 256, 0, stream>>>(F, FbT);

    // 2. chunked: sim = Xb Xb^T + top-K
    for (int r0 = 0; r0 < B; r0 += R) {
        dim3 g(B / 128, R / 128);
        k_mfma_nt<<<g, 256, 0, stream>>>(Xb + (size_t)r0 * D, D, Xb, D, chunk, B, 0, D);
        k_topk2<<<R, 256, 0, stream>>>(chunk, topk, r0);
    }

    // 3. graph build
    k_zero2<<<B / 256, 256, 0, stream>>>(indeg, rfill);
    k_count<<<B * KNN / 256, 256, 0, stream>>>(topk, indeg);
    k_scan<<<1, 1024, 0, stream>>>(indeg, roff);
    k_dinv<<<B / 256, 256, 0, stream>>>(indeg, dinv);
    k_fill<<<B * KNN / 256, 256, 0, stream>>>(topk, roff, rfill, ridx);

    // 4. G1b = A_hat Fb (bf16); Yb = 10*Xhat + normalize(A_hat G1b)  (fused)
    k_spmm1<<<B, 128, 0, stream>>>(Fb, G1b, topk, roff, ridx, dinv);
    k_spmm2y<<<B, 128, 0, stream>>>(G1b, F, invnf, Yb, topk, roff, ridx, dinv);

    // 5. chunked: logits = Xb @ Yb^T (= 10*sim + cos) -> softmax -> out rows = W @ F
    for (int r0 = 0; r0 < B; r0 += R) {
        dim3 g(B / 128, R / 128);
        k_mfma_nt<<<g, 256, 0, stream>>>(Xb + (size_t)r0 * D, D, Yb, D, chunk, B, 0, D);
        k_softmax<<<R, 256, 0, stream>>>(chunk);
        float* part = chunk + 4096;
        dim3 gf(D / 128, R / 128, SK);
        k_mfma_nt<<<gf, 256, 0, stream>>>((const unsigned short*)chunk, 2 * B, FbT, B,
                                          part, B, D, ksplit);
        k_red<<<R / 2, 256, 0, stream>>>(part, out + (size_t)r0 * D, SK);
    }
}

// Round 8
// 804.738 us; speedup vs baseline: 6.6676x; 1.0420x over previous
//
#include <hip/hip_runtime.h>
#include <hip/hip_bf16.h>
#include <float.h>
#include <math.h>

constexpr int B = 8192;
constexpr int D = 512;
constexpr int KNN = 32;

typedef __attribute__((ext_vector_type(8))) short bhalf8;
typedef __attribute__((ext_vector_type(4))) float floatx4;

#if defined(__has_builtin)
#if __has_builtin(__builtin_amdgcn_global_load_lds)
#define HAS_GLD 1
#else
#define HAS_GLD 0
#endif
#else
#define HAS_GLD 0
#endif

__device__ __forceinline__ unsigned short f2bf(float f) {
    __hip_bfloat16 h = __float2bfloat16(f);
    return __builtin_bit_cast(unsigned short, h);
}

__device__ __forceinline__ float bf2f(unsigned short u) {
    unsigned int x = ((unsigned int)u) << 16;
    return __builtin_bit_cast(float, x);
}

__device__ __forceinline__ float waveReduceSum(float v) {
#pragma unroll
    for (int off = 32; off; off >>= 1) v += __shfl_down(v, off);
    return v;
}

// stage one 16B chunk of a 128x32-bf16 tile (linear LDS, 64B rows).
__device__ __forceinline__ void stage_chunk(const unsigned short* __restrict__ g,
                                            char* __restrict__ lds_tile, int c) {
#if HAS_GLD
    char* wavebase = lds_tile + (size_t)(c & ~63) * 16;
    __builtin_amdgcn_global_load_lds((const __attribute__((address_space(1))) void*)g,
                                     (__attribute__((address_space(3))) void*)wavebase,
                                     16, 0, 0);
#else
    *(int4*)(lds_tile + (size_t)c * 16) = *(const int4*)g;
#endif
}

// ---------------- bf16 MFMA GEMM, NT form ----------------
// C[m][n] = A[m][:].B1[n][:].  128x128 tile, BK=32, 4 waves 2x2.
// Split-K via blockIdx.z: K-range [z*ksplit, (z+1)*ksplit), C += z*zstride.
// lda/ldb in u16 elements; ldc/zstride in floats.
__global__ __launch_bounds__(256, 2) void k_mfma_nt(
    const unsigned short* __restrict__ A, int lda,
    const unsigned short* __restrict__ B1, int ldb,
    float* __restrict__ C, int ldc, int zstride, int ksplit) {
    __shared__ __align__(16) char smem[2 * 8192];
    char* Asm = smem;
    char* B1sm = smem + 8192;

    int tid = threadIdx.x;
    int lane = tid & 63;
    int wid = tid >> 6;
    int wm = (wid >> 1) * 64, wn = (wid & 1) * 64;
    int lrow = lane & 15;
    int kh = lane >> 4;
    int gm = blockIdx.y * 128, gn = blockIdx.x * 128;
    int kbeg = blockIdx.z * ksplit;
    C += (size_t)blockIdx.z * zstride;

    floatx4 zero4 = {0.0f, 0.0f, 0.0f, 0.0f};
    floatx4 acc1[4][4];
#pragma unroll
    for (int m = 0; m < 4; m++)
#pragma unroll
        for (int n = 0; n < 4; n++) acc1[m][n] = zero4;

    for (int k0 = kbeg; k0 < kbeg + ksplit; k0 += 32) {
        __syncthreads();
#pragma unroll
        for (int p = 0; p < 2; p++) {
            int c = p * 256 + tid;
            int row = c >> 2;
            int col = (c & 3) * 8;
            stage_chunk(A + (size_t)(gm + row) * lda + k0 + col, Asm, c);
            stage_chunk(B1 + (size_t)(gn + row) * ldb + k0 + col, B1sm, c);
        }
        __syncthreads();

        bhalf8 a[4];
#pragma unroll
        for (int m = 0; m < 4; m++)
            a[m] = *(const bhalf8*)(Asm + (wm + m * 16 + lrow) * 64 + kh * 16);
#pragma unroll
        for (int n = 0; n < 4; n++) {
            bhalf8 b = *(const bhalf8*)(B1sm + (wn + n * 16 + lrow) * 64 + kh * 16);
#pragma unroll
            for (int m = 0; m < 4; m++)
                acc1[m][n] = __builtin_amdgcn_mfma_f32_16x16x32_bf16(a[m], b, acc1[m][n], 0, 0, 0);
        }
    }

    // C/D layout col=lane&15, row=(lane>>4)*4+q  [m89-verified]
#pragma unroll
    for (int m = 0; m < 4; m++) {
#pragma unroll
        for (int n = 0; n < 4; n++) {
            int cc = gn + wn + n * 16 + lrow;
#pragma unroll
            for (int q = 0; q < 4; q++) {
                int r = gm + wm + m * 16 + kh * 4 + q;
                C[(size_t)r * ldc + cc] = acc1[m][n][q];
            }
        }
    }
}

// ---------------- split-K reduce: out[lr][d] = sum_p partial(p,lr,d) ----------------
__global__ __launch_bounds__(256) void k_red(const float* __restrict__ P,
                                             float* __restrict__ outp, int SK) {
    int idx = blockIdx.x * 256 + threadIdx.x;
    int lr = idx >> 7;
    int d4 = (idx & 127) * 4;
    const float* base = P + (size_t)lr * 8192 + d4;
    float4 s = *(const float4*)base;
    for (int p = 1; p < SK; p++) {
        float4 v = *(const float4*)(base + (size_t)p * 512);
        s.x += v.x; s.y += v.y; s.z += v.z; s.w += v.w;
    }
    *(float4*)(outp + (size_t)lr * 512 + d4) = s;
}

// ------- normalize rows of F -> bf16 Xb (normalized), bf16 Fb (raw), invnf -------
__global__ __launch_bounds__(128) void k_norm(const float* __restrict__ F,
                                              unsigned short* __restrict__ Xb,
                                              unsigned short* __restrict__ Fb,
                                              float* __restrict__ invnf) {
    int row = blockIdx.x, tid = threadIdx.x;
    float4 v = ((const float4*)(F + (size_t)row * D))[tid];
    float ss = v.x * v.x + v.y * v.y + v.z * v.z + v.w * v.w;
    ss = waveReduceSum(ss);
    __shared__ float s2[2];
    if ((tid & 63) == 0) s2[tid >> 6] = ss;
    __syncthreads();
    float inv = 1.0f / fmaxf(sqrtf(s2[0] + s2[1]), 1e-12f);
    if (tid == 0) invnf[row] = inv;
    union { unsigned short s[4]; int2 q; } ux, uf;
    ux.s[0] = f2bf(v.x * inv); ux.s[1] = f2bf(v.y * inv);
    ux.s[2] = f2bf(v.z * inv); ux.s[3] = f2bf(v.w * inv);
    uf.s[0] = f2bf(v.x); uf.s[1] = f2bf(v.y);
    uf.s[2] = f2bf(v.z); uf.s[3] = f2bf(v.w);
    *(int2*)(Xb + (size_t)row * D + tid * 4) = ux.q;
    *(int2*)(Fb + (size_t)row * D + tid * 4) = uf.q;
}

// ---------------- transpose F (fp32 BxD) -> FbT (bf16 DxB) ----------------
__global__ __launch_bounds__(256) void k_transpose(const float* __restrict__ F,
                                                   unsigned short* __restrict__ FbT) {
    __shared__ float t[64][65];
    int r0 = blockIdx.x * 64, d0 = blockIdx.y * 64;
    int tid = threadIdx.x;
#pragma unroll
    for (int p = 0; p < 4; p++) {
        int idx = p * 256 + tid;
        int r = idx >> 4, c4 = (idx & 15) * 4;
        float4 v = *(const float4*)(F + (size_t)(r0 + r) * D + d0 + c4);
        t[r][c4 + 0] = v.x; t[r][c4 + 1] = v.y; t[r][c4 + 2] = v.z; t[r][c4 + 3] = v.w;
    }
    __syncthreads();
#pragma unroll
    for (int p = 0; p < 2; p++) {
        int idx = p * 256 + tid;
        int d = idx >> 3, rc = (idx & 7) * 8;
        union { unsigned short s[8]; int4 v; } u;
#pragma unroll
        for (int j = 0; j < 8; j++) u.s[j] = f2bf(t[rc + j][d]);
        *(int4*)(FbT + (size_t)(d0 + d) * B + r0 + rc) = u.v;
    }
}

// ---------------- top-K: 12-bit radix histogram select + exact candidate argmax ------
// Matches lax.top_k order: value desc, then index asc (packed u64 keys).
__global__ __launch_bounds__(256) void k_topk2(const float* __restrict__ S,
                                               int* __restrict__ topk, int r0) {
    __shared__ int hist[4096];
    __shared__ int totals[256];
    __shared__ int cslot[2][4];
    __shared__ int islot[4];
    __shared__ unsigned long long buf[128];
    __shared__ int outIdx[KNN];
    __shared__ int ccount;
    __shared__ int sbin;
    __shared__ int sSb;
    int li = blockIdx.x, tid = threadIdx.x;
    int i = r0 + li;
    const float* rp = S + (size_t)li * B;

    // load 32 keys/thread; col = j8*1024 + tid*4 + q ; monotonic uint mapping
    unsigned int key[32];
#pragma unroll
    for (int j8 = 0; j8 < 8; j8++) {
        float4 v = *(const float4*)(rp + j8 * 1024 + tid * 4);
        float fv[4] = {v.x, v.y, v.z, v.w};
#pragma unroll
        for (int q = 0; q < 4; q++) {
            int col = j8 * 1024 + tid * 4 + q;
            unsigned int u = __builtin_bit_cast(unsigned int, fv[q]);
            unsigned int k = u ^ ((u & 0x80000000u) ? 0xFFFFFFFFu : 0x80000000u);
            key[j8 * 4 + q] = (col == i) ? 0u : k;
        }
    }

    // zero histogram + init
#pragma unroll
    for (int j = 0; j < 16; j++) hist[tid * 16 + j] = 0;
    if (tid == 0) { sbin = -1; ccount = 0; }
    __syncthreads();

    // histogram top 12 bits
#pragma unroll
    for (int j = 0; j < 32; j++) atomicAdd(&hist[key[j] >> 20], 1);
    __syncthreads();

    // per-thread bin totals (bins [tid*16, tid*16+16))
    int base = tid * 16;
    {
        int s = 0;
#pragma unroll
        for (int j = 0; j < 16; j++) s += hist[base + j];
        totals[tid] = s;
    }
    __syncthreads();
    // Hillis-Steele suffix scan over totals: totals[t] = sum_{t'>=t}
    for (int off = 1; off < 256; off <<= 1) {
        int v = (tid + off < 256) ? totals[tid + off] : 0;
        __syncthreads();
        totals[tid] += v;
        __syncthreads();
    }
    int nextT = (tid < 255) ? totals[tid + 1] : 0;

    // highest bin with suffix >= KNN (per-thread candidate, then block max)
    {
        int bestj = -1;
        int s2 = nextT;
#pragma unroll
        for (int j = 15; j >= 0; j--) {
            s2 += hist[base + j];
            if (s2 >= KNN && bestj < 0) bestj = base + j;
        }
        if (bestj >= 0) atomicMax(&sbin, bestj);
    }
    __syncthreads();
    int b = sbin;  // >= 0 always (suffix(0) = B-1 >= KNN)
    if (tid == (b >> 4)) {
        int s2 = nextT;
        for (int j = 15; j >= (b & 15); j--) s2 += hist[(b & ~15) + j];
        sSb = s2;  // suffix(b) = count(keys >= b<<20)
    }
    __syncthreads();
    int Sb = sSb;

    unsigned int T = 0;
    bool found = false;
    if (Sb <= 128) {
        // b >= 1 here (bin 0 has suffix B-1 > 128)
        T = (((unsigned int)b) << 20) - 1u;
        found = true;
    } else {
        // refine inside bin b: count(>lo) > 128, count(>hi) < KNN
        unsigned int lo = (b == 0) ? 0u : ((((unsigned int)b) << 20) - 1u);
        unsigned int hi = (((unsigned int)(b + 1)) << 20) - 1u;  // b=4095 wraps to 0xFFFFFFFF
        for (int it = 0; it < 33; ++it) {
            unsigned int mid = lo + ((hi - lo) >> 1);
            if (mid == lo) break;
            int c = 0;
#pragma unroll
            for (int j = 0; j < 32; j++) c += (key[j] > mid) ? 1 : 0;
#pragma unroll
            for (int off = 32; off; off >>= 1) c += __shfl_down(c, off);
            if ((tid & 63) == 0) cslot[it & 1][tid >> 6] = c;
            __syncthreads();
            int tot = cslot[it & 1][0] + cslot[it & 1][1] + cslot[it & 1][2] + cslot[it & 1][3];
            if (tot >= KNN && tot <= 128) { T = mid; found = true; break; }
            if (tot < KNN) hi = mid; else lo = mid;
        }
        if (!found) T = hi;  // exact-tie slow path: keys > hi are candidates, rest == hi
    }
    __syncthreads();

    // collect candidates (key > T) into buf
#pragma unroll
    for (int j8 = 0; j8 < 8; j8++) {
#pragma unroll
        for (int q = 0; q < 4; q++) {
            int j = j8 * 4 + q;
            if (key[j] > T) {
                int p = atomicAdd(&ccount, 1);
                if (p < 128) {
                    int col = j8 * 1024 + tid * 4 + q;
                    buf[p] = ((unsigned long long)key[j] << 13) |
                             (unsigned long long)(8191 - col);
                }
            }
        }
    }
    __syncthreads();
    int C = ccount < 128 ? ccount : 128;

    // wave 0: iterative argmax over candidates (<=128)
    if (tid < 64) {
        unsigned long long p0 = (tid < C) ? buf[tid] : 0ull;
        unsigned long long p1 = (tid + 64 < C) ? buf[tid + 64] : 0ull;
        for (int it = 0; it < KNN; ++it) {
            unsigned long long m = (p0 > p1) ? p0 : p1;
#pragma unroll
            for (int off = 32; off; off >>= 1) {
                unsigned long long o = __shfl_down(m, off);
                m = (o > m) ? o : m;
            }
            m = __shfl(m, 0);
            if (tid == 0 && m != 0ull) outIdx[it] = 8191 - (int)(m & 0x1FFFull);
            if (p0 == m) p0 = 0ull; else if (p1 == m) p1 = 0ull;
        }
    }
    __syncthreads();

    if (C < KNN) {
        // fill remaining with smallest-index ties (key == T); effectively never hit
        int last = -1;
        for (int it = C; it < KNN; ++it) {
            int best = 0x7fffffff;
#pragma unroll
            for (int j8 = 0; j8 < 8; j8++) {
#pragma unroll
                for (int q = 0; q < 4; q++) {
                    int j = j8 * 4 + q;
                    int col = j8 * 1024 + tid * 4 + q;
                    if (key[j] == T && col > last && col < best) best = col;
                }
            }
#pragma unroll
            for (int off = 32; off; off >>= 1) {
                int o = __shfl_down(best, off);
                best = (o < best) ? o : best;
            }
            if ((tid & 63) == 0) islot[tid >> 6] = best;
            __syncthreads();
            best = min(min(islot[0], islot[1]), min(islot[2], islot[3]));
            if (tid == 0) outIdx[it] = best;
            last = best;
            __syncthreads();
        }
    }
    __syncthreads();
    if (tid < KNN) topk[(size_t)i * KNN + tid] = outIdx[tid];
}

// ---------------- graph build ----------------
__global__ void k_zero2(int* __restrict__ a, int* __restrict__ b) {
    int i = blockIdx.x * 256 + threadIdx.x;
    a[i] = 0;
    b[i] = 0;
}

__global__ void k_count(const int* __restrict__ topk, int* __restrict__ indeg) {
    int e = blockIdx.x * 256 + threadIdx.x;
    atomicAdd(&indeg[topk[e]], 1);
}

__global__ __launch_bounds__(1024) void k_scan(const int* __restrict__ indeg,
                                               int* __restrict__ roff) {
    __shared__ int sums[1024];
    int tid = threadIdx.x;
    int base = tid * 8;
    int loc[8];
    int s = 0;
#pragma unroll
    for (int j = 0; j < 8; j++) { loc[j] = s; s += indeg[base + j]; }
    sums[tid] = s;
    __syncthreads();
    for (int off = 1; off < 1024; off <<= 1) {
        int v = (tid >= off) ? sums[tid - off] : 0;
        __syncthreads();
        sums[tid] += v;
        __syncthreads();
    }
    int prev = (tid > 0) ? sums[tid - 1] : 0;
#pragma unroll
    for (int j = 0; j < 8; j++) roff[base + j] = prev + loc[j];
    if (tid == 1023) roff[B] = sums[1023];
}

__global__ void k_dinv(const int* __restrict__ indeg, float* __restrict__ dinv) {
    int i = blockIdx.x * 256 + threadIdx.x;
    float dg = (float)(KNN + indeg[i]);
    dinv[i] = fminf(1.0f / sqrtf(dg), 1e6f);
}

__global__ void k_fill(const int* __restrict__ topk, const int* __restrict__ roff,
                       int* __restrict__ fill, int* __restrict__ ridx) {
    int e = blockIdx.x * 256 + threadIdx.x;
    int dst = topk[e];
    int src = e >> 5;
    int pos = atomicAdd(&fill[dst], 1);
    ridx[roff[dst] + pos] = src;
}

// ------- SpMM 1: G1b (bf16) = A_hat @ Fb, gather in bf16, int4-batched indices -------
__global__ __launch_bounds__(128) void k_spmm1(const unsigned short* __restrict__ Fb,
                                               unsigned short* __restrict__ G1b,
                                               const int* __restrict__ topk,
                                               const int* __restrict__ roff,
                                               const int* __restrict__ ridx,
                                               const float* __restrict__ dinv) {
    int i = blockIdx.x, tid = threadIdx.x;
    float a0 = 0, a1 = 0, a2 = 0, a3 = 0;
    const int* ti = topk + (size_t)i * KNN;
#pragma unroll
    for (int k4 = 0; k4 < KNN / 4; k4++) {
        int4 nn = *(const int4*)(ti + k4 * 4);
        float w0 = dinv[nn.x], w1 = dinv[nn.y], w2 = dinv[nn.z], w3 = dinv[nn.w];
        int2 p0 = *(const int2*)(Fb + (size_t)nn.x * D + tid * 4);
        int2 p1 = *(const int2*)(Fb + (size_t)nn.y * D + tid * 4);
        int2 p2 = *(const int2*)(Fb + (size_t)nn.z * D + tid * 4);
        int2 p3 = *(const int2*)(Fb + (size_t)nn.w * D + tid * 4);
        const unsigned short* u0 = (const unsigned short*)&p0;
        const unsigned short* u1 = (const unsigned short*)&p1;
        const unsigned short* u2 = (const unsigned short*)&p2;
        const unsigned short* u3 = (const unsigned short*)&p3;
        a0 += w0 * bf2f(u0[0]) + w1 * bf2f(u1[0]) + w2 * bf2f(u2[0]) + w3 * bf2f(u3[0]);
        a1 += w0 * bf2f(u0[1]) + w1 * bf2f(u1[1]) + w2 * bf2f(u2[1]) + w3 * bf2f(u3[1]);
        a2 += w0 * bf2f(u0[2]) + w1 * bf2f(u1[2]) + w2 * bf2f(u2[2]) + w3 * bf2f(u3[2]);
        a3 += w0 * bf2f(u0[3]) + w1 * bf2f(u1[3]) + w2 * bf2f(u2[3]) + w3 * bf2f(u3[3]);
    }
    int s = roff[i], e = roff[i + 1];
    int t = s;
    for (; t + 2 <= e; t += 2) {
        int j0 = ridx[t], j1 = ridx[t + 1];
        float w0 = dinv[j0], w1 = dinv[j1];
        int2 p0 = *(const int2*)(Fb + (size_t)j0 * D + tid * 4);
        int2 p1 = *(const int2*)(Fb + (size_t)j1 * D + tid * 4);
        const unsigned short* u0 = (const unsigned short*)&p0;
        const unsigned short* u1 = (const unsigned short*)&p1;
        a0 += w0 * bf2f(u0[0]) + w1 * bf2f(u1[0]);
        a1 += w0 * bf2f(u0[1]) + w1 * bf2f(u1[1]);
        a2 += w0 * bf2f(u0[2]) + w1 * bf2f(u1[2]);
        a3 += w0 * bf2f(u0[3]) + w1 * bf2f(u1[3]);
    }
    if (t < e) {
        int j0 = ridx[t];
        float w0 = dinv[j0];
        int2 p0 = *(const int2*)(Fb + (size_t)j0 * D + tid * 4);
        const unsigned short* u0 = (const unsigned short*)&p0;
        a0 += w0 * bf2f(u0[0]); a1 += w0 * bf2f(u0[1]);
        a2 += w0 * bf2f(u0[2]); a3 += w0 * bf2f(u0[3]);
    }
    float wi = dinv[i];
    union { unsigned short s4[4]; int2 q; } u;
    u.s4[0] = f2bf(wi * a0); u.s4[1] = f2bf(wi * a1);
    u.s4[2] = f2bf(wi * a2); u.s4[3] = f2bf(wi * a3);
    *(int2*)(G1b + (size_t)i * D + tid * 4) = u.q;
}

// ------- SpMM 2 fused with Yb build:
//   g = (A_hat @ G1b)_row i ;  Yb_i = bf16(10 * F_i * invnf_i + g / max(||g||,1e-12))
__global__ __launch_bounds__(128) void k_spmm2y(const unsigned short* __restrict__ G1b,
                                                const float* __restrict__ F,
                                                const float* __restrict__ invnf,
                                                unsigned short* __restrict__ Yb,
                                                const int* __restrict__ topk,
                                                const int* __restrict__ roff,
                                                const int* __restrict__ ridx,
                                                const float* __restrict__ dinv) {
    int i = blockIdx.x, tid = threadIdx.x;
    float a0 = 0, a1 = 0, a2 = 0, a3 = 0;
    const int* ti = topk + (size_t)i * KNN;
#pragma unroll
    for (int k4 = 0; k4 < KNN / 4; k4++) {
        int4 nn = *(const int4*)(ti + k4 * 4);
        float w0 = dinv[nn.x], w1 = dinv[nn.y], w2 = dinv[nn.z], w3 = dinv[nn.w];
        int2 p0 = *(const int2*)(G1b + (size_t)nn.x * D + tid * 4);
        int2 p1 = *(const int2*)(G1b + (size_t)nn.y * D + tid * 4);
        int2 p2 = *(const int2*)(G1b + (size_t)nn.z * D + tid * 4);
        int2 p3 = *(const int2*)(G1b + (size_t)nn.w * D + tid * 4);
        const unsigned short* u0 = (const unsigned short*)&p0;
        const unsigned short* u1 = (const unsigned short*)&p1;
        const unsigned short* u2 = (const unsigned short*)&p2;
        const unsigned short* u3 = (const unsigned short*)&p3;
        a0 += w0 * bf2f(u0[0]) + w1 * bf2f(u1[0]) + w2 * bf2f(u2[0]) + w3 * bf2f(u3[0]);
        a1 += w0 * bf2f(u0[1]) + w1 * bf2f(u1[1]) + w2 * bf2f(u2[1]) + w3 * bf2f(u3[1]);
        a2 += w0 * bf2f(u0[2]) + w1 * bf2f(u1[2]) + w2 * bf2f(u2[2]) + w3 * bf2f(u3[2]);
        a3 += w0 * bf2f(u0[3]) + w1 * bf2f(u1[3]) + w2 * bf2f(u2[3]) + w3 * bf2f(u3[3]);
    }
    int s = roff[i], e = roff[i + 1];
    int t = s;
    for (; t + 2 <= e; t += 2) {
        int j0 = ridx[t], j1 = ridx[t + 1];
        float w0 = dinv[j0], w1 = dinv[j1];
        int2 p0 = *(const int2*)(G1b + (size_t)j0 * D + tid * 4);
        int2 p1 = *(const int2*)(G1b + (size_t)j1 * D + tid * 4);
        const unsigned short* u0 = (const unsigned short*)&p0;
        const unsigned short* u1 = (const unsigned short*)&p1;
        a0 += w0 * bf2f(u0[0]) + w1 * bf2f(u1[0]);
        a1 += w0 * bf2f(u0[1]) + w1 * bf2f(u1[1]);
        a2 += w0 * bf2f(u0[2]) + w1 * bf2f(u1[2]);
        a3 += w0 * bf2f(u0[3]) + w1 * bf2f(u1[3]);
    }
    if (t < e) {
        int j0 = ridx[t];
        float w0 = dinv[j0];
        int2 p0 = *(const int2*)(G1b + (size_t)j0 * D + tid * 4);
        const unsigned short* u0 = (const unsigned short*)&p0;
        a0 += w0 * bf2f(u0[0]); a1 += w0 * bf2f(u0[1]);
        a2 += w0 * bf2f(u0[2]); a3 += w0 * bf2f(u0[3]);
    }
    float wi = dinv[i];
    float g0 = wi * a0, g1 = wi * a1, g2 = wi * a2, g3 = wi * a3;

    float ss = g0 * g0 + g1 * g1 + g2 * g2 + g3 * g3;
    ss = waveReduceSum(ss);
    __shared__ float s2[2];
    if ((tid & 63) == 0) s2[tid >> 6] = ss;
    __syncthreads();
    float invng = 1.0f / fmaxf(sqrtf(s2[0] + s2[1]), 1e-12f);

    float4 f = ((const float4*)(F + (size_t)i * D))[tid];
    float inf_ = 10.0f * invnf[i];
    union { unsigned short s4[4]; int2 q; } u;
    u.s4[0] = f2bf(f.x * inf_ + g0 * invng);
    u.s4[1] = f2bf(f.y * inf_ + g1 * invng);
    u.s4[2] = f2bf(f.z * inf_ + g2 * invng);
    u.s4[3] = f2bf(f.w * inf_ + g3 * invng);
    *(int2*)(Yb + (size_t)i * D + tid * 4) = u.q;
}

// ------- register-resident online row softmax; writes bf16 weights in place ----------
// one global read (32 fp32/thread in VGPRs), one bf16 write; no LDS row buffer.
__global__ __launch_bounds__(256) void k_softmax(float* __restrict__ chunk) {
    __shared__ float sm[4], sl[4];
    int li = blockIdx.x, tid = threadIdx.x;
    float* rp = chunk + (size_t)li * B;
    float4 v[8];
    float mt = -FLT_MAX;
#pragma unroll
    for (int p = 0; p < 8; p++) {
        v[p] = *(const float4*)(rp + p * 1024 + tid * 4);
        mt = fmaxf(mt, fmaxf(fmaxf(v[p].x, v[p].y), fmaxf(v[p].z, v[p].w)));
    }
    float l = 0.0f;
#pragma unroll
    for (int p = 0; p < 8; p++) {
        v[p].x = __expf(v[p].x - mt);
        v[p].y = __expf(v[p].y - mt);
        v[p].z = __expf(v[p].z - mt);
        v[p].w = __expf(v[p].w - mt);
        l += v[p].x + v[p].y + v[p].z + v[p].w;
    }
    // (m,l) merge reduce: wave then cross-wave (lane 0 of each wave is valid)
    float m = mt, lw = l;
#pragma unroll
    for (int off = 32; off; off >>= 1) {
        float om = __shfl_down(m, off);
        float ol = __shfl_down(lw, off);
        float nm = fmaxf(m, om);
        lw = lw * __expf(m - nm) + ol * __expf(om - nm);
        m = nm;
    }
    if ((tid & 63) == 0) { sm[tid >> 6] = m; sl[tid >> 6] = lw; }
    __syncthreads();
    float M = fmaxf(fmaxf(sm[0], sm[1]), fmaxf(sm[2], sm[3]));
    float L = sl[0] * __expf(sm[0] - M) + sl[1] * __expf(sm[1] - M) +
              sl[2] * __expf(sm[2] - M) + sl[3] * __expf(sm[3] - M);
    float fct = __expf(mt - M) / L;
    unsigned short* wp = (unsigned short*)rp;  // bf16 over first half of the fp32 row
#pragma unroll
    for (int p = 0; p < 8; p++) {
        union { unsigned short s[4]; int2 q; } u;
        u.s[0] = f2bf(v[p].x * fct);
        u.s[1] = f2bf(v[p].y * fct);
        u.s[2] = f2bf(v[p].z * fct);
        u.s[3] = f2bf(v[p].w * fct);
        *(int2*)(wp + p * 1024 + tid * 4) = u.q;
    }
}

extern "C" void kernel_launch(void* const* d_in, const int* in_sizes, int n_in,
                              void* d_out, int out_size, void* d_ws, size_t ws_size,
                              hipStream_t stream) {
    (void)in_sizes; (void)n_in; (void)out_size;
    const float* F = (const float*)d_in[0];
    float* out = (float*)d_out;

    char* ws = (char*)d_ws;
    size_t off = 0;
    auto take = [&](size_t bytes) -> void* {
        void* p = ws + off;
        off += (bytes + 255) & ~(size_t)255;
        return p;
    };
    float* invnf = (float*)take((size_t)B * 4);
    float* dinv = (float*)take((size_t)B * 4);
    int* topk = (int*)take((size_t)B * KNN * 4);
    int* indeg = (int*)take((size_t)B * 4);
    int* roff = (int*)take((size_t)(B + 1) * 4);
    int* rfill = (int*)take((size_t)B * 4);
    int* ridx = (int*)take((size_t)B * KNN * 4);
    unsigned short* Xb = (unsigned short*)take((size_t)B * D * 2);
    unsigned short* Fb = (unsigned short*)take((size_t)B * D * 2);
    unsigned short* Yb = (unsigned short*)take((size_t)B * D * 2);
    unsigned short* FbT = (unsigned short*)take((size_t)D * B * 2);
    size_t fixed = off;

    int R = 2048;
    if (ws_size > 0) {
        while (R > 128 && fixed + (size_t)R * B * 4 > ws_size) R >>= 1;
    } else {
        R = 1024;
    }
    float* chunk = (float*)(ws + fixed);
    unsigned short* G1b = (unsigned short*)out;  // d_out as scratch for SpMM-1 (8 MB of 16)

    int SK = 8192 / R;
    if (SK > 8) SK = 8;
    int ksplit = B / SK;

    // 1. Xb / Fb / invnf; FbT = bf16 F^T
    k_norm<<<B, 128, 0, stream>>>(F, Xb, Fb, invnf);
    dim3 gt(B / 64, D / 64);
    k_transpose<<<gt, 256, 0, stream>>>(F, FbT);

    // 2. chunked: sim = Xb Xb^T + top-K
    for (int r0 = 0; r0 < B; r0 += R) {
        dim3 g(B / 128, R / 128);
        k_mfma_nt<<<g, 256, 0, stream>>>(Xb + (size_t)r0 * D, D, Xb, D, chunk, B, 0, D);
        k_topk2<<<R, 256, 0, stream>>>(chunk, topk, r0);
    }

    // 3. graph build
    k_zero2<<<B / 256, 256, 0, stream>>>(indeg, rfill);
    k_count<<<B * KNN / 256, 256, 0, stream>>>(topk, indeg);
    k_scan<<<1, 1024, 0, stream>>>(indeg, roff);
    k_dinv<<<B / 256, 256, 0, stream>>>(indeg, dinv);
    k_fill<<<B * KNN / 256, 256, 0, stream>>>(topk, roff, rfill, ridx);

    // 4. G1b = A_hat Fb (bf16); Yb = 10*Xhat + normalize(A_hat G1b)  (fused)
    k_spmm1<<<B, 128, 0, stream>>>(Fb, G1b, topk, roff, ridx, dinv);
    k_spmm2y<<<B, 128, 0, stream>>>(G1b, F, invnf, Yb, topk, roff, ridx, dinv);

    // 5. chunked: logits = Xb @ Yb^T (= 10*sim + cos) -> softmax -> out rows = W @ F
    for (int r0 = 0; r0 < B; r0 += R) {
        dim3 g(B / 128, R / 128);
        k_mfma_nt<<<g, 256, 0, stream>>>(Xb + (size_t)r0 * D, D, Yb, D, chunk, B, 0, D);
        k_softmax<<<R, 256, 0, stream>>>(chunk);
        float* part = chunk + 4096;
        dim3 gf(D / 128, R / 128, SK);
        k_mfma_nt<<<gf, 256, 0, stream>>>((const unsigned short*)chunk, 2 * B, FbT, B,
                                          part, B, D, ksplit);
        k_red<<<R / 2, 256, 0, stream>>>(part, out + (size_t)r0 * D, SK);
    }
}

// Round 9
// 783.943 us; speedup vs baseline: 6.8445x; 1.0265x over previous
//
#include <hip/hip_runtime.h>
#include <hip/hip_bf16.h>
#include <float.h>
#include <math.h>

constexpr int B = 8192;
constexpr int D = 512;
constexpr int KNN = 32;

typedef __attribute__((ext_vector_type(8))) short bhalf8;
typedef __attribute__((ext_vector_type(4))) float floatx4;

#if defined(__has_builtin)
#if __has_builtin(__builtin_amdgcn_global_load_lds)
#define HAS_GLD 1
#else
#define HAS_GLD 0
#endif
#else
#define HAS_GLD 0
#endif

__device__ __forceinline__ unsigned short f2bf(float f) {
    __hip_bfloat16 h = __float2bfloat16(f);
    return __builtin_bit_cast(unsigned short, h);
}

__device__ __forceinline__ float bf2f(unsigned short u) {
    unsigned int x = ((unsigned int)u) << 16;
    return __builtin_bit_cast(float, x);
}

__device__ __forceinline__ float waveReduceSum(float v) {
#pragma unroll
    for (int off = 32; off; off >>= 1) v += __shfl_down(v, off);
    return v;
}

// stage one 16B chunk of a 128x32-bf16 tile (linear LDS, 64B rows). (old 128^2 kernel)
__device__ __forceinline__ void stage_chunk(const unsigned short* __restrict__ g,
                                            char* __restrict__ lds_tile, int c) {
#if HAS_GLD
    char* wavebase = lds_tile + (size_t)(c & ~63) * 16;
    __builtin_amdgcn_global_load_lds((const __attribute__((address_space(1))) void*)g,
                                     (__attribute__((address_space(3))) void*)wavebase,
                                     16, 0, 0);
#else
    *(int4*)(lds_tile + (size_t)c * 16) = *(const int4*)g;
#endif
}

// ================= 8-phase 256x256 bf16 NT GEMM (m201-style) =================
// C[gm+i][gn+j] = A[gm+i,:] . Bm[gn+j,:], K multiple of 128.
// 512 threads = 8 waves (2M x 4N); per-wave 128x64 out; BK=64, 2 K-tiles/iter.
// LDS 128 KiB: A0,A1,B0,B1 tiles of [256][64] bf16, st-swizzled (slot ^= row&7)
// via pre-swizzled global source + swizzled ds_read (XOR involution).
__global__ __launch_bounds__(512) void k_mfma8(
    const unsigned short* __restrict__ A, int lda,
    const unsigned short* __restrict__ Bm, int ldb,
    float* __restrict__ C, int ldc, int Kd) {
    __shared__ __align__(16) char lds[131072];
    constexpr int AOFF0 = 0, AOFF1 = 32768, BOFF0 = 65536, BOFF1 = 98304;

    int tid = threadIdx.x;
    int lane = tid & 63;
    int wid = tid >> 6;
    int wm = (wid >> 2) * 128;  // 0 / 128
    int wn = (wid & 3) * 64;    // 0,64,128,192
    int lrow = lane & 15;
    int khi = lane >> 4;        // 0..3
    int lk7 = lane & 7;
    int gm = blockIdx.y * 256, gn = blockIdx.x * 256;

    floatx4 zero4 = {0.0f, 0.0f, 0.0f, 0.0f};
    floatx4 acc[8][4];
#pragma unroll
    for (int m = 0; m < 8; m++)
#pragma unroll
        for (int n = 0; n < 4; n++) acc[m][n] = zero4;
    bhalf8 bfrag[4][2];

    // stage one half-tile (128 rows x 64 cols bf16 = 16KB): 2 gld_lds/thread.
    // LDS dest linear; global source pre-swizzled so ds_read swizzle round-trips.
    auto stage_half = [&](const unsigned short* __restrict__ src, int ld,
                          int rowg0, int k0, int ldsbase) {
#pragma unroll
        for (int rd = 0; rd < 2; rd++) {
            int idx = rd * 512 + tid;
            int r = idx >> 3;
            int s = (idx & 7) ^ (r & 7);
            const unsigned short* g = src + (size_t)(rowg0 + r) * ld + k0 + s * 8;
#if HAS_GLD
            char* wb = lds + ldsbase + rd * 8192 + (tid >> 6) * 1024;
            __builtin_amdgcn_global_load_lds(
                (const __attribute__((address_space(1))) void*)g,
                (__attribute__((address_space(3))) void*)wb, 16, 0, 0);
#else
            *(int4*)(lds + ldsbase + (size_t)idx * 16) = *(const int4*)g;
#endif
        }
    };
    auto rdA = [&](int bufoff, int mf, int kk) -> bhalf8 {
        int r = wm + mf * 16 + lrow;
        int slot = ((kk << 2) + khi) ^ lk7;
        return *(const bhalf8*)(lds + bufoff + r * 128 + slot * 16);
    };
    auto rdB = [&](int bufoff, int nf, int kk) -> bhalf8 {
        int r = wn + nf * 16 + lrow;
        int slot = ((kk << 2) + khi) ^ lk7;
        return *(const bhalf8*)(lds + bufoff + r * 128 + slot * 16);
    };

    // ---- prologue: stage A-t0(2), B-t0(2), B-t1(2) = 12 loads ----
    stage_half(A, lda, gm, 0, AOFF0);
    stage_half(A, lda, gm + 128, 0, AOFF0 + 16384);
    stage_half(Bm, ldb, gn, 0, BOFF0);
    stage_half(Bm, ldb, gn + 128, 0, BOFF0 + 16384);
    stage_half(Bm, ldb, gn, 64, BOFF1);
    stage_half(Bm, ldb, gn + 128, 64, BOFF1 + 16384);
    asm volatile("s_waitcnt vmcnt(4)" ::: "memory");  // A-t0,B-t0 landed; B-t1 flying
    __builtin_amdgcn_s_barrier();

#define PH(mq, AO, BO, STAGE_STMT, TAIL_STMT)                                      \
    {                                                                              \
        if ((mq) == 0) {                                                           \
            _Pragma("unroll") for (int nf = 0; nf < 4; nf++) {                     \
                bfrag[nf][0] = rdB((BO), nf, 0);                                   \
                bfrag[nf][1] = rdB((BO), nf, 1);                                   \
            }                                                                      \
        }                                                                          \
        bhalf8 a00 = rdA((AO), 2 * (mq), 0);                                       \
        bhalf8 a01 = rdA((AO), 2 * (mq), 1);                                       \
        bhalf8 a10 = rdA((AO), 2 * (mq) + 1, 0);                                   \
        bhalf8 a11 = rdA((AO), 2 * (mq) + 1, 1);                                   \
        STAGE_STMT;                                                                \
        __builtin_amdgcn_s_barrier();                                              \
        asm volatile("s_waitcnt lgkmcnt(0)" ::: "memory");                         \
        __builtin_amdgcn_sched_barrier(0);                                         \
        __builtin_amdgcn_s_setprio(1);                                             \
        _Pragma("unroll") for (int nf = 0; nf < 4; nf++) {                         \
            acc[2 * (mq)][nf] = __builtin_amdgcn_mfma_f32_16x16x32_bf16(           \
                a00, bfrag[nf][0], acc[2 * (mq)][nf], 0, 0, 0);                    \
            acc[2 * (mq) + 1][nf] = __builtin_amdgcn_mfma_f32_16x16x32_bf16(       \
                a10, bfrag[nf][0], acc[2 * (mq) + 1][nf], 0, 0, 0);                \
        }                                                                          \
        _Pragma("unroll") for (int nf = 0; nf < 4; nf++) {                         \
            acc[2 * (mq)][nf] = __builtin_amdgcn_mfma_f32_16x16x32_bf16(           \
                a01, bfrag[nf][1], acc[2 * (mq)][nf], 0, 0, 0);                    \
            acc[2 * (mq) + 1][nf] = __builtin_amdgcn_mfma_f32_16x16x32_bf16(       \
                a11, bfrag[nf][1], acc[2 * (mq) + 1][nf], 0, 0, 0);                \
        }                                                                          \
        __builtin_amdgcn_s_setprio(0);                                             \
        TAIL_STMT;                                                                 \
        __builtin_amdgcn_s_barrier();                                              \
    }

    int iters = Kd >> 7;  // K / 128
    for (int it = 0; it < iters; ++it) {
        bool lastI = (it == iters - 1);
        int kodd = (2 * it + 1) << 6;
        int kne = (2 * it + 2) << 6;
        int kno = (2 * it + 3) << 6;
        // tail waits: before closing barrier of phases 3 and 7 (wait-then-barrier)
        PH(0, AOFF0, BOFF0, stage_half(A, lda, gm, kodd, AOFF1), );
        PH(1, AOFF0, BOFF0, stage_half(A, lda, gm + 128, kodd, AOFF1 + 16384), );
        PH(2, AOFF0, BOFF0, if (!lastI) stage_half(Bm, ldb, gn, kne, BOFF0), );
        PH(3, AOFF0, BOFF0, if (!lastI) stage_half(Bm, ldb, gn + 128, kne, BOFF0 + 16384),
           if (lastI) { asm volatile("s_waitcnt vmcnt(0)" ::: "memory"); } else {
               asm volatile("s_waitcnt vmcnt(4)" ::: "memory"); });
        PH(0 + 4 - 4, AOFF1, BOFF1, if (!lastI) stage_half(A, lda, gm, kne, AOFF0), );
        PH(1, AOFF1, BOFF1, if (!lastI) stage_half(A, lda, gm + 128, kne, AOFF0 + 16384), );
        PH(2, AOFF1, BOFF1, if (!lastI) stage_half(Bm, ldb, gn, kno, BOFF1), );
        PH(3, AOFF1, BOFF1, if (!lastI) stage_half(Bm, ldb, gn + 128, kno, BOFF1 + 16384),
           if (lastI) { asm volatile("s_waitcnt vmcnt(0)" ::: "memory"); } else {
               asm volatile("s_waitcnt vmcnt(4)" ::: "memory"); });
    }
#undef PH

    // epilogue: C/D layout col=lane&15, row=(lane>>4)*4+q [m89-verified]
#pragma unroll
    for (int mf = 0; mf < 8; mf++) {
#pragma unroll
        for (int nf = 0; nf < 4; nf++) {
            int cc = gn + wn + nf * 16 + lrow;
#pragma unroll
            for (int q = 0; q < 4; q++) {
                int r = gm + wm + mf * 16 + khi * 4 + q;
                C[(size_t)r * ldc + cc] = acc[mf][nf][q];
            }
        }
    }
}

// ---------------- bf16 MFMA GEMM, NT form (old 128^2; used for final GEMM) ----------
// Split-K via blockIdx.z: K-range [z*ksplit, (z+1)*ksplit), C += z*zstride.
__global__ __launch_bounds__(256, 2) void k_mfma_nt(
    const unsigned short* __restrict__ A, int lda,
    const unsigned short* __restrict__ B1, int ldb,
    float* __restrict__ C, int ldc, int zstride, int ksplit) {
    __shared__ __align__(16) char smem[2 * 8192];
    char* Asm = smem;
    char* B1sm = smem + 8192;

    int tid = threadIdx.x;
    int lane = tid & 63;
    int wid = tid >> 6;
    int wm = (wid >> 1) * 64, wn = (wid & 1) * 64;
    int lrow = lane & 15;
    int kh = lane >> 4;
    int gm = blockIdx.y * 128, gn = blockIdx.x * 128;
    int kbeg = blockIdx.z * ksplit;
    C += (size_t)blockIdx.z * zstride;

    floatx4 zero4 = {0.0f, 0.0f, 0.0f, 0.0f};
    floatx4 acc1[4][4];
#pragma unroll
    for (int m = 0; m < 4; m++)
#pragma unroll
        for (int n = 0; n < 4; n++) acc1[m][n] = zero4;

    for (int k0 = kbeg; k0 < kbeg + ksplit; k0 += 32) {
        __syncthreads();
#pragma unroll
        for (int p = 0; p < 2; p++) {
            int c = p * 256 + tid;
            int row = c >> 2;
            int col = (c & 3) * 8;
            stage_chunk(A + (size_t)(gm + row) * lda + k0 + col, Asm, c);
            stage_chunk(B1 + (size_t)(gn + row) * ldb + k0 + col, B1sm, c);
        }
        __syncthreads();

        bhalf8 a[4];
#pragma unroll
        for (int m = 0; m < 4; m++)
            a[m] = *(const bhalf8*)(Asm + (wm + m * 16 + lrow) * 64 + kh * 16);
#pragma unroll
        for (int n = 0; n < 4; n++) {
            bhalf8 b = *(const bhalf8*)(B1sm + (wn + n * 16 + lrow) * 64 + kh * 16);
#pragma unroll
            for (int m = 0; m < 4; m++)
                acc1[m][n] = __builtin_amdgcn_mfma_f32_16x16x32_bf16(a[m], b, acc1[m][n], 0, 0, 0);
        }
    }

#pragma unroll
    for (int m = 0; m < 4; m++) {
#pragma unroll
        for (int n = 0; n < 4; n++) {
            int cc = gn + wn + n * 16 + lrow;
#pragma unroll
            for (int q = 0; q < 4; q++) {
                int r = gm + wm + m * 16 + kh * 4 + q;
                C[(size_t)r * ldc + cc] = acc1[m][n][q];
            }
        }
    }
}

// ---------------- split-K reduce ----------------
__global__ __launch_bounds__(256) void k_red(const float* __restrict__ P,
                                             float* __restrict__ outp, int SK) {
    int idx = blockIdx.x * 256 + threadIdx.x;
    int lr = idx >> 7;
    int d4 = (idx & 127) * 4;
    const float* base = P + (size_t)lr * 8192 + d4;
    float4 s = *(const float4*)base;
    for (int p = 1; p < SK; p++) {
        float4 v = *(const float4*)(base + (size_t)p * 512);
        s.x += v.x; s.y += v.y; s.z += v.z; s.w += v.w;
    }
    *(float4*)(outp + (size_t)lr * 512 + d4) = s;
}

// ------- normalize rows of F -> bf16 Xb (normalized), bf16 Fb (raw), invnf -------
__global__ __launch_bounds__(128) void k_norm(const float* __restrict__ F,
                                              unsigned short* __restrict__ Xb,
                                              unsigned short* __restrict__ Fb,
                                              float* __restrict__ invnf) {
    int row = blockIdx.x, tid = threadIdx.x;
    float4 v = ((const float4*)(F + (size_t)row * D))[tid];
    float ss = v.x * v.x + v.y * v.y + v.z * v.z + v.w * v.w;
    ss = waveReduceSum(ss);
    __shared__ float s2[2];
    if ((tid & 63) == 0) s2[tid >> 6] = ss;
    __syncthreads();
    float inv = 1.0f / fmaxf(sqrtf(s2[0] + s2[1]), 1e-12f);
    if (tid == 0) invnf[row] = inv;
    union { unsigned short s[4]; int2 q; } ux, uf;
    ux.s[0] = f2bf(v.x * inv); ux.s[1] = f2bf(v.y * inv);
    ux.s[2] = f2bf(v.z * inv); ux.s[3] = f2bf(v.w * inv);
    uf.s[0] = f2bf(v.x); uf.s[1] = f2bf(v.y);
    uf.s[2] = f2bf(v.z); uf.s[3] = f2bf(v.w);
    *(int2*)(Xb + (size_t)row * D + tid * 4) = ux.q;
    *(int2*)(Fb + (size_t)row * D + tid * 4) = uf.q;
}

// ---------------- transpose F (fp32 BxD) -> FbT (bf16 DxB) ----------------
__global__ __launch_bounds__(256) void k_transpose(const float* __restrict__ F,
                                                   unsigned short* __restrict__ FbT) {
    __shared__ float t[64][65];
    int r0 = blockIdx.x * 64, d0 = blockIdx.y * 64;
    int tid = threadIdx.x;
#pragma unroll
    for (int p = 0; p < 4; p++) {
        int idx = p * 256 + tid;
        int r = idx >> 4, c4 = (idx & 15) * 4;
        float4 v = *(const float4*)(F + (size_t)(r0 + r) * D + d0 + c4);
        t[r][c4 + 0] = v.x; t[r][c4 + 1] = v.y; t[r][c4 + 2] = v.z; t[r][c4 + 3] = v.w;
    }
    __syncthreads();
#pragma unroll
    for (int p = 0; p < 2; p++) {
        int idx = p * 256 + tid;
        int d = idx >> 3, rc = (idx & 7) * 8;
        union { unsigned short s[8]; int4 v; } u;
#pragma unroll
        for (int j = 0; j < 8; j++) u.s[j] = f2bf(t[rc + j][d]);
        *(int4*)(FbT + (size_t)(d0 + d) * B + r0 + rc) = u.v;
    }
}

// ---------------- top-K: 12-bit radix histogram select + exact candidate argmax ------
__global__ __launch_bounds__(256) void k_topk2(const float* __restrict__ S,
                                               int* __restrict__ topk, int r0) {
    __shared__ int hist[4096];
    __shared__ int totals[256];
    __shared__ int cslot[2][4];
    __shared__ int islot[4];
    __shared__ unsigned long long buf[128];
    __shared__ int outIdx[KNN];
    __shared__ int ccount;
    __shared__ int sbin;
    __shared__ int sSb;
    int li = blockIdx.x, tid = threadIdx.x;
    int i = r0 + li;
    const float* rp = S + (size_t)li * B;

    unsigned int key[32];
#pragma unroll
    for (int j8 = 0; j8 < 8; j8++) {
        float4 v = *(const float4*)(rp + j8 * 1024 + tid * 4);
        float fv[4] = {v.x, v.y, v.z, v.w};
#pragma unroll
        for (int q = 0; q < 4; q++) {
            int col = j8 * 1024 + tid * 4 + q;
            unsigned int u = __builtin_bit_cast(unsigned int, fv[q]);
            unsigned int k = u ^ ((u & 0x80000000u) ? 0xFFFFFFFFu : 0x80000000u);
            key[j8 * 4 + q] = (col == i) ? 0u : k;
        }
    }

#pragma unroll
    for (int j = 0; j < 16; j++) hist[tid * 16 + j] = 0;
    if (tid == 0) { sbin = -1; ccount = 0; }
    __syncthreads();

#pragma unroll
    for (int j = 0; j < 32; j++) atomicAdd(&hist[key[j] >> 20], 1);
    __syncthreads();

    int base = tid * 16;
    {
        int s = 0;
#pragma unroll
        for (int j = 0; j < 16; j++) s += hist[base + j];
        totals[tid] = s;
    }
    __syncthreads();
    for (int off = 1; off < 256; off <<= 1) {
        int v = (tid + off < 256) ? totals[tid + off] : 0;
        __syncthreads();
        totals[tid] += v;
        __syncthreads();
    }
    int nextT = (tid < 255) ? totals[tid + 1] : 0;

    {
        int bestj = -1;
        int s2 = nextT;
#pragma unroll
        for (int j = 15; j >= 0; j--) {
            s2 += hist[base + j];
            if (s2 >= KNN && bestj < 0) bestj = base + j;
        }
        if (bestj >= 0) atomicMax(&sbin, bestj);
    }
    __syncthreads();
    int b = sbin;
    if (tid == (b >> 4)) {
        int s2 = nextT;
        for (int j = 15; j >= (b & 15); j--) s2 += hist[(b & ~15) + j];
        sSb = s2;
    }
    __syncthreads();
    int Sb = sSb;

    unsigned int T = 0;
    bool found = false;
    if (Sb <= 128) {
        T = (((unsigned int)b) << 20) - 1u;
        found = true;
    } else {
        unsigned int lo = (b == 0) ? 0u : ((((unsigned int)b) << 20) - 1u);
        unsigned int hi = (((unsigned int)(b + 1)) << 20) - 1u;
        for (int it = 0; it < 33; ++it) {
            unsigned int mid = lo + ((hi - lo) >> 1);
            if (mid == lo) break;
            int c = 0;
#pragma unroll
            for (int j = 0; j < 32; j++) c += (key[j] > mid) ? 1 : 0;
#pragma unroll
            for (int off = 32; off; off >>= 1) c += __shfl_down(c, off);
            if ((tid & 63) == 0) cslot[it & 1][tid >> 6] = c;
            __syncthreads();
            int tot = cslot[it & 1][0] + cslot[it & 1][1] + cslot[it & 1][2] + cslot[it & 1][3];
            if (tot >= KNN && tot <= 128) { T = mid; found = true; break; }
            if (tot < KNN) hi = mid; else lo = mid;
        }
        if (!found) T = hi;
    }
    __syncthreads();

#pragma unroll
    for (int j8 = 0; j8 < 8; j8++) {
#pragma unroll
        for (int q = 0; q < 4; q++) {
            int j = j8 * 4 + q;
            if (key[j] > T) {
                int p = atomicAdd(&ccount, 1);
                if (p < 128) {
                    int col = j8 * 1024 + tid * 4 + q;
                    buf[p] = ((unsigned long long)key[j] << 13) |
                             (unsigned long long)(8191 - col);
                }
            }
        }
    }
    __syncthreads();
    int C = ccount < 128 ? ccount : 128;

    if (tid < 64) {
        unsigned long long p0 = (tid < C) ? buf[tid] : 0ull;
        unsigned long long p1 = (tid + 64 < C) ? buf[tid + 64] : 0ull;
        for (int it = 0; it < KNN; ++it) {
            unsigned long long m = (p0 > p1) ? p0 : p1;
#pragma unroll
            for (int off = 32; off; off >>= 1) {
                unsigned long long o = __shfl_down(m, off);
                m = (o > m) ? o : m;
            }
            m = __shfl(m, 0);
            if (tid == 0 && m != 0ull) outIdx[it] = 8191 - (int)(m & 0x1FFFull);
            if (p0 == m) p0 = 0ull; else if (p1 == m) p1 = 0ull;
        }
    }
    __syncthreads();

    if (C < KNN) {
        int last = -1;
        for (int it = C; it < KNN; ++it) {
            int best = 0x7fffffff;
#pragma unroll
            for (int j8 = 0; j8 < 8; j8++) {
#pragma unroll
                for (int q = 0; q < 4; q++) {
                    int j = j8 * 4 + q;
                    int col = j8 * 1024 + tid * 4 + q;
                    if (key[j] == T && col > last && col < best) best = col;
                }
            }
#pragma unroll
            for (int off = 32; off; off >>= 1) {
                int o = __shfl_down(best, off);
                best = (o < best) ? o : best;
            }
            if ((tid & 63) == 0) islot[tid >> 6] = best;
            __syncthreads();
            best = min(min(islot[0], islot[1]), min(islot[2], islot[3]));
            if (tid == 0) outIdx[it] = best;
            last = best;
            __syncthreads();
        }
    }
    __syncthreads();
    if (tid < KNN) topk[(size_t)i * KNN + tid] = outIdx[tid];
}

// ---------------- graph build ----------------
__global__ void k_zero2(int* __restrict__ a, int* __restrict__ b) {
    int i = blockIdx.x * 256 + threadIdx.x;
    a[i] = 0;
    b[i] = 0;
}

__global__ void k_count(const int* __restrict__ topk, int* __restrict__ indeg) {
    int e = blockIdx.x * 256 + threadIdx.x;
    atomicAdd(&indeg[topk[e]], 1);
}

__global__ __launch_bounds__(1024) void k_scan(const int* __restrict__ indeg,
                                               int* __restrict__ roff) {
    __shared__ int sums[1024];
    int tid = threadIdx.x;
    int base = tid * 8;
    int loc[8];
    int s = 0;
#pragma unroll
    for (int j = 0; j < 8; j++) { loc[j] = s; s += indeg[base + j]; }
    sums[tid] = s;
    __syncthreads();
    for (int off = 1; off < 1024; off <<= 1) {
        int v = (tid >= off) ? sums[tid - off] : 0;
        __syncthreads();
        sums[tid] += v;
        __syncthreads();
    }
    int prev = (tid > 0) ? sums[tid - 1] : 0;
#pragma unroll
    for (int j = 0; j < 8; j++) roff[base + j] = prev + loc[j];
    if (tid == 1023) roff[B] = sums[1023];
}

__global__ void k_dinv(const int* __restrict__ indeg, float* __restrict__ dinv) {
    int i = blockIdx.x * 256 + threadIdx.x;
    float dg = (float)(KNN + indeg[i]);
    dinv[i] = fminf(1.0f / sqrtf(dg), 1e6f);
}

__global__ void k_fill(const int* __restrict__ topk, const int* __restrict__ roff,
                       int* __restrict__ fill, int* __restrict__ ridx) {
    int e = blockIdx.x * 256 + threadIdx.x;
    int dst = topk[e];
    int src = e >> 5;
    int pos = atomicAdd(&fill[dst], 1);
    ridx[roff[dst] + pos] = src;
}

// ------- SpMM 1: G1b (bf16) = A_hat @ Fb, gather in bf16, int4-batched indices -------
__global__ __launch_bounds__(128) void k_spmm1(const unsigned short* __restrict__ Fb,
                                               unsigned short* __restrict__ G1b,
                                               const int* __restrict__ topk,
                                               const int* __restrict__ roff,
                                               const int* __restrict__ ridx,
                                               const float* __restrict__ dinv) {
    int i = blockIdx.x, tid = threadIdx.x;
    float a0 = 0, a1 = 0, a2 = 0, a3 = 0;
    const int* ti = topk + (size_t)i * KNN;
#pragma unroll
    for (int k4 = 0; k4 < KNN / 4; k4++) {
        int4 nn = *(const int4*)(ti + k4 * 4);
        float w0 = dinv[nn.x], w1 = dinv[nn.y], w2 = dinv[nn.z], w3 = dinv[nn.w];
        int2 p0 = *(const int2*)(Fb + (size_t)nn.x * D + tid * 4);
        int2 p1 = *(const int2*)(Fb + (size_t)nn.y * D + tid * 4);
        int2 p2 = *(const int2*)(Fb + (size_t)nn.z * D + tid * 4);
        int2 p3 = *(const int2*)(Fb + (size_t)nn.w * D + tid * 4);
        const unsigned short* u0 = (const unsigned short*)&p0;
        const unsigned short* u1 = (const unsigned short*)&p1;
        const unsigned short* u2 = (const unsigned short*)&p2;
        const unsigned short* u3 = (const unsigned short*)&p3;
        a0 += w0 * bf2f(u0[0]) + w1 * bf2f(u1[0]) + w2 * bf2f(u2[0]) + w3 * bf2f(u3[0]);
        a1 += w0 * bf2f(u0[1]) + w1 * bf2f(u1[1]) + w2 * bf2f(u2[1]) + w3 * bf2f(u3[1]);
        a2 += w0 * bf2f(u0[2]) + w1 * bf2f(u1[2]) + w2 * bf2f(u2[2]) + w3 * bf2f(u3[2]);
        a3 += w0 * bf2f(u0[3]) + w1 * bf2f(u1[3]) + w2 * bf2f(u2[3]) + w3 * bf2f(u3[3]);
    }
    int s = roff[i], e = roff[i + 1];
    int t = s;
    for (; t + 2 <= e; t += 2) {
        int j0 = ridx[t], j1 = ridx[t + 1];
        float w0 = dinv[j0], w1 = dinv[j1];
        int2 p0 = *(const int2*)(Fb + (size_t)j0 * D + tid * 4);
        int2 p1 = *(const int2*)(Fb + (size_t)j1 * D + tid * 4);
        const unsigned short* u0 = (const unsigned short*)&p0;
        const unsigned short* u1 = (const unsigned short*)&p1;
        a0 += w0 * bf2f(u0[0]) + w1 * bf2f(u1[0]);
        a1 += w0 * bf2f(u0[1]) + w1 * bf2f(u1[1]);
        a2 += w0 * bf2f(u0[2]) + w1 * bf2f(u1[2]);
        a3 += w0 * bf2f(u0[3]) + w1 * bf2f(u1[3]);
    }
    if (t < e) {
        int j0 = ridx[t];
        float w0 = dinv[j0];
        int2 p0 = *(const int2*)(Fb + (size_t)j0 * D + tid * 4);
        const unsigned short* u0 = (const unsigned short*)&p0;
        a0 += w0 * bf2f(u0[0]); a1 += w0 * bf2f(u0[1]);
        a2 += w0 * bf2f(u0[2]); a3 += w0 * bf2f(u0[3]);
    }
    float wi = dinv[i];
    union { unsigned short s4[4]; int2 q; } u;
    u.s4[0] = f2bf(wi * a0); u.s4[1] = f2bf(wi * a1);
    u.s4[2] = f2bf(wi * a2); u.s4[3] = f2bf(wi * a3);
    *(int2*)(G1b + (size_t)i * D + tid * 4) = u.q;
}

// ------- SpMM 2 fused with Yb build -------
__global__ __launch_bounds__(128) void k_spmm2y(const unsigned short* __restrict__ G1b,
                                                const float* __restrict__ F,
                                                const float* __restrict__ invnf,
                                                unsigned short* __restrict__ Yb,
                                                const int* __restrict__ topk,
                                                const int* __restrict__ roff,
                                                const int* __restrict__ ridx,
                                                const float* __restrict__ dinv) {
    int i = blockIdx.x, tid = threadIdx.x;
    float a0 = 0, a1 = 0, a2 = 0, a3 = 0;
    const int* ti = topk + (size_t)i * KNN;
#pragma unroll
    for (int k4 = 0; k4 < KNN / 4; k4++) {
        int4 nn = *(const int4*)(ti + k4 * 4);
        float w0 = dinv[nn.x], w1 = dinv[nn.y], w2 = dinv[nn.z], w3 = dinv[nn.w];
        int2 p0 = *(const int2*)(G1b + (size_t)nn.x * D + tid * 4);
        int2 p1 = *(const int2*)(G1b + (size_t)nn.y * D + tid * 4);
        int2 p2 = *(const int2*)(G1b + (size_t)nn.z * D + tid * 4);
        int2 p3 = *(const int2*)(G1b + (size_t)nn.w * D + tid * 4);
        const unsigned short* u0 = (const unsigned short*)&p0;
        const unsigned short* u1 = (const unsigned short*)&p1;
        const unsigned short* u2 = (const unsigned short*)&p2;
        const unsigned short* u3 = (const unsigned short*)&p3;
        a0 += w0 * bf2f(u0[0]) + w1 * bf2f(u1[0]) + w2 * bf2f(u2[0]) + w3 * bf2f(u3[0]);
        a1 += w0 * bf2f(u0[1]) + w1 * bf2f(u1[1]) + w2 * bf2f(u2[1]) + w3 * bf2f(u3[1]);
        a2 += w0 * bf2f(u0[2]) + w1 * bf2f(u1[2]) + w2 * bf2f(u2[2]) + w3 * bf2f(u3[2]);
        a3 += w0 * bf2f(u0[3]) + w1 * bf2f(u1[3]) + w2 * bf2f(u2[3]) + w3 * bf2f(u3[3]);
    }
    int s = roff[i], e = roff[i + 1];
    int t = s;
    for (; t + 2 <= e; t += 2) {
        int j0 = ridx[t], j1 = ridx[t + 1];
        float w0 = dinv[j0], w1 = dinv[j1];
        int2 p0 = *(const int2*)(G1b + (size_t)j0 * D + tid * 4);
        int2 p1 = *(const int2*)(G1b + (size_t)j1 * D + tid * 4);
        const unsigned short* u0 = (const unsigned short*)&p0;
        const unsigned short* u1 = (const unsigned short*)&p1;
        a0 += w0 * bf2f(u0[0]) + w1 * bf2f(u1[0]);
        a1 += w0 * bf2f(u0[1]) + w1 * bf2f(u1[1]);
        a2 += w0 * bf2f(u0[2]) + w1 * bf2f(u1[2]);
        a3 += w0 * bf2f(u0[3]) + w1 * bf2f(u1[3]);
    }
    if (t < e) {
        int j0 = ridx[t];
        float w0 = dinv[j0];
        int2 p0 = *(const int2*)(G1b + (size_t)j0 * D + tid * 4);
        const unsigned short* u0 = (const unsigned short*)&p0;
        a0 += w0 * bf2f(u0[0]); a1 += w0 * bf2f(u0[1]);
        a2 += w0 * bf2f(u0[2]); a3 += w0 * bf2f(u0[3]);
    }
    float wi = dinv[i];
    float g0 = wi * a0, g1 = wi * a1, g2 = wi * a2, g3 = wi * a3;

    float ss = g0 * g0 + g1 * g1 + g2 * g2 + g3 * g3;
    ss = waveReduceSum(ss);
    __shared__ float s2[2];
    if ((tid & 63) == 0) s2[tid >> 6] = ss;
    __syncthreads();
    float invng = 1.0f / fmaxf(sqrtf(s2[0] + s2[1]), 1e-12f);

    float4 f = ((const float4*)(F + (size_t)i * D))[tid];
    float inf_ = 10.0f * invnf[i];
    union { unsigned short s4[4]; int2 q; } u;
    u.s4[0] = f2bf(f.x * inf_ + g0 * invng);
    u.s4[1] = f2bf(f.y * inf_ + g1 * invng);
    u.s4[2] = f2bf(f.z * inf_ + g2 * invng);
    u.s4[3] = f2bf(f.w * inf_ + g3 * invng);
    *(int2*)(Yb + (size_t)i * D + tid * 4) = u.q;
}

// ------- register-resident online row softmax; writes bf16 weights in place ----------
__global__ __launch_bounds__(256) void k_softmax(float* __restrict__ chunk) {
    __shared__ float sm[4], sl[4];
    int li = blockIdx.x, tid = threadIdx.x;
    float* rp = chunk + (size_t)li * B;
    float4 v[8];
    float mt = -FLT_MAX;
#pragma unroll
    for (int p = 0; p < 8; p++) {
        v[p] = *(const float4*)(rp + p * 1024 + tid * 4);
        mt = fmaxf(mt, fmaxf(fmaxf(v[p].x, v[p].y), fmaxf(v[p].z, v[p].w)));
    }
    float l = 0.0f;
#pragma unroll
    for (int p = 0; p < 8; p++) {
        v[p].x = __expf(v[p].x - mt);
        v[p].y = __expf(v[p].y - mt);
        v[p].z = __expf(v[p].z - mt);
        v[p].w = __expf(v[p].w - mt);
        l += v[p].x + v[p].y + v[p].z + v[p].w;
    }
    float m = mt, lw = l;
#pragma unroll
    for (int off = 32; off; off >>= 1) {
        float om = __shfl_down(m, off);
        float ol = __shfl_down(lw, off);
        float nm = fmaxf(m, om);
        lw = lw * __expf(m - nm) + ol * __expf(om - nm);
        m = nm;
    }
    if ((tid & 63) == 0) { sm[tid >> 6] = m; sl[tid >> 6] = lw; }
    __syncthreads();
    float M = fmaxf(fmaxf(sm[0], sm[1]), fmaxf(sm[2], sm[3]));
    float L = sl[0] * __expf(sm[0] - M) + sl[1] * __expf(sm[1] - M) +
              sl[2] * __expf(sm[2] - M) + sl[3] * __expf(sm[3] - M);
    float fct = __expf(mt - M) / L;
    unsigned short* wp = (unsigned short*)rp;
#pragma unroll
    for (int p = 0; p < 8; p++) {
        union { unsigned short s[4]; int2 q; } u;
        u.s[0] = f2bf(v[p].x * fct);
        u.s[1] = f2bf(v[p].y * fct);
        u.s[2] = f2bf(v[p].z * fct);
        u.s[3] = f2bf(v[p].w * fct);
        *(int2*)(wp + p * 1024 + tid * 4) = u.q;
    }
}

extern "C" void kernel_launch(void* const* d_in, const int* in_sizes, int n_in,
                              void* d_out, int out_size, void* d_ws, size_t ws_size,
                              hipStream_t stream) {
    (void)in_sizes; (void)n_in; (void)out_size;
    const float* F = (const float*)d_in[0];
    float* out = (float*)d_out;

    char* ws = (char*)d_ws;
    size_t off = 0;
    auto take = [&](size_t bytes) -> void* {
        void* p = ws + off;
        off += (bytes + 255) & ~(size_t)255;
        return p;
    };
    float* invnf = (float*)take((size_t)B * 4);
    float* dinv = (float*)take((size_t)B * 4);
    int* topk = (int*)take((size_t)B * KNN * 4);
    int* indeg = (int*)take((size_t)B * 4);
    int* roff = (int*)take((size_t)(B + 1) * 4);
    int* rfill = (int*)take((size_t)B * 4);
    int* ridx = (int*)take((size_t)B * KNN * 4);
    unsigned short* Xb = (unsigned short*)take((size_t)B * D * 2);
    unsigned short* Fb = (unsigned short*)take((size_t)B * D * 2);
    unsigned short* Yb = (unsigned short*)take((size_t)B * D * 2);
    unsigned short* FbT = (unsigned short*)take((size_t)D * B * 2);
    size_t fixed = off;

    int R = 2048;
    if (ws_size > 0) {
        while (R > 128 && fixed + (size_t)R * B * 4 > ws_size) R >>= 1;
    } else {
        R = 1024;
    }
    float* chunk = (float*)(ws + fixed);
    unsigned short* G1b = (unsigned short*)out;

    int SK = 8192 / R;
    if (SK > 8) SK = 8;
    int ksplit = B / SK;
    bool use8 = (R % 256) == 0;

    // 1. Xb / Fb / invnf; FbT = bf16 F^T
    k_norm<<<B, 128, 0, stream>>>(F, Xb, Fb, invnf);
    dim3 gt(B / 64, D / 64);
    k_transpose<<<gt, 256, 0, stream>>>(F, FbT);

    // 2. chunked: sim = Xb Xb^T + top-K
    for (int r0 = 0; r0 < B; r0 += R) {
        if (use8) {
            dim3 g8(B / 256, R / 256);
            k_mfma8<<<g8, 512, 0, stream>>>(Xb + (size_t)r0 * D, D, Xb, D, chunk, B, D);
        } else {
            dim3 g(B / 128, R / 128);
            k_mfma_nt<<<g, 256, 0, stream>>>(Xb + (size_t)r0 * D, D, Xb, D, chunk, B, 0, D);
        }
        k_topk2<<<R, 256, 0, stream>>>(chunk, topk, r0);
    }

    // 3. graph build
    k_zero2<<<B / 256, 256, 0, stream>>>(indeg, rfill);
    k_count<<<B * KNN / 256, 256, 0, stream>>>(topk, indeg);
    k_scan<<<1, 1024, 0, stream>>>(indeg, roff);
    k_dinv<<<B / 256, 256, 0, stream>>>(indeg, dinv);
    k_fill<<<B * KNN / 256, 256, 0, stream>>>(topk, roff, rfill, ridx);

    // 4. G1b = A_hat Fb; Yb = 10*Xhat + normalize(A_hat G1b)
    k_spmm1<<<B, 128, 0, stream>>>(Fb, G1b, topk, roff, ridx, dinv);
    k_spmm2y<<<B, 128, 0, stream>>>(G1b, F, invnf, Yb, topk, roff, ridx, dinv);

    // 5. chunked: logits = Xb @ Yb^T -> softmax -> out rows = W @ F
    for (int r0 = 0; r0 < B; r0 += R) {
        if (use8) {
            dim3 g8(B / 256, R / 256);
            k_mfma8<<<g8, 512, 0, stream>>>(Xb + (size_t)r0 * D, D, Yb, D, chunk, B, D);
        } else {
            dim3 g(B / 128, R / 128);
            k_mfma_nt<<<g, 256, 0, stream>>>(Xb + (size_t)r0 * D, D, Yb, D, chunk, B, 0, D);
        }
        k_softmax<<<R, 256, 0, stream>>>(chunk);
        float* part = chunk + 4096;
        dim3 gf(D / 128, R / 128, SK);
        k_mfma_nt<<<gf, 256, 0, stream>>>((const unsigned short*)chunk, 2 * B, FbT, B,
                                          part, B, D, ksplit);
        k_red<<<R / 2, 256, 0, stream>>>(part, out + (size_t)r0 * D, SK);
    }
}

// Round 10
// 780.060 us; speedup vs baseline: 6.8786x; 1.0050x over previous
//
#include <hip/hip_runtime.h>
#include <hip/hip_bf16.h>
#include <float.h>
#include <math.h>

constexpr int B = 8192;
constexpr int D = 512;
constexpr int KNN = 32;

typedef __attribute__((ext_vector_type(8))) short bhalf8;
typedef __attribute__((ext_vector_type(4))) float floatx4;

#if defined(__has_builtin)
#if __has_builtin(__builtin_amdgcn_global_load_lds)
#define HAS_GLD 1
#else
#define HAS_GLD 0
#endif
#else
#define HAS_GLD 0
#endif

__device__ __forceinline__ unsigned short f2bf(float f) {
    __hip_bfloat16 h = __float2bfloat16(f);
    return __builtin_bit_cast(unsigned short, h);
}

__device__ __forceinline__ float bf2f(unsigned short u) {
    unsigned int x = ((unsigned int)u) << 16;
    return __builtin_bit_cast(float, x);
}

__device__ __forceinline__ float waveReduceSum(float v) {
#pragma unroll
    for (int off = 32; off; off >>= 1) v += __shfl_down(v, off);
    return v;
}

// stage one 16B chunk of a 128x32-bf16 tile (linear LDS, 64B rows). (old 128^2 kernel)
__device__ __forceinline__ void stage_chunk(const unsigned short* __restrict__ g,
                                            char* __restrict__ lds_tile, int c) {
#if HAS_GLD
    char* wavebase = lds_tile + (size_t)(c & ~63) * 16;
    __builtin_amdgcn_global_load_lds((const __attribute__((address_space(1))) void*)g,
                                     (__attribute__((address_space(3))) void*)wavebase,
                                     16, 0, 0);
#else
    *(int4*)(lds_tile + (size_t)c * 16) = *(const int4*)g;
#endif
}

// ================= 8-phase 256x256 bf16 NT GEMM (m201-style) =================
__global__ __launch_bounds__(512) void k_mfma8(
    const unsigned short* __restrict__ A, int lda,
    const unsigned short* __restrict__ Bm, int ldb,
    float* __restrict__ C, int ldc, int Kd) {
    __shared__ __align__(16) char lds[131072];
    constexpr int AOFF0 = 0, AOFF1 = 32768, BOFF0 = 65536, BOFF1 = 98304;

    int tid = threadIdx.x;
    int lane = tid & 63;
    int wid = tid >> 6;
    int wm = (wid >> 2) * 128;
    int wn = (wid & 3) * 64;
    int lrow = lane & 15;
    int khi = lane >> 4;
    int lk7 = lane & 7;
    int gm = blockIdx.y * 256, gn = blockIdx.x * 256;

    floatx4 zero4 = {0.0f, 0.0f, 0.0f, 0.0f};
    floatx4 acc[8][4];
#pragma unroll
    for (int m = 0; m < 8; m++)
#pragma unroll
        for (int n = 0; n < 4; n++) acc[m][n] = zero4;
    bhalf8 bfrag[4][2];

    auto stage_half = [&](const unsigned short* __restrict__ src, int ld,
                          int rowg0, int k0, int ldsbase) {
#pragma unroll
        for (int rd = 0; rd < 2; rd++) {
            int idx = rd * 512 + tid;
            int r = idx >> 3;
            int s = (idx & 7) ^ (r & 7);
            const unsigned short* g = src + (size_t)(rowg0 + r) * ld + k0 + s * 8;
#if HAS_GLD
            char* wb = lds + ldsbase + rd * 8192 + (tid >> 6) * 1024;
            __builtin_amdgcn_global_load_lds(
                (const __attribute__((address_space(1))) void*)g,
                (__attribute__((address_space(3))) void*)wb, 16, 0, 0);
#else
            *(int4*)(lds + ldsbase + (size_t)idx * 16) = *(const int4*)g;
#endif
        }
    };
    auto rdA = [&](int bufoff, int mf, int kk) -> bhalf8 {
        int r = wm + mf * 16 + lrow;
        int slot = ((kk << 2) + khi) ^ lk7;
        return *(const bhalf8*)(lds + bufoff + r * 128 + slot * 16);
    };
    auto rdB = [&](int bufoff, int nf, int kk) -> bhalf8 {
        int r = wn + nf * 16 + lrow;
        int slot = ((kk << 2) + khi) ^ lk7;
        return *(const bhalf8*)(lds + bufoff + r * 128 + slot * 16);
    };

    stage_half(A, lda, gm, 0, AOFF0);
    stage_half(A, lda, gm + 128, 0, AOFF0 + 16384);
    stage_half(Bm, ldb, gn, 0, BOFF0);
    stage_half(Bm, ldb, gn + 128, 0, BOFF0 + 16384);
    stage_half(Bm, ldb, gn, 64, BOFF1);
    stage_half(Bm, ldb, gn + 128, 64, BOFF1 + 16384);
    asm volatile("s_waitcnt vmcnt(4)" ::: "memory");
    __builtin_amdgcn_s_barrier();

#define PH(mq, AO, BO, STAGE_STMT, TAIL_STMT)                                      \
    {                                                                              \
        if ((mq) == 0) {                                                           \
            _Pragma("unroll") for (int nf = 0; nf < 4; nf++) {                     \
                bfrag[nf][0] = rdB((BO), nf, 0);                                   \
                bfrag[nf][1] = rdB((BO), nf, 1);                                   \
            }                                                                      \
        }                                                                          \
        bhalf8 a00 = rdA((AO), 2 * (mq), 0);                                       \
        bhalf8 a01 = rdA((AO), 2 * (mq), 1);                                       \
        bhalf8 a10 = rdA((AO), 2 * (mq) + 1, 0);                                   \
        bhalf8 a11 = rdA((AO), 2 * (mq) + 1, 1);                                   \
        STAGE_STMT;                                                                \
        __builtin_amdgcn_s_barrier();                                              \
        asm volatile("s_waitcnt lgkmcnt(0)" ::: "memory");                         \
        __builtin_amdgcn_sched_barrier(0);                                         \
        __builtin_amdgcn_s_setprio(1);                                             \
        _Pragma("unroll") for (int nf = 0; nf < 4; nf++) {                         \
            acc[2 * (mq)][nf] = __builtin_amdgcn_mfma_f32_16x16x32_bf16(           \
                a00, bfrag[nf][0], acc[2 * (mq)][nf], 0, 0, 0);                    \
            acc[2 * (mq) + 1][nf] = __builtin_amdgcn_mfma_f32_16x16x32_bf16(       \
                a10, bfrag[nf][0], acc[2 * (mq) + 1][nf], 0, 0, 0);                \
        }                                                                          \
        _Pragma("unroll") for (int nf = 0; nf < 4; nf++) {                         \
            acc[2 * (mq)][nf] = __builtin_amdgcn_mfma_f32_16x16x32_bf16(           \
                a01, bfrag[nf][1], acc[2 * (mq)][nf], 0, 0, 0);                    \
            acc[2 * (mq) + 1][nf] = __builtin_amdgcn_mfma_f32_16x16x32_bf16(       \
                a11, bfrag[nf][1], acc[2 * (mq) + 1][nf], 0, 0, 0);                \
        }                                                                          \
        __builtin_amdgcn_s_setprio(0);                                             \
        TAIL_STMT;                                                                 \
        __builtin_amdgcn_s_barrier();                                              \
    }

    int iters = Kd >> 7;
    for (int it = 0; it < iters; ++it) {
        bool lastI = (it == iters - 1);
        int kodd = (2 * it + 1) << 6;
        int kne = (2 * it + 2) << 6;
        int kno = (2 * it + 3) << 6;
        PH(0, AOFF0, BOFF0, stage_half(A, lda, gm, kodd, AOFF1), );
        PH(1, AOFF0, BOFF0, stage_half(A, lda, gm + 128, kodd, AOFF1 + 16384), );
        PH(2, AOFF0, BOFF0, if (!lastI) stage_half(Bm, ldb, gn, kne, BOFF0), );
        PH(3, AOFF0, BOFF0, if (!lastI) stage_half(Bm, ldb, gn + 128, kne, BOFF0 + 16384),
           if (lastI) { asm volatile("s_waitcnt vmcnt(0)" ::: "memory"); } else {
               asm volatile("s_waitcnt vmcnt(4)" ::: "memory"); });
        PH(0, AOFF1, BOFF1, if (!lastI) stage_half(A, lda, gm, kne, AOFF0), );
        PH(1, AOFF1, BOFF1, if (!lastI) stage_half(A, lda, gm + 128, kne, AOFF0 + 16384), );
        PH(2, AOFF1, BOFF1, if (!lastI) stage_half(Bm, ldb, gn, kno, BOFF1), );
        PH(3, AOFF1, BOFF1, if (!lastI) stage_half(Bm, ldb, gn + 128, kno, BOFF1 + 16384),
           if (lastI) { asm volatile("s_waitcnt vmcnt(0)" ::: "memory"); } else {
               asm volatile("s_waitcnt vmcnt(4)" ::: "memory"); });
    }
#undef PH

#pragma unroll
    for (int mf = 0; mf < 8; mf++) {
#pragma unroll
        for (int nf = 0; nf < 4; nf++) {
            int cc = gn + wn + nf * 16 + lrow;
#pragma unroll
            for (int q = 0; q < 4; q++) {
                int r = gm + wm + mf * 16 + khi * 4 + q;
                C[(size_t)r * ldc + cc] = acc[mf][nf][q];
            }
        }
    }
}

// ---------------- bf16 MFMA GEMM, NT form (old 128^2; used for final GEMM) ----------
__global__ __launch_bounds__(256, 2) void k_mfma_nt(
    const unsigned short* __restrict__ A, int lda,
    const unsigned short* __restrict__ B1, int ldb,
    float* __restrict__ C, int ldc, int zstride, int ksplit) {
    __shared__ __align__(16) char smem[2 * 8192];
    char* Asm = smem;
    char* B1sm = smem + 8192;

    int tid = threadIdx.x;
    int lane = tid & 63;
    int wid = tid >> 6;
    int wm = (wid >> 1) * 64, wn = (wid & 1) * 64;
    int lrow = lane & 15;
    int kh = lane >> 4;
    int gm = blockIdx.y * 128, gn = blockIdx.x * 128;
    int kbeg = blockIdx.z * ksplit;
    C += (size_t)blockIdx.z * zstride;

    floatx4 zero4 = {0.0f, 0.0f, 0.0f, 0.0f};
    floatx4 acc1[4][4];
#pragma unroll
    for (int m = 0; m < 4; m++)
#pragma unroll
        for (int n = 0; n < 4; n++) acc1[m][n] = zero4;

    for (int k0 = kbeg; k0 < kbeg + ksplit; k0 += 32) {
        __syncthreads();
#pragma unroll
        for (int p = 0; p < 2; p++) {
            int c = p * 256 + tid;
            int row = c >> 2;
            int col = (c & 3) * 8;
            stage_chunk(A + (size_t)(gm + row) * lda + k0 + col, Asm, c);
            stage_chunk(B1 + (size_t)(gn + row) * ldb + k0 + col, B1sm, c);
        }
        __syncthreads();

        bhalf8 a[4];
#pragma unroll
        for (int m = 0; m < 4; m++)
            a[m] = *(const bhalf8*)(Asm + (wm + m * 16 + lrow) * 64 + kh * 16);
#pragma unroll
        for (int n = 0; n < 4; n++) {
            bhalf8 b = *(const bhalf8*)(B1sm + (wn + n * 16 + lrow) * 64 + kh * 16);
#pragma unroll
            for (int m = 0; m < 4; m++)
                acc1[m][n] = __builtin_amdgcn_mfma_f32_16x16x32_bf16(a[m], b, acc1[m][n], 0, 0, 0);
        }
    }

#pragma unroll
    for (int m = 0; m < 4; m++) {
#pragma unroll
        for (int n = 0; n < 4; n++) {
            int cc = gn + wn + n * 16 + lrow;
#pragma unroll
            for (int q = 0; q < 4; q++) {
                int r = gm + wm + m * 16 + kh * 4 + q;
                C[(size_t)r * ldc + cc] = acc1[m][n][q];
            }
        }
    }
}

// ---------------- split-K reduce ----------------
__global__ __launch_bounds__(256) void k_red(const float* __restrict__ P,
                                             float* __restrict__ outp, int SK) {
    int idx = blockIdx.x * 256 + threadIdx.x;
    int lr = idx >> 7;
    int d4 = (idx & 127) * 4;
    const float* base = P + (size_t)lr * 8192 + d4;
    float4 s = *(const float4*)base;
    for (int p = 1; p < SK; p++) {
        float4 v = *(const float4*)(base + (size_t)p * 512);
        s.x += v.x; s.y += v.y; s.z += v.z; s.w += v.w;
    }
    *(float4*)(outp + (size_t)lr * 512 + d4) = s;
}

// ------- normalize rows of F -> bf16 Xb (normalized), bf16 Fb (raw), invnf -------
__global__ __launch_bounds__(128) void k_norm(const float* __restrict__ F,
                                              unsigned short* __restrict__ Xb,
                                              unsigned short* __restrict__ Fb,
                                              float* __restrict__ invnf) {
    int row = blockIdx.x, tid = threadIdx.x;
    float4 v = ((const float4*)(F + (size_t)row * D))[tid];
    float ss = v.x * v.x + v.y * v.y + v.z * v.z + v.w * v.w;
    ss = waveReduceSum(ss);
    __shared__ float s2[2];
    if ((tid & 63) == 0) s2[tid >> 6] = ss;
    __syncthreads();
    float inv = 1.0f / fmaxf(sqrtf(s2[0] + s2[1]), 1e-12f);
    if (tid == 0) invnf[row] = inv;
    union { unsigned short s[4]; int2 q; } ux, uf;
    ux.s[0] = f2bf(v.x * inv); ux.s[1] = f2bf(v.y * inv);
    ux.s[2] = f2bf(v.z * inv); ux.s[3] = f2bf(v.w * inv);
    uf.s[0] = f2bf(v.x); uf.s[1] = f2bf(v.y);
    uf.s[2] = f2bf(v.z); uf.s[3] = f2bf(v.w);
    *(int2*)(Xb + (size_t)row * D + tid * 4) = ux.q;
    *(int2*)(Fb + (size_t)row * D + tid * 4) = uf.q;
}

// ---------------- transpose F (fp32 BxD) -> FbT (bf16 DxB) ----------------
__global__ __launch_bounds__(256) void k_transpose(const float* __restrict__ F,
                                                   unsigned short* __restrict__ FbT) {
    __shared__ float t[64][65];
    int r0 = blockIdx.x * 64, d0 = blockIdx.y * 64;
    int tid = threadIdx.x;
#pragma unroll
    for (int p = 0; p < 4; p++) {
        int idx = p * 256 + tid;
        int r = idx >> 4, c4 = (idx & 15) * 4;
        float4 v = *(const float4*)(F + (size_t)(r0 + r) * D + d0 + c4);
        t[r][c4 + 0] = v.x; t[r][c4 + 1] = v.y; t[r][c4 + 2] = v.z; t[r][c4 + 3] = v.w;
    }
    __syncthreads();
#pragma unroll
    for (int p = 0; p < 2; p++) {
        int idx = p * 256 + tid;
        int d = idx >> 3, rc = (idx & 7) * 8;
        union { unsigned short s[8]; int4 v; } u;
#pragma unroll
        for (int j = 0; j < 8; j++) u.s[j] = f2bf(t[rc + j][d]);
        *(int4*)(FbT + (size_t)(d0 + d) * B + r0 + rc) = u.v;
    }
}

// ---------------- top-K: radix histogram + wave-level suffix scans (low-barrier) ------
// Matches lax.top_k order: value desc, then index asc (packed u64 keys).
__global__ __launch_bounds__(256) void k_topk2(const float* __restrict__ S,
                                               int* __restrict__ topk, int r0) {
    __shared__ int hist[4096];
    __shared__ int wtot[4];
    __shared__ int cslot[2][4];
    __shared__ int islot[4];
    __shared__ unsigned long long buf[128];
    __shared__ int outIdx[KNN];
    __shared__ int ccount;
    __shared__ int sbin;
    __shared__ int sSb;
    int li = blockIdx.x, tid = threadIdx.x;
    int i = r0 + li;
    const float* rp = S + (size_t)li * B;

    // load 32 keys/thread; col = j8*1024 + tid*4 + q ; monotonic uint mapping
    unsigned int key[32];
#pragma unroll
    for (int j8 = 0; j8 < 8; j8++) {
        float4 v = *(const float4*)(rp + j8 * 1024 + tid * 4);
        float fv[4] = {v.x, v.y, v.z, v.w};
#pragma unroll
        for (int q = 0; q < 4; q++) {
            int col = j8 * 1024 + tid * 4 + q;
            unsigned int u = __builtin_bit_cast(unsigned int, fv[q]);
            unsigned int k = u ^ ((u & 0x80000000u) ? 0xFFFFFFFFu : 0x80000000u);
            key[j8 * 4 + q] = (col == i) ? 0u : k;
        }
    }

    // zero histogram + init (overlaps load latency)
#pragma unroll
    for (int j = 0; j < 16; j++) hist[tid * 16 + j] = 0;
    if (tid == 0) { sbin = -1; ccount = 0; }
    __syncthreads();

    // histogram top 12 bits
#pragma unroll
    for (int j = 0; j < 32; j++) atomicAdd(&hist[key[j] >> 20], 1);
    __syncthreads();

    // per-thread 16-bin group sum, wave-level suffix scan (shfl, no barriers)
    int base = tid * 16;
    int st = 0;
#pragma unroll
    for (int j = 0; j < 16; j++) st += hist[base + j];
    int lane = tid & 63, wv = tid >> 6;
    int vsuf = st;
#pragma unroll
    for (int off = 1; off < 64; off <<= 1) {
        int o = __shfl_down(vsuf, off);
        if (lane + off < 64) vsuf += o;
    }
    if (lane == 0) wtot[wv] = vsuf;  // wave total (suffix at lane 0)
    __syncthreads();
    int Ow = 0;
#pragma unroll
    for (int w = 1; w < 4; w++)
        if (w > wv) Ow += wtot[w];
    // suffix strictly after this thread's 16 bins
    int Safter = Ow + vsuf - st;

    // highest bin with suffix >= KNN in this thread's range; block max via atomic
    {
        int bestj = -1;
        int s2 = Safter;
#pragma unroll
        for (int j = 15; j >= 0; j--) {
            s2 += hist[base + j];
            if (s2 >= KNN && bestj < 0) bestj = base + j;
        }
        if (bestj >= 0) atomicMax(&sbin, bestj);
    }
    __syncthreads();
    int b = sbin;  // >= 0 always (suffix(0) = B-1 >= KNN)
    if (tid == (b >> 4)) {
        int s2 = Safter;
        for (int j = 15; j >= (b & 15); j--) s2 += hist[base + j];
        sSb = s2;  // suffix(b) = count(keys >= b<<20)
    }
    __syncthreads();
    int Sb = sSb;

    unsigned int T = 0;
    bool found = false;
    if (Sb <= 128) {
        T = (((unsigned int)b) << 20) - 1u;  // b >= 1 here (bin 0 suffix > 128)
        found = true;
    } else {
        // refine inside bin b (rare): count(>lo) > 128, count(>hi) < KNN
        unsigned int lo = (b == 0) ? 0u : ((((unsigned int)b) << 20) - 1u);
        unsigned int hi = (((unsigned int)(b + 1)) << 20) - 1u;
        for (int it = 0; it < 33; ++it) {
            unsigned int mid = lo + ((hi - lo) >> 1);
            if (mid == lo) break;
            int c = 0;
#pragma unroll
            for (int j = 0; j < 32; j++) c += (key[j] > mid) ? 1 : 0;
#pragma unroll
            for (int off = 32; off; off >>= 1) c += __shfl_down(c, off);
            if ((tid & 63) == 0) cslot[it & 1][tid >> 6] = c;
            __syncthreads();
            int tot = cslot[it & 1][0] + cslot[it & 1][1] + cslot[it & 1][2] + cslot[it & 1][3];
            if (tot >= KNN && tot <= 128) { T = mid; found = true; break; }
            if (tot < KNN) hi = mid; else lo = mid;
        }
        if (!found) T = hi;  // exact-tie slow path
    }
    __syncthreads();

    // collect candidates (key > T) into buf
#pragma unroll
    for (int j8 = 0; j8 < 8; j8++) {
#pragma unroll
        for (int q = 0; q < 4; q++) {
            int j = j8 * 4 + q;
            if (key[j] > T) {
                int p = atomicAdd(&ccount, 1);
                if (p < 128) {
                    int col = j8 * 1024 + tid * 4 + q;
                    buf[p] = ((unsigned long long)key[j] << 13) |
                             (unsigned long long)(8191 - col);
                }
            }
        }
    }
    __syncthreads();
    int C = ccount < 128 ? ccount : 128;

    // wave 0: iterative argmax over candidates (<=128)
    if (tid < 64) {
        unsigned long long p0 = (tid < C) ? buf[tid] : 0ull;
        unsigned long long p1 = (tid + 64 < C) ? buf[tid + 64] : 0ull;
        for (int it = 0; it < KNN; ++it) {
            unsigned long long m = (p0 > p1) ? p0 : p1;
#pragma unroll
            for (int off = 32; off; off >>= 1) {
                unsigned long long o = __shfl_down(m, off);
                m = (o > m) ? o : m;
            }
            m = __shfl(m, 0);
            if (tid == 0 && m != 0ull) outIdx[it] = 8191 - (int)(m & 0x1FFFull);
            if (p0 == m) p0 = 0ull; else if (p1 == m) p1 = 0ull;
        }
    }
    __syncthreads();

    if (C < KNN) {
        // fill remaining with smallest-index ties (key == T); effectively never hit
        int last = -1;
        for (int it = C; it < KNN; ++it) {
            int best = 0x7fffffff;
#pragma unroll
            for (int j8 = 0; j8 < 8; j8++) {
#pragma unroll
                for (int q = 0; q < 4; q++) {
                    int j = j8 * 4 + q;
                    int col = j8 * 1024 + tid * 4 + q;
                    if (key[j] == T && col > last && col < best) best = col;
                }
            }
#pragma unroll
            for (int off = 32; off; off >>= 1) {
                int o = __shfl_down(best, off);
                best = (o < best) ? o : best;
            }
            if ((tid & 63) == 0) islot[tid >> 6] = best;
            __syncthreads();
            best = min(min(islot[0], islot[1]), min(islot[2], islot[3]));
            if (tid == 0) outIdx[it] = best;
            last = best;
            __syncthreads();
        }
    }
    __syncthreads();
    if (tid < KNN) topk[(size_t)i * KNN + tid] = outIdx[tid];
}

// ---------------- graph build ----------------
__global__ void k_zero2(int* __restrict__ a, int* __restrict__ b) {
    int i = blockIdx.x * 256 + threadIdx.x;
    a[i] = 0;
    b[i] = 0;
}

__global__ void k_count(const int* __restrict__ topk, int* __restrict__ indeg) {
    int e = blockIdx.x * 256 + threadIdx.x;
    atomicAdd(&indeg[topk[e]], 1);
}

__global__ __launch_bounds__(1024) void k_scan(const int* __restrict__ indeg,
                                               int* __restrict__ roff) {
    __shared__ int sums[1024];
    int tid = threadIdx.x;
    int base = tid * 8;
    int loc[8];
    int s = 0;
#pragma unroll
    for (int j = 0; j < 8; j++) { loc[j] = s; s += indeg[base + j]; }
    sums[tid] = s;
    __syncthreads();
    for (int off = 1; off < 1024; off <<= 1) {
        int v = (tid >= off) ? sums[tid - off] : 0;
        __syncthreads();
        sums[tid] += v;
        __syncthreads();
    }
    int prev = (tid > 0) ? sums[tid - 1] : 0;
#pragma unroll
    for (int j = 0; j < 8; j++) roff[base + j] = prev + loc[j];
    if (tid == 1023) roff[B] = sums[1023];
}

__global__ void k_dinv(const int* __restrict__ indeg, float* __restrict__ dinv) {
    int i = blockIdx.x * 256 + threadIdx.x;
    float dg = (float)(KNN + indeg[i]);
    dinv[i] = fminf(1.0f / sqrtf(dg), 1e6f);
}

__global__ void k_fill(const int* __restrict__ topk, const int* __restrict__ roff,
                       int* __restrict__ fill, int* __restrict__ ridx) {
    int e = blockIdx.x * 256 + threadIdx.x;
    int dst = topk[e];
    int src = e >> 5;
    int pos = atomicAdd(&fill[dst], 1);
    ridx[roff[dst] + pos] = src;
}

// ------- SpMM 1: G1b (bf16) = A_hat @ Fb, gather in bf16, int4-batched indices -------
__global__ __launch_bounds__(128) void k_spmm1(const unsigned short* __restrict__ Fb,
                                               unsigned short* __restrict__ G1b,
                                               const int* __restrict__ topk,
                                               const int* __restrict__ roff,
                                               const int* __restrict__ ridx,
                                               const float* __restrict__ dinv) {
    int i = blockIdx.x, tid = threadIdx.x;
    float a0 = 0, a1 = 0, a2 = 0, a3 = 0;
    const int* ti = topk + (size_t)i * KNN;
#pragma unroll
    for (int k4 = 0; k4 < KNN / 4; k4++) {
        int4 nn = *(const int4*)(ti + k4 * 4);
        float w0 = dinv[nn.x], w1 = dinv[nn.y], w2 = dinv[nn.z], w3 = dinv[nn.w];
        int2 p0 = *(const int2*)(Fb + (size_t)nn.x * D + tid * 4);
        int2 p1 = *(const int2*)(Fb + (size_t)nn.y * D + tid * 4);
        int2 p2 = *(const int2*)(Fb + (size_t)nn.z * D + tid * 4);
        int2 p3 = *(const int2*)(Fb + (size_t)nn.w * D + tid * 4);
        const unsigned short* u0 = (const unsigned short*)&p0;
        const unsigned short* u1 = (const unsigned short*)&p1;
        const unsigned short* u2 = (const unsigned short*)&p2;
        const unsigned short* u3 = (const unsigned short*)&p3;
        a0 += w0 * bf2f(u0[0]) + w1 * bf2f(u1[0]) + w2 * bf2f(u2[0]) + w3 * bf2f(u3[0]);
        a1 += w0 * bf2f(u0[1]) + w1 * bf2f(u1[1]) + w2 * bf2f(u2[1]) + w3 * bf2f(u3[1]);
        a2 += w0 * bf2f(u0[2]) + w1 * bf2f(u1[2]) + w2 * bf2f(u2[2]) + w3 * bf2f(u3[2]);
        a3 += w0 * bf2f(u0[3]) + w1 * bf2f(u1[3]) + w2 * bf2f(u2[3]) + w3 * bf2f(u3[3]);
    }
    int s = roff[i], e = roff[i + 1];
    int t = s;
    for (; t + 2 <= e; t += 2) {
        int j0 = ridx[t], j1 = ridx[t + 1];
        float w0 = dinv[j0], w1 = dinv[j1];
        int2 p0 = *(const int2*)(Fb + (size_t)j0 * D + tid * 4);
        int2 p1 = *(const int2*)(Fb + (size_t)j1 * D + tid * 4);
        const unsigned short* u0 = (const unsigned short*)&p0;
        const unsigned short* u1 = (const unsigned short*)&p1;
        a0 += w0 * bf2f(u0[0]) + w1 * bf2f(u1[0]);
        a1 += w0 * bf2f(u0[1]) + w1 * bf2f(u1[1]);
        a2 += w0 * bf2f(u0[2]) + w1 * bf2f(u1[2]);
        a3 += w0 * bf2f(u0[3]) + w1 * bf2f(u1[3]);
    }
    if (t < e) {
        int j0 = ridx[t];
        float w0 = dinv[j0];
        int2 p0 = *(const int2*)(Fb + (size_t)j0 * D + tid * 4);
        const unsigned short* u0 = (const unsigned short*)&p0;
        a0 += w0 * bf2f(u0[0]); a1 += w0 * bf2f(u0[1]);
        a2 += w0 * bf2f(u0[2]); a3 += w0 * bf2f(u0[3]);
    }
    float wi = dinv[i];
    union { unsigned short s4[4]; int2 q; } u;
    u.s4[0] = f2bf(wi * a0); u.s4[1] = f2bf(wi * a1);
    u.s4[2] = f2bf(wi * a2); u.s4[3] = f2bf(wi * a3);
    *(int2*)(G1b + (size_t)i * D + tid * 4) = u.q;
}

// ------- SpMM 2 fused with Yb build -------
__global__ __launch_bounds__(128) void k_spmm2y(const unsigned short* __restrict__ G1b,
                                                const float* __restrict__ F,
                                                const float* __restrict__ invnf,
                                                unsigned short* __restrict__ Yb,
                                                const int* __restrict__ topk,
                                                const int* __restrict__ roff,
                                                const int* __restrict__ ridx,
                                                const float* __restrict__ dinv) {
    int i = blockIdx.x, tid = threadIdx.x;
    float a0 = 0, a1 = 0, a2 = 0, a3 = 0;
    const int* ti = topk + (size_t)i * KNN;
#pragma unroll
    for (int k4 = 0; k4 < KNN / 4; k4++) {
        int4 nn = *(const int4*)(ti + k4 * 4);
        float w0 = dinv[nn.x], w1 = dinv[nn.y], w2 = dinv[nn.z], w3 = dinv[nn.w];
        int2 p0 = *(const int2*)(G1b + (size_t)nn.x * D + tid * 4);
        int2 p1 = *(const int2*)(G1b + (size_t)nn.y * D + tid * 4);
        int2 p2 = *(const int2*)(G1b + (size_t)nn.z * D + tid * 4);
        int2 p3 = *(const int2*)(G1b + (size_t)nn.w * D + tid * 4);
        const unsigned short* u0 = (const unsigned short*)&p0;
        const unsigned short* u1 = (const unsigned short*)&p1;
        const unsigned short* u2 = (const unsigned short*)&p2;
        const unsigned short* u3 = (const unsigned short*)&p3;
        a0 += w0 * bf2f(u0[0]) + w1 * bf2f(u1[0]) + w2 * bf2f(u2[0]) + w3 * bf2f(u3[0]);
        a1 += w0 * bf2f(u0[1]) + w1 * bf2f(u1[1]) + w2 * bf2f(u2[1]) + w3 * bf2f(u3[1]);
        a2 += w0 * bf2f(u0[2]) + w1 * bf2f(u1[2]) + w2 * bf2f(u2[2]) + w3 * bf2f(u3[2]);
        a3 += w0 * bf2f(u0[3]) + w1 * bf2f(u1[3]) + w2 * bf2f(u2[3]) + w3 * bf2f(u3[3]);
    }
    int s = roff[i], e = roff[i + 1];
    int t = s;
    for (; t + 2 <= e; t += 2) {
        int j0 = ridx[t], j1 = ridx[t + 1];
        float w0 = dinv[j0], w1 = dinv[j1];
        int2 p0 = *(const int2*)(G1b + (size_t)j0 * D + tid * 4);
        int2 p1 = *(const int2*)(G1b + (size_t)j1 * D + tid * 4);
        const unsigned short* u0 = (const unsigned short*)&p0;
        const unsigned short* u1 = (const unsigned short*)&p1;
        a0 += w0 * bf2f(u0[0]) + w1 * bf2f(u1[0]);
        a1 += w0 * bf2f(u0[1]) + w1 * bf2f(u1[1]);
        a2 += w0 * bf2f(u0[2]) + w1 * bf2f(u1[2]);
        a3 += w0 * bf2f(u0[3]) + w1 * bf2f(u1[3]);
    }
    if (t < e) {
        int j0 = ridx[t];
        float w0 = dinv[j0];
        int2 p0 = *(const int2*)(G1b + (size_t)j0 * D + tid * 4);
        const unsigned short* u0 = (const unsigned short*)&p0;
        a0 += w0 * bf2f(u0[0]); a1 += w0 * bf2f(u0[1]);
        a2 += w0 * bf2f(u0[2]); a3 += w0 * bf2f(u0[3]);
    }
    float wi = dinv[i];
    float g0 = wi * a0, g1 = wi * a1, g2 = wi * a2, g3 = wi * a3;

    float ss = g0 * g0 + g1 * g1 + g2 * g2 + g3 * g3;
    ss = waveReduceSum(ss);
    __shared__ float s2[2];
    if ((tid & 63) == 0) s2[tid >> 6] = ss;
    __syncthreads();
    float invng = 1.0f / fmaxf(sqrtf(s2[0] + s2[1]), 1e-12f);

    float4 f = ((const float4*)(F + (size_t)i * D))[tid];
    float inf_ = 10.0f * invnf[i];
    union { unsigned short s4[4]; int2 q; } u;
    u.s4[0] = f2bf(f.x * inf_ + g0 * invng);
    u.s4[1] = f2bf(f.y * inf_ + g1 * invng);
    u.s4[2] = f2bf(f.z * inf_ + g2 * invng);
    u.s4[3] = f2bf(f.w * inf_ + g3 * invng);
    *(int2*)(Yb + (size_t)i * D + tid * 4) = u.q;
}

// ------- register-resident online row softmax; writes bf16 weights in place ----------
__global__ __launch_bounds__(256) void k_softmax(float* __restrict__ chunk) {
    __shared__ float sm[4], sl[4];
    int li = blockIdx.x, tid = threadIdx.x;
    float* rp = chunk + (size_t)li * B;
    float4 v[8];
    float mt = -FLT_MAX;
#pragma unroll
    for (int p = 0; p < 8; p++) {
        v[p] = *(const float4*)(rp + p * 1024 + tid * 4);
        mt = fmaxf(mt, fmaxf(fmaxf(v[p].x, v[p].y), fmaxf(v[p].z, v[p].w)));
    }
    float l = 0.0f;
#pragma unroll
    for (int p = 0; p < 8; p++) {
        v[p].x = __expf(v[p].x - mt);
        v[p].y = __expf(v[p].y - mt);
        v[p].z = __expf(v[p].z - mt);
        v[p].w = __expf(v[p].w - mt);
        l += v[p].x + v[p].y + v[p].z + v[p].w;
    }
    float m = mt, lw = l;
#pragma unroll
    for (int off = 32; off; off >>= 1) {
        float om = __shfl_down(m, off);
        float ol = __shfl_down(lw, off);
        float nm = fmaxf(m, om);
        lw = lw * __expf(m - nm) + ol * __expf(om - nm);
        m = nm;
    }
    if ((tid & 63) == 0) { sm[tid >> 6] = m; sl[tid >> 6] = lw; }
    __syncthreads();
    float M = fmaxf(fmaxf(sm[0], sm[1]), fmaxf(sm[2], sm[3]));
    float L = sl[0] * __expf(sm[0] - M) + sl[1] * __expf(sm[1] - M) +
              sl[2] * __expf(sm[2] - M) + sl[3] * __expf(sm[3] - M);
    float fct = __expf(mt - M) / L;
    unsigned short* wp = (unsigned short*)rp;
#pragma unroll
    for (int p = 0; p < 8; p++) {
        union { unsigned short s[4]; int2 q; } u;
        u.s[0] = f2bf(v[p].x * fct);
        u.s[1] = f2bf(v[p].y * fct);
        u.s[2] = f2bf(v[p].z * fct);
        u.s[3] = f2bf(v[p].w * fct);
        *(int2*)(wp + p * 1024 + tid * 4) = u.q;
    }
}

extern "C" void kernel_launch(void* const* d_in, const int* in_sizes, int n_in,
                              void* d_out, int out_size, void* d_ws, size_t ws_size,
                              hipStream_t stream) {
    (void)in_sizes; (void)n_in; (void)out_size;
    const float* F = (const float*)d_in[0];
    float* out = (float*)d_out;

    char* ws = (char*)d_ws;
    size_t off = 0;
    auto take = [&](size_t bytes) -> void* {
        void* p = ws + off;
        off += (bytes + 255) & ~(size_t)255;
        return p;
    };
    float* invnf = (float*)take((size_t)B * 4);
    float* dinv = (float*)take((size_t)B * 4);
    int* topk = (int*)take((size_t)B * KNN * 4);
    int* indeg = (int*)take((size_t)B * 4);
    int* roff = (int*)take((size_t)(B + 1) * 4);
    int* rfill = (int*)take((size_t)B * 4);
    int* ridx = (int*)take((size_t)B * KNN * 4);
    unsigned short* Xb = (unsigned short*)take((size_t)B * D * 2);
    unsigned short* Fb = (unsigned short*)take((size_t)B * D * 2);
    unsigned short* Yb = (unsigned short*)take((size_t)B * D * 2);
    unsigned short* FbT = (unsigned short*)take((size_t)D * B * 2);
    size_t fixed = off;

    int R = 2048;
    if (ws_size > 0) {
        while (R > 128 && fixed + (size_t)R * B * 4 > ws_size) R >>= 1;
    } else {
        R = 1024;
    }
    float* chunk = (float*)(ws + fixed);
    unsigned short* G1b = (unsigned short*)out;

    int SK = 8192 / R;
    if (SK > 8) SK = 8;
    int ksplit = B / SK;
    bool use8 = (R % 256) == 0;

    // 1. Xb / Fb / invnf; FbT = bf16 F^T
    k_norm<<<B, 128, 0, stream>>>(F, Xb, Fb, invnf);
    dim3 gt(B / 64, D / 64);
    k_transpose<<<gt, 256, 0, stream>>>(F, FbT);

    // 2. chunked: sim = Xb Xb^T + top-K
    for (int r0 = 0; r0 < B; r0 += R) {
        if (use8) {
            dim3 g8(B / 256, R / 256);
            k_mfma8<<<g8, 512, 0, stream>>>(Xb + (size_t)r0 * D, D, Xb, D, chunk, B, D);
        } else {
            dim3 g(B / 128, R / 128);
            k_mfma_nt<<<g, 256, 0, stream>>>(Xb + (size_t)r0 * D, D, Xb, D, chunk, B, 0, D);
        }
        k_topk2<<<R, 256, 0, stream>>>(chunk, topk, r0);
    }

    // 3. graph build
    k_zero2<<<B / 256, 256, 0, stream>>>(indeg, rfill);
    k_count<<<B * KNN / 256, 256, 0, stream>>>(topk, indeg);
    k_scan<<<1, 1024, 0, stream>>>(indeg, roff);
    k_dinv<<<B / 256, 256, 0, stream>>>(indeg, dinv);
    k_fill<<<B * KNN / 256, 256, 0, stream>>>(topk, roff, rfill, ridx);

    // 4. G1b = A_hat Fb; Yb = 10*Xhat + normalize(A_hat G1b)
    k_spmm1<<<B, 128, 0, stream>>>(Fb, G1b, topk, roff, ridx, dinv);
    k_spmm2y<<<B, 128, 0, stream>>>(G1b, F, invnf, Yb, topk, roff, ridx, dinv);

    // 5. chunked: logits = Xb @ Yb^T -> softmax -> out rows = W @ F
    for (int r0 = 0; r0 < B; r0 += R) {
        if (use8) {
            dim3 g8(B / 256, R / 256);
            k_mfma8<<<g8, 512, 0, stream>>>(Xb + (size_t)r0 * D, D, Yb, D, chunk, B, D);
        } else {
            dim3 g(B / 128, R / 128);
            k_mfma_nt<<<g, 256, 0, stream>>>(Xb + (size_t)r0 * D, D, Yb, D, chunk, B, 0, D);
        }
        k_softmax<<<R, 256, 0, stream>>>(chunk);
        float* part = chunk + 4096;
        dim3 gf(D / 128, R / 128, SK);
        k_mfma_nt<<<gf, 256, 0, stream>>>((const unsigned short*)chunk, 2 * B, FbT, B,
                                          part, B, D, ksplit);
        k_red<<<R / 2, 256, 0, stream>>>(part, out + (size_t)r0 * D, SK);
    }
}

// Round 11
// 669.064 us; speedup vs baseline: 8.0197x; 1.1659x over previous
//
#include <hip/hip_runtime.h>
#include <hip/hip_bf16.h>
#include <float.h>
#include <math.h>

constexpr int B = 8192;
constexpr int D = 512;
constexpr int KNN = 32;

typedef __attribute__((ext_vector_type(8))) short bhalf8;
typedef __attribute__((ext_vector_type(4))) float floatx4;

#if defined(__has_builtin)
#if __has_builtin(__builtin_amdgcn_global_load_lds)
#define HAS_GLD 1
#else
#define HAS_GLD 0
#endif
#else
#define HAS_GLD 0
#endif

__device__ __forceinline__ unsigned short f2bf(float f) {
    __hip_bfloat16 h = __float2bfloat16(f);
    return __builtin_bit_cast(unsigned short, h);
}

__device__ __forceinline__ float bf2f(unsigned short u) {
    unsigned int x = ((unsigned int)u) << 16;
    return __builtin_bit_cast(float, x);
}

__device__ __forceinline__ float waveReduceSum(float v) {
#pragma unroll
    for (int off = 32; off; off >>= 1) v += __shfl_down(v, off);
    return v;
}

__device__ __forceinline__ int waveReduceSumI(int v) {
#pragma unroll
    for (int off = 32; off; off >>= 1) v += __shfl_down(v, off);
    return v;
}

// stage one 16B chunk of a 128x32-bf16 tile (linear LDS, 64B rows). (old 128^2 kernel)
__device__ __forceinline__ void stage_chunk(const unsigned short* __restrict__ g,
                                            char* __restrict__ lds_tile, int c) {
#if HAS_GLD
    char* wavebase = lds_tile + (size_t)(c & ~63) * 16;
    __builtin_amdgcn_global_load_lds((const __attribute__((address_space(1))) void*)g,
                                     (__attribute__((address_space(3))) void*)wavebase,
                                     16, 0, 0);
#else
    *(int4*)(lds_tile + (size_t)c * 16) = *(const int4*)g;
#endif
}

// ================= 8-phase 256x256 bf16 NT GEMM (m201-style) =================
__global__ __launch_bounds__(512) void k_mfma8(
    const unsigned short* __restrict__ A, int lda,
    const unsigned short* __restrict__ Bm, int ldb,
    float* __restrict__ C, int ldc, int Kd) {
    __shared__ __align__(16) char lds[131072];
    constexpr int AOFF0 = 0, AOFF1 = 32768, BOFF0 = 65536, BOFF1 = 98304;

    int tid = threadIdx.x;
    int lane = tid & 63;
    int wid = tid >> 6;
    int wm = (wid >> 2) * 128;
    int wn = (wid & 3) * 64;
    int lrow = lane & 15;
    int khi = lane >> 4;
    int lk7 = lane & 7;
    int gm = blockIdx.y * 256, gn = blockIdx.x * 256;

    floatx4 zero4 = {0.0f, 0.0f, 0.0f, 0.0f};
    floatx4 acc[8][4];
#pragma unroll
    for (int m = 0; m < 8; m++)
#pragma unroll
        for (int n = 0; n < 4; n++) acc[m][n] = zero4;
    bhalf8 bfrag[4][2];

    auto stage_half = [&](const unsigned short* __restrict__ src, int ld,
                          int rowg0, int k0, int ldsbase) {
#pragma unroll
        for (int rd = 0; rd < 2; rd++) {
            int idx = rd * 512 + tid;
            int r = idx >> 3;
            int s = (idx & 7) ^ (r & 7);
            const unsigned short* g = src + (size_t)(rowg0 + r) * ld + k0 + s * 8;
#if HAS_GLD
            char* wb = lds + ldsbase + rd * 8192 + (tid >> 6) * 1024;
            __builtin_amdgcn_global_load_lds(
                (const __attribute__((address_space(1))) void*)g,
                (__attribute__((address_space(3))) void*)wb, 16, 0, 0);
#else
            *(int4*)(lds + ldsbase + (size_t)idx * 16) = *(const int4*)g;
#endif
        }
    };
    auto rdA = [&](int bufoff, int mf, int kk) -> bhalf8 {
        int r = wm + mf * 16 + lrow;
        int slot = ((kk << 2) + khi) ^ lk7;
        return *(const bhalf8*)(lds + bufoff + r * 128 + slot * 16);
    };
    auto rdB = [&](int bufoff, int nf, int kk) -> bhalf8 {
        int r = wn + nf * 16 + lrow;
        int slot = ((kk << 2) + khi) ^ lk7;
        return *(const bhalf8*)(lds + bufoff + r * 128 + slot * 16);
    };

    stage_half(A, lda, gm, 0, AOFF0);
    stage_half(A, lda, gm + 128, 0, AOFF0 + 16384);
    stage_half(Bm, ldb, gn, 0, BOFF0);
    stage_half(Bm, ldb, gn + 128, 0, BOFF0 + 16384);
    stage_half(Bm, ldb, gn, 64, BOFF1);
    stage_half(Bm, ldb, gn + 128, 64, BOFF1 + 16384);
    asm volatile("s_waitcnt vmcnt(4)" ::: "memory");
    __builtin_amdgcn_s_barrier();

#define PH(mq, AO, BO, STAGE_STMT, TAIL_STMT)                                      \
    {                                                                              \
        if ((mq) == 0) {                                                           \
            _Pragma("unroll") for (int nf = 0; nf < 4; nf++) {                     \
                bfrag[nf][0] = rdB((BO), nf, 0);                                   \
                bfrag[nf][1] = rdB((BO), nf, 1);                                   \
            }                                                                      \
        }                                                                          \
        bhalf8 a00 = rdA((AO), 2 * (mq), 0);                                       \
        bhalf8 a01 = rdA((AO), 2 * (mq), 1);                                       \
        bhalf8 a10 = rdA((AO), 2 * (mq) + 1, 0);                                   \
        bhalf8 a11 = rdA((AO), 2 * (mq) + 1, 1);                                   \
        STAGE_STMT;                                                                \
        __builtin_amdgcn_s_barrier();                                              \
        asm volatile("s_waitcnt lgkmcnt(0)" ::: "memory");                         \
        __builtin_amdgcn_sched_barrier(0);                                         \
        __builtin_amdgcn_s_setprio(1);                                             \
        _Pragma("unroll") for (int nf = 0; nf < 4; nf++) {                         \
            acc[2 * (mq)][nf] = __builtin_amdgcn_mfma_f32_16x16x32_bf16(           \
                a00, bfrag[nf][0], acc[2 * (mq)][nf], 0, 0, 0);                    \
            acc[2 * (mq) + 1][nf] = __builtin_amdgcn_mfma_f32_16x16x32_bf16(       \
                a10, bfrag[nf][0], acc[2 * (mq) + 1][nf], 0, 0, 0);                \
        }                                                                          \
        _Pragma("unroll") for (int nf = 0; nf < 4; nf++) {                         \
            acc[2 * (mq)][nf] = __builtin_amdgcn_mfma_f32_16x16x32_bf16(           \
                a01, bfrag[nf][1], acc[2 * (mq)][nf], 0, 0, 0);                    \
            acc[2 * (mq) + 1][nf] = __builtin_amdgcn_mfma_f32_16x16x32_bf16(       \
                a11, bfrag[nf][1], acc[2 * (mq) + 1][nf], 0, 0, 0);                \
        }                                                                          \
        __builtin_amdgcn_s_setprio(0);                                             \
        TAIL_STMT;                                                                 \
        __builtin_amdgcn_s_barrier();                                              \
    }

    int iters = Kd >> 7;
    for (int it = 0; it < iters; ++it) {
        bool lastI = (it == iters - 1);
        int kodd = (2 * it + 1) << 6;
        int kne = (2 * it + 2) << 6;
        int kno = (2 * it + 3) << 6;
        PH(0, AOFF0, BOFF0, stage_half(A, lda, gm, kodd, AOFF1), );
        PH(1, AOFF0, BOFF0, stage_half(A, lda, gm + 128, kodd, AOFF1 + 16384), );
        PH(2, AOFF0, BOFF0, if (!lastI) stage_half(Bm, ldb, gn, kne, BOFF0), );
        PH(3, AOFF0, BOFF0, if (!lastI) stage_half(Bm, ldb, gn + 128, kne, BOFF0 + 16384),
           if (lastI) { asm volatile("s_waitcnt vmcnt(0)" ::: "memory"); } else {
               asm volatile("s_waitcnt vmcnt(4)" ::: "memory"); });
        PH(0, AOFF1, BOFF1, if (!lastI) stage_half(A, lda, gm, kne, AOFF0), );
        PH(1, AOFF1, BOFF1, if (!lastI) stage_half(A, lda, gm + 128, kne, AOFF0 + 16384), );
        PH(2, AOFF1, BOFF1, if (!lastI) stage_half(Bm, ldb, gn, kno, BOFF1), );
        PH(3, AOFF1, BOFF1, if (!lastI) stage_half(Bm, ldb, gn + 128, kno, BOFF1 + 16384),
           if (lastI) { asm volatile("s_waitcnt vmcnt(0)" ::: "memory"); } else {
               asm volatile("s_waitcnt vmcnt(4)" ::: "memory"); });
    }
#undef PH

#pragma unroll
    for (int mf = 0; mf < 8; mf++) {
#pragma unroll
        for (int nf = 0; nf < 4; nf++) {
            int cc = gn + wn + nf * 16 + lrow;
#pragma unroll
            for (int q = 0; q < 4; q++) {
                int r = gm + wm + mf * 16 + khi * 4 + q;
                C[(size_t)r * ldc + cc] = acc[mf][nf][q];
            }
        }
    }
}

// ---------------- bf16 MFMA GEMM, NT form (old 128^2; used for final GEMM) ----------
__global__ __launch_bounds__(256, 2) void k_mfma_nt(
    const unsigned short* __restrict__ A, int lda,
    const unsigned short* __restrict__ B1, int ldb,
    float* __restrict__ C, int ldc, int zstride, int ksplit) {
    __shared__ __align__(16) char smem[2 * 8192];
    char* Asm = smem;
    char* B1sm = smem + 8192;

    int tid = threadIdx.x;
    int lane = tid & 63;
    int wid = tid >> 6;
    int wm = (wid >> 1) * 64, wn = (wid & 1) * 64;
    int lrow = lane & 15;
    int kh = lane >> 4;
    int gm = blockIdx.y * 128, gn = blockIdx.x * 128;
    int kbeg = blockIdx.z * ksplit;
    C += (size_t)blockIdx.z * zstride;

    floatx4 zero4 = {0.0f, 0.0f, 0.0f, 0.0f};
    floatx4 acc1[4][4];
#pragma unroll
    for (int m = 0; m < 4; m++)
#pragma unroll
        for (int n = 0; n < 4; n++) acc1[m][n] = zero4;

    for (int k0 = kbeg; k0 < kbeg + ksplit; k0 += 32) {
        __syncthreads();
#pragma unroll
        for (int p = 0; p < 2; p++) {
            int c = p * 256 + tid;
            int row = c >> 2;
            int col = (c & 3) * 8;
            stage_chunk(A + (size_t)(gm + row) * lda + k0 + col, Asm, c);
            stage_chunk(B1 + (size_t)(gn + row) * ldb + k0 + col, B1sm, c);
        }
        __syncthreads();

        bhalf8 a[4];
#pragma unroll
        for (int m = 0; m < 4; m++)
            a[m] = *(const bhalf8*)(Asm + (wm + m * 16 + lrow) * 64 + kh * 16);
#pragma unroll
        for (int n = 0; n < 4; n++) {
            bhalf8 b = *(const bhalf8*)(B1sm + (wn + n * 16 + lrow) * 64 + kh * 16);
#pragma unroll
            for (int m = 0; m < 4; m++)
                acc1[m][n] = __builtin_amdgcn_mfma_f32_16x16x32_bf16(a[m], b, acc1[m][n], 0, 0, 0);
        }
    }

#pragma unroll
    for (int m = 0; m < 4; m++) {
#pragma unroll
        for (int n = 0; n < 4; n++) {
            int cc = gn + wn + n * 16 + lrow;
#pragma unroll
            for (int q = 0; q < 4; q++) {
                int r = gm + wm + m * 16 + kh * 4 + q;
                C[(size_t)r * ldc + cc] = acc1[m][n][q];
            }
        }
    }
}

// ---------------- split-K reduce ----------------
__global__ __launch_bounds__(256) void k_red(const float* __restrict__ P,
                                             float* __restrict__ outp, int SK) {
    int idx = blockIdx.x * 256 + threadIdx.x;
    int lr = idx >> 7;
    int d4 = (idx & 127) * 4;
    const float* base = P + (size_t)lr * 8192 + d4;
    float4 s = *(const float4*)base;
    for (int p = 1; p < SK; p++) {
        float4 v = *(const float4*)(base + (size_t)p * 512);
        s.x += v.x; s.y += v.y; s.z += v.z; s.w += v.w;
    }
    *(float4*)(outp + (size_t)lr * 512 + d4) = s;
}

// ------- normalize rows of F -> bf16 Xb (normalized), bf16 Fb (raw), invnf -------
__global__ __launch_bounds__(128) void k_norm(const float* __restrict__ F,
                                              unsigned short* __restrict__ Xb,
                                              unsigned short* __restrict__ Fb,
                                              float* __restrict__ invnf) {
    int row = blockIdx.x, tid = threadIdx.x;
    float4 v = ((const float4*)(F + (size_t)row * D))[tid];
    float ss = v.x * v.x + v.y * v.y + v.z * v.z + v.w * v.w;
    ss = waveReduceSum(ss);
    __shared__ float s2[2];
    if ((tid & 63) == 0) s2[tid >> 6] = ss;
    __syncthreads();
    float inv = 1.0f / fmaxf(sqrtf(s2[0] + s2[1]), 1e-12f);
    if (tid == 0) invnf[row] = inv;
    union { unsigned short s[4]; int2 q; } ux, uf;
    ux.s[0] = f2bf(v.x * inv); ux.s[1] = f2bf(v.y * inv);
    ux.s[2] = f2bf(v.z * inv); ux.s[3] = f2bf(v.w * inv);
    uf.s[0] = f2bf(v.x); uf.s[1] = f2bf(v.y);
    uf.s[2] = f2bf(v.z); uf.s[3] = f2bf(v.w);
    *(int2*)(Xb + (size_t)row * D + tid * 4) = ux.q;
    *(int2*)(Fb + (size_t)row * D + tid * 4) = uf.q;
}

// ---------------- transpose F (fp32 BxD) -> FbT (bf16 DxB) ----------------
__global__ __launch_bounds__(256) void k_transpose(const float* __restrict__ F,
                                                   unsigned short* __restrict__ FbT) {
    __shared__ float t[64][65];
    int r0 = blockIdx.x * 64, d0 = blockIdx.y * 64;
    int tid = threadIdx.x;
#pragma unroll
    for (int p = 0; p < 4; p++) {
        int idx = p * 256 + tid;
        int r = idx >> 4, c4 = (idx & 15) * 4;
        float4 v = *(const float4*)(F + (size_t)(r0 + r) * D + d0 + c4);
        t[r][c4 + 0] = v.x; t[r][c4 + 1] = v.y; t[r][c4 + 2] = v.z; t[r][c4 + 3] = v.w;
    }
    __syncthreads();
#pragma unroll
    for (int p = 0; p < 2; p++) {
        int idx = p * 256 + tid;
        int d = idx >> 3, rc = (idx & 7) * 8;
        union { unsigned short s[8]; int4 v; } u;
#pragma unroll
        for (int j = 0; j < 8; j++) u.s[j] = f2bf(t[rc + j][d]);
        *(int4*)(FbT + (size_t)(d0 + d) * B + r0 + rc) = u.v;
    }
}

// -------- top-K: moment-threshold + bracketed bisection + parallel rank select -------
// Exact; matches lax.top_k tie order (value desc, index asc) via packed u64 keys.
__global__ __launch_bounds__(256) void k_topk2(const float* __restrict__ S,
                                               int* __restrict__ topk, int r0) {
    __shared__ float fs[4], fs2[4];
    __shared__ int cslot[2][4];
    __shared__ int islot[4];
    __shared__ unsigned long long buf[128];
    __shared__ int ccount;
    int li = blockIdx.x, tid = threadIdx.x;
    int i = r0 + li;
    const float* rp = S + (size_t)li * B;

    // load 32 values/thread; col = j8*1024 + tid*4 + q ; monotonic uint keys
    unsigned int key[32];
    float sum = 0.0f, sumsq = 0.0f;
#pragma unroll
    for (int j8 = 0; j8 < 8; j8++) {
        float4 v = *(const float4*)(rp + j8 * 1024 + tid * 4);
        float fv[4] = {v.x, v.y, v.z, v.w};
#pragma unroll
        for (int q = 0; q < 4; q++) {
            int col = j8 * 1024 + tid * 4 + q;
            bool self = (col == i);
            float vv = self ? 0.0f : fv[q];
            sum += vv;
            sumsq += vv * vv;
            unsigned int u = __builtin_bit_cast(unsigned int, fv[q]);
            unsigned int k = u ^ ((u & 0x80000000u) ? 0xFFFFFFFFu : 0x80000000u);
            key[j8 * 4 + q] = self ? 0u : k;
        }
    }

    // block reduce mean/var
    float s1 = waveReduceSum(sum);
    float s2 = waveReduceSum(sumsq);
    int lane = tid & 63, wv = tid >> 6;
    if (lane == 0) { fs[wv] = s1; fs2[wv] = s2; }
    if (tid == 0) ccount = 0;
    __syncthreads();
    float S1 = fs[0] + fs[1] + fs[2] + fs[3];
    float S2 = fs2[0] + fs2[1] + fs2[2] + fs2[3];
    float mu = S1 * (1.0f / 8192.0f);
    float var = fmaxf(S2 * (1.0f / 8192.0f) - mu * mu, 0.0f);
    float sg = sqrtf(var);

    // threshold search: Gaussian ladder (<=8 probes) then integer bisection.
    // Invariant: count(>klo) > 128 (klo=0: 8191), count(>khi) < KNN (khi=max: 0).
    unsigned int klo = 0u, khi = 0xFFFFFFFFu;
    unsigned int T = 0;
    bool found = false;
    float z = 2.4f;
    for (int it = 0; it < 48; ++it) {
        unsigned int kt;
        if (it < 8) {
            float tf = mu + z * sg;
            unsigned int u = __builtin_bit_cast(unsigned int, tf);
            kt = u ^ ((u & 0x80000000u) ? 0xFFFFFFFFu : 0x80000000u);
            if (kt <= klo || kt >= khi) kt = klo + ((khi - klo) >> 1);
        } else {
            kt = klo + ((khi - klo) >> 1);
        }
        if (kt == klo) break;  // bracket exhausted: khi = klo+1
        int c = 0;
#pragma unroll
        for (int j = 0; j < 32; j++) c += (key[j] > kt) ? 1 : 0;
        c = waveReduceSumI(c);
        if (lane == 0) cslot[it & 1][wv] = c;
        __syncthreads();
        int tot = cslot[it & 1][0] + cslot[it & 1][1] + cslot[it & 1][2] + cslot[it & 1][3];
        if (tot >= KNN && tot <= 128) { T = kt; found = true; break; }
        if (tot < KNN) { khi = kt; z -= 0.3f; }
        else          { klo = kt; z += 0.3f; }
    }
    if (!found) T = khi;  // count(>T) < KNN; rest are exact ties key==T
    __syncthreads();

    // collect candidates (key > T) into buf (set is deterministic; order isn't)
#pragma unroll
    for (int j8 = 0; j8 < 8; j8++) {
#pragma unroll
        for (int q = 0; q < 4; q++) {
            int j = j8 * 4 + q;
            if (key[j] > T) {
                int p = atomicAdd(&ccount, 1);
                if (p < 128) {
                    int col = j8 * 1024 + tid * 4 + q;
                    buf[p] = ((unsigned long long)key[j] << 13) |
                             (unsigned long long)(8191 - col);
                }
            }
        }
    }
    __syncthreads();
    int C = ccount < 128 ? ccount : 128;

    // parallel rank select: rank = #{greater}; rank<KNN writes directly (order-free)
    if (tid < C) {
        unsigned long long my = buf[tid];
        int rank = 0;
        for (int j = 0; j < C; j++) rank += (buf[j] > my) ? 1 : 0;
        if (rank < KNN) topk[(size_t)i * KNN + rank] = 8191 - (int)(my & 0x1FFFull);
    }
    __syncthreads();

    if (C < KNN) {
        // fill remaining with smallest-index ties (key == T); rare path
        int last = -1;
        for (int it = C; it < KNN; ++it) {
            int best = 0x7fffffff;
#pragma unroll
            for (int j8 = 0; j8 < 8; j8++) {
#pragma unroll
                for (int q = 0; q < 4; q++) {
                    int j = j8 * 4 + q;
                    int col = j8 * 1024 + tid * 4 + q;
                    if (key[j] == T && col > last && col < best) best = col;
                }
            }
#pragma unroll
            for (int off = 32; off; off >>= 1) {
                int o = __shfl_down(best, off);
                best = (o < best) ? o : best;
            }
            if ((tid & 63) == 0) islot[tid >> 6] = best;
            __syncthreads();
            best = min(min(islot[0], islot[1]), min(islot[2], islot[3]));
            if (tid == 0) topk[(size_t)i * KNN + it] = best;
            last = best;
            __syncthreads();
        }
    }
}

// ---------------- graph build ----------------
__global__ void k_zero2(int* __restrict__ a, int* __restrict__ b) {
    int i = blockIdx.x * 256 + threadIdx.x;
    a[i] = 0;
    b[i] = 0;
}

__global__ void k_count(const int* __restrict__ topk, int* __restrict__ indeg) {
    int e = blockIdx.x * 256 + threadIdx.x;
    atomicAdd(&indeg[topk[e]], 1);
}

__global__ __launch_bounds__(1024) void k_scan(const int* __restrict__ indeg,
                                               int* __restrict__ roff) {
    __shared__ int sums[1024];
    int tid = threadIdx.x;
    int base = tid * 8;
    int loc[8];
    int s = 0;
#pragma unroll
    for (int j = 0; j < 8; j++) { loc[j] = s; s += indeg[base + j]; }
    sums[tid] = s;
    __syncthreads();
    for (int off = 1; off < 1024; off <<= 1) {
        int v = (tid >= off) ? sums[tid - off] : 0;
        __syncthreads();
        sums[tid] += v;
        __syncthreads();
    }
    int prev = (tid > 0) ? sums[tid - 1] : 0;
#pragma unroll
    for (int j = 0; j < 8; j++) roff[base + j] = prev + loc[j];
    if (tid == 1023) roff[B] = sums[1023];
}

__global__ void k_dinv(const int* __restrict__ indeg, float* __restrict__ dinv) {
    int i = blockIdx.x * 256 + threadIdx.x;
    float dg = (float)(KNN + indeg[i]);
    dinv[i] = fminf(1.0f / sqrtf(dg), 1e6f);
}

__global__ void k_fill(const int* __restrict__ topk, const int* __restrict__ roff,
                       int* __restrict__ fill, int* __restrict__ ridx) {
    int e = blockIdx.x * 256 + threadIdx.x;
    int dst = topk[e];
    int src = e >> 5;
    int pos = atomicAdd(&fill[dst], 1);
    ridx[roff[dst] + pos] = src;
}

// ------- SpMM 1: G1b (bf16) = A_hat @ Fb, gather in bf16, int4-batched indices -------
__global__ __launch_bounds__(128) void k_spmm1(const unsigned short* __restrict__ Fb,
                                               unsigned short* __restrict__ G1b,
                                               const int* __restrict__ topk,
                                               const int* __restrict__ roff,
                                               const int* __restrict__ ridx,
                                               const float* __restrict__ dinv) {
    int i = blockIdx.x, tid = threadIdx.x;
    float a0 = 0, a1 = 0, a2 = 0, a3 = 0;
    const int* ti = topk + (size_t)i * KNN;
#pragma unroll
    for (int k4 = 0; k4 < KNN / 4; k4++) {
        int4 nn = *(const int4*)(ti + k4 * 4);
        float w0 = dinv[nn.x], w1 = dinv[nn.y], w2 = dinv[nn.z], w3 = dinv[nn.w];
        int2 p0 = *(const int2*)(Fb + (size_t)nn.x * D + tid * 4);
        int2 p1 = *(const int2*)(Fb + (size_t)nn.y * D + tid * 4);
        int2 p2 = *(const int2*)(Fb + (size_t)nn.z * D + tid * 4);
        int2 p3 = *(const int2*)(Fb + (size_t)nn.w * D + tid * 4);
        const unsigned short* u0 = (const unsigned short*)&p0;
        const unsigned short* u1 = (const unsigned short*)&p1;
        const unsigned short* u2 = (const unsigned short*)&p2;
        const unsigned short* u3 = (const unsigned short*)&p3;
        a0 += w0 * bf2f(u0[0]) + w1 * bf2f(u1[0]) + w2 * bf2f(u2[0]) + w3 * bf2f(u3[0]);
        a1 += w0 * bf2f(u0[1]) + w1 * bf2f(u1[1]) + w2 * bf2f(u2[1]) + w3 * bf2f(u3[1]);
        a2 += w0 * bf2f(u0[2]) + w1 * bf2f(u1[2]) + w2 * bf2f(u2[2]) + w3 * bf2f(u3[2]);
        a3 += w0 * bf2f(u0[3]) + w1 * bf2f(u1[3]) + w2 * bf2f(u2[3]) + w3 * bf2f(u3[3]);
    }
    int s = roff[i], e = roff[i + 1];
    int t = s;
    for (; t + 2 <= e; t += 2) {
        int j0 = ridx[t], j1 = ridx[t + 1];
        float w0 = dinv[j0], w1 = dinv[j1];
        int2 p0 = *(const int2*)(Fb + (size_t)j0 * D + tid * 4);
        int2 p1 = *(const int2*)(Fb + (size_t)j1 * D + tid * 4);
        const unsigned short* u0 = (const unsigned short*)&p0;
        const unsigned short* u1 = (const unsigned short*)&p1;
        a0 += w0 * bf2f(u0[0]) + w1 * bf2f(u1[0]);
        a1 += w0 * bf2f(u0[1]) + w1 * bf2f(u1[1]);
        a2 += w0 * bf2f(u0[2]) + w1 * bf2f(u1[2]);
        a3 += w0 * bf2f(u0[3]) + w1 * bf2f(u1[3]);
    }
    if (t < e) {
        int j0 = ridx[t];
        float w0 = dinv[j0];
        int2 p0 = *(const int2*)(Fb + (size_t)j0 * D + tid * 4);
        const unsigned short* u0 = (const unsigned short*)&p0;
        a0 += w0 * bf2f(u0[0]); a1 += w0 * bf2f(u0[1]);
        a2 += w0 * bf2f(u0[2]); a3 += w0 * bf2f(u0[3]);
    }
    float wi = dinv[i];
    union { unsigned short s4[4]; int2 q; } u;
    u.s4[0] = f2bf(wi * a0); u.s4[1] = f2bf(wi * a1);
    u.s4[2] = f2bf(wi * a2); u.s4[3] = f2bf(wi * a3);
    *(int2*)(G1b + (size_t)i * D + tid * 4) = u.q;
}

// ------- SpMM 2 fused with Yb build -------
__global__ __launch_bounds__(128) void k_spmm2y(const unsigned short* __restrict__ G1b,
                                                const float* __restrict__ F,
                                                const float* __restrict__ invnf,
                                                unsigned short* __restrict__ Yb,
                                                const int* __restrict__ topk,
                                                const int* __restrict__ roff,
                                                const int* __restrict__ ridx,
                                                const float* __restrict__ dinv) {
    int i = blockIdx.x, tid = threadIdx.x;
    float a0 = 0, a1 = 0, a2 = 0, a3 = 0;
    const int* ti = topk + (size_t)i * KNN;
#pragma unroll
    for (int k4 = 0; k4 < KNN / 4; k4++) {
        int4 nn = *(const int4*)(ti + k4 * 4);
        float w0 = dinv[nn.x], w1 = dinv[nn.y], w2 = dinv[nn.z], w3 = dinv[nn.w];
        int2 p0 = *(const int2*)(G1b + (size_t)nn.x * D + tid * 4);
        int2 p1 = *(const int2*)(G1b + (size_t)nn.y * D + tid * 4);
        int2 p2 = *(const int2*)(G1b + (size_t)nn.z * D + tid * 4);
        int2 p3 = *(const int2*)(G1b + (size_t)nn.w * D + tid * 4);
        const unsigned short* u0 = (const unsigned short*)&p0;
        const unsigned short* u1 = (const unsigned short*)&p1;
        const unsigned short* u2 = (const unsigned short*)&p2;
        const unsigned short* u3 = (const unsigned short*)&p3;
        a0 += w0 * bf2f(u0[0]) + w1 * bf2f(u1[0]) + w2 * bf2f(u2[0]) + w3 * bf2f(u3[0]);
        a1 += w0 * bf2f(u0[1]) + w1 * bf2f(u1[1]) + w2 * bf2f(u2[1]) + w3 * bf2f(u3[1]);
        a2 += w0 * bf2f(u0[2]) + w1 * bf2f(u1[2]) + w2 * bf2f(u2[2]) + w3 * bf2f(u3[2]);
        a3 += w0 * bf2f(u0[3]) + w1 * bf2f(u1[3]) + w2 * bf2f(u2[3]) + w3 * bf2f(u3[3]);
    }
    int s = roff[i], e = roff[i + 1];
    int t = s;
    for (; t + 2 <= e; t += 2) {
        int j0 = ridx[t], j1 = ridx[t + 1];
        float w0 = dinv[j0], w1 = dinv[j1];
        int2 p0 = *(const int2*)(G1b + (size_t)j0 * D + tid * 4);
        int2 p1 = *(const int2*)(G1b + (size_t)j1 * D + tid * 4);
        const unsigned short* u0 = (const unsigned short*)&p0;
        const unsigned short* u1 = (const unsigned short*)&p1;
        a0 += w0 * bf2f(u0[0]) + w1 * bf2f(u1[0]);
        a1 += w0 * bf2f(u0[1]) + w1 * bf2f(u1[1]);
        a2 += w0 * bf2f(u0[2]) + w1 * bf2f(u1[2]);
        a3 += w0 * bf2f(u0[3]) + w1 * bf2f(u1[3]);
    }
    if (t < e) {
        int j0 = ridx[t];
        float w0 = dinv[j0];
        int2 p0 = *(const int2*)(G1b + (size_t)j0 * D + tid * 4);
        const unsigned short* u0 = (const unsigned short*)&p0;
        a0 += w0 * bf2f(u0[0]); a1 += w0 * bf2f(u0[1]);
        a2 += w0 * bf2f(u0[2]); a3 += w0 * bf2f(u0[3]);
    }
    float wi = dinv[i];
    float g0 = wi * a0, g1 = wi * a1, g2 = wi * a2, g3 = wi * a3;

    float ss = g0 * g0 + g1 * g1 + g2 * g2 + g3 * g3;
    ss = waveReduceSum(ss);
    __shared__ float s2[2];
    if ((tid & 63) == 0) s2[tid >> 6] = ss;
    __syncthreads();
    float invng = 1.0f / fmaxf(sqrtf(s2[0] + s2[1]), 1e-12f);

    float4 f = ((const float4*)(F + (size_t)i * D))[tid];
    float inf_ = 10.0f * invnf[i];
    union { unsigned short s4[4]; int2 q; } u;
    u.s4[0] = f2bf(f.x * inf_ + g0 * invng);
    u.s4[1] = f2bf(f.y * inf_ + g1 * invng);
    u.s4[2] = f2bf(f.z * inf_ + g2 * invng);
    u.s4[3] = f2bf(f.w * inf_ + g3 * invng);
    *(int2*)(Yb + (size_t)i * D + tid * 4) = u.q;
}

// ------- register-resident online row softmax; writes bf16 weights in place ----------
__global__ __launch_bounds__(256) void k_softmax(float* __restrict__ chunk) {
    __shared__ float sm[4], sl[4];
    int li = blockIdx.x, tid = threadIdx.x;
    float* rp = chunk + (size_t)li * B;
    float4 v[8];
    float mt = -FLT_MAX;
#pragma unroll
    for (int p = 0; p < 8; p++) {
        v[p] = *(const float4*)(rp + p * 1024 + tid * 4);
        mt = fmaxf(mt, fmaxf(fmaxf(v[p].x, v[p].y), fmaxf(v[p].z, v[p].w)));
    }
    float l = 0.0f;
#pragma unroll
    for (int p = 0; p < 8; p++) {
        v[p].x = __expf(v[p].x - mt);
        v[p].y = __expf(v[p].y - mt);
        v[p].z = __expf(v[p].z - mt);
        v[p].w = __expf(v[p].w - mt);
        l += v[p].x + v[p].y + v[p].z + v[p].w;
    }
    float m = mt, lw = l;
#pragma unroll
    for (int off = 32; off; off >>= 1) {
        float om = __shfl_down(m, off);
        float ol = __shfl_down(lw, off);
        float nm = fmaxf(m, om);
        lw = lw * __expf(m - nm) + ol * __expf(om - nm);
        m = nm;
    }
    if ((tid & 63) == 0) { sm[tid >> 6] = m; sl[tid >> 6] = lw; }
    __syncthreads();
    float M = fmaxf(fmaxf(sm[0], sm[1]), fmaxf(sm[2], sm[3]));
    float L = sl[0] * __expf(sm[0] - M) + sl[1] * __expf(sm[1] - M) +
              sl[2] * __expf(sm[2] - M) + sl[3] * __expf(sm[3] - M);
    float fct = __expf(mt - M) / L;
    unsigned short* wp = (unsigned short*)rp;
#pragma unroll
    for (int p = 0; p < 8; p++) {
        union { unsigned short s[4]; int2 q; } u;
        u.s[0] = f2bf(v[p].x * fct);
        u.s[1] = f2bf(v[p].y * fct);
        u.s[2] = f2bf(v[p].z * fct);
        u.s[3] = f2bf(v[p].w * fct);
        *(int2*)(wp + p * 1024 + tid * 4) = u.q;
    }
}

extern "C" void kernel_launch(void* const* d_in, const int* in_sizes, int n_in,
                              void* d_out, int out_size, void* d_ws, size_t ws_size,
                              hipStream_t stream) {
    (void)in_sizes; (void)n_in; (void)out_size;
    const float* F = (const float*)d_in[0];
    float* out = (float*)d_out;

    char* ws = (char*)d_ws;
    size_t off = 0;
    auto take = [&](size_t bytes) -> void* {
        void* p = ws + off;
        off += (bytes + 255) & ~(size_t)255;
        return p;
    };
    float* invnf = (float*)take((size_t)B * 4);
    float* dinv = (float*)take((size_t)B * 4);
    int* topk = (int*)take((size_t)B * KNN * 4);
    int* indeg = (int*)take((size_t)B * 4);
    int* roff = (int*)take((size_t)(B + 1) * 4);
    int* rfill = (int*)take((size_t)B * 4);
    int* ridx = (int*)take((size_t)B * KNN * 4);
    unsigned short* Xb = (unsigned short*)take((size_t)B * D * 2);
    unsigned short* Fb = (unsigned short*)take((size_t)B * D * 2);
    unsigned short* Yb = (unsigned short*)take((size_t)B * D * 2);
    unsigned short* FbT = (unsigned short*)take((size_t)D * B * 2);
    size_t fixed = off;

    int R = 2048;
    if (ws_size > 0) {
        while (R > 128 && fixed + (size_t)R * B * 4 > ws_size) R >>= 1;
    } else {
        R = 1024;
    }
    float* chunk = (float*)(ws + fixed);
    unsigned short* G1b = (unsigned short*)out;

    int SK = 8192 / R;
    if (SK > 8) SK = 8;
    int ksplit = B / SK;
    bool use8 = (R % 256) == 0;

    // 1. Xb / Fb / invnf; FbT = bf16 F^T
    k_norm<<<B, 128, 0, stream>>>(F, Xb, Fb, invnf);
    dim3 gt(B / 64, D / 64);
    k_transpose<<<gt, 256, 0, stream>>>(F, FbT);

    // 2. chunked: sim = Xb Xb^T + top-K
    for (int r0 = 0; r0 < B; r0 += R) {
        if (use8) {
            dim3 g8(B / 256, R / 256);
            k_mfma8<<<g8, 512, 0, stream>>>(Xb + (size_t)r0 * D, D, Xb, D, chunk, B, D);
        } else {
            dim3 g(B / 128, R / 128);
            k_mfma_nt<<<g, 256, 0, stream>>>(Xb + (size_t)r0 * D, D, Xb, D, chunk, B, 0, D);
        }
        k_topk2<<<R, 256, 0, stream>>>(chunk, topk, r0);
    }

    // 3. graph build
    k_zero2<<<B / 256, 256, 0, stream>>>(indeg, rfill);
    k_count<<<B * KNN / 256, 256, 0, stream>>>(topk, indeg);
    k_scan<<<1, 1024, 0, stream>>>(indeg, roff);
    k_dinv<<<B / 256, 256, 0, stream>>>(indeg, dinv);
    k_fill<<<B * KNN / 256, 256, 0, stream>>>(topk, roff, rfill, ridx);

    // 4. G1b = A_hat Fb; Yb = 10*Xhat + normalize(A_hat G1b)
    k_spmm1<<<B, 128, 0, stream>>>(Fb, G1b, topk, roff, ridx, dinv);
    k_spmm2y<<<B, 128, 0, stream>>>(G1b, F, invnf, Yb, topk, roff, ridx, dinv);

    // 5. chunked: logits = Xb @ Yb^T -> softmax -> out rows = W @ F
    for (int r0 = 0; r0 < B; r0 += R) {
        if (use8) {
            dim3 g8(B / 256, R / 256);
            k_mfma8<<<g8, 512, 0, stream>>>(Xb + (size_t)r0 * D, D, Yb, D, chunk, B, D);
        } else {
            dim3 g(B / 128, R / 128);
            k_mfma_nt<<<g, 256, 0, stream>>>(Xb + (size_t)r0 * D, D, Yb, D, chunk, B, 0, D);
        }
        k_softmax<<<R, 256, 0, stream>>>(chunk);
        float* part = chunk + 4096;
        dim3 gf(D / 128, R / 128, SK);
        k_mfma_nt<<<gf, 256, 0, stream>>>((const unsigned short*)chunk, 2 * B, FbT, B,
                                          part, B, D, ksplit);
        k_red<<<R / 2, 256, 0, stream>>>(part, out + (size_t)r0 * D, SK);
    }
}